// Round 1
// baseline (3172.558 us; speedup 1.0000x reference)
//
#include <hip/hip_runtime.h>
#include <math.h>

constexpr int NB = 32;       // samples per angle
constexpr int LL = 16;       // bandwidth
constexpr int MM = 31;       // spectral orders (2*BW-1)
constexpr int MOFF = 15;
constexpr int NBATCH = 8;
constexpr int NCH = 50;
constexpr int NQ = MM * MM;          // 961
constexpr int SPAT = NB * NB * NB;   // 32768
constexpr long long HN = (long long)NBATCH * NCH * SPAT;  // 13,107,200

#define PI_D 3.14159265358979323846

__device__ inline float2 c_mk(float x, float y) { float2 r; r.x = x; r.y = y; return r; }

__device__ inline void fill_tw(float2* tw) {
  int t = threadIdx.x;
  if (t < 32) {
    double a = (double)t * (PI_D / 16.0);
    tw[t] = c_mk((float)cos(a), (float)sin(a));
  }
}

__device__ inline double dpow(double x, int n) {
  double r = 1.0;
  for (int i = 0; i < n; ++i) r *= x;
  return r;
}

// ---------------- constants ----------------

__global__ void qw_kernel(float* __restrict__ qw) {
  int j = threadIdx.x;
  if (j >= NB) return;
  double beta = PI_D * (2 * j + 1) / 64.0;
  double acc = 0.0;
  for (int kk = 0; kk < LL; ++kk)
    acc += sin((double)(2 * j + 1) * (2 * kk + 1) * PI_D / 64.0) / (double)(2 * kk + 1);
  qw[j] = (float)((2.0 / 16.0) * sin(beta) * acc);
}

// out layout [j][l][mp][m]; eqmode: nj==1, beta=pi/2
__global__ void wigner_kernel(float* __restrict__ out, int nj, int eqmode) {
  __shared__ double fact[66];
  int tid = threadIdx.x;
  if (tid < 66) { double f = 1.0; for (int i = 2; i <= tid; ++i) f *= (double)i; fact[tid] = f; }
  __syncthreads();
  int total = nj * LL * NQ;
  int idx = blockIdx.x * blockDim.x + tid;
  if (idx >= total) return;
  int q = idx % NQ;
  int l = (idx / NQ) % LL;
  int j = idx / (NQ * LL);
  int mp = q / MM - MOFF;
  int m  = q % MM - MOFF;
  int amp = mp < 0 ? -mp : mp, am = m < 0 ? -m : m;
  float res = 0.f;
  if (amp <= l && am <= l) {
    double beta = eqmode ? (PI_D * 0.5) : (PI_D * (2 * j + 1) / 64.0);
    double c = cos(beta * 0.5), s = sin(beta * 0.5);
    double pref = sqrt(fact[l + mp] * fact[l - mp] * fact[l + m] * fact[l - m]);
    int k0 = max(0, m - mp), k1 = min(l + m, l - mp);
    double acc = 0.0;
    for (int k = k0; k <= k1; ++k) {
      double denom = fact[l + m - k] * fact[k] * fact[l - k - mp] * fact[k - m + mp];
      double term = dpow(c, 2 * l - 2 * k + m - mp) * dpow(s, 2 * k - m + mp) / denom;
      acc += ((mp - m + k) & 1) ? -term : term;
    }
    res = (float)(pref * acc);
  }
  out[idx] = res;
}

// ---------------- layer 1 (S2 conv) ----------------

// per-b block: FFT x over alpha at signed orders, then contract over beta j.
__global__ __launch_bounds__(256) void s2_xh_kernel(const float* __restrict__ x,
                                                    const float* __restrict__ qw,
                                                    const float* __restrict__ dbeta,
                                                    float2* __restrict__ xh1) {
  __shared__ float xt[NB * NB];
  __shared__ float2 Xf0[NB * MM];
  __shared__ float2 tw[32];
  fill_tw(tw);
  int tid = threadIdx.x, b = blockIdx.x;
  for (int e = tid; e < NB * NB; e += 256) xt[e] = x[b * 1024 + e];
  __syncthreads();
  for (int e = tid; e < NB * MM; e += 256) {
    int j = e / MM, mi = e % MM, m = mi - MOFF;
    float re = 0.f, im = 0.f;
    const float* row = xt + j * NB;
    for (int a = 0; a < NB; ++a) {
      float v = row[a];
      float2 t = tw[(m * a) & 31];
      re += v * t.x; im -= v * t.y;   // e^{-i m a th}
    }
    Xf0[e] = c_mk(re, im);
  }
  __syncthreads();
  for (int e = tid; e < LL * MM; e += 256) {
    int l = e / MM, mi = e % MM;
    float re = 0.f, im = 0.f;
    for (int j = 0; j < NB; ++j) {
      float w = qw[j] * dbeta[(j * LL + l) * NQ + mi * MM + MOFF];
      float2 X = Xf0[j * MM + mi];
      re += w * X.x; im += w * X.y;
    }
    xh1[(b * LL + l) * MM + mi] = c_mk(re, im);
  }
}

// Wf[ni][ic] = sum_t W[ic][t] e^{-2pi i n t/32}, ic = i*Co+o
__global__ __launch_bounds__(256) void wfft_kernel(const float* __restrict__ W, int CiCo,
                                                   float2* __restrict__ Wf) {
  __shared__ float2 tw[32];
  fill_tw(tw);
  __syncthreads();
  int idx = blockIdx.x * blockDim.x + threadIdx.x;
  if (idx >= MM * CiCo) return;
  int ni = idx / CiCo, ic = idx % CiCo;
  int n = ni - MOFF;
  float re = 0.f, im = 0.f;
  for (int t = 0; t < NB; ++t) {
    float v = W[ic * NB + t];
    float2 tt = tw[(n * t) & 31];
    re += v * tt.x; im -= v * tt.y;
  }
  Wf[idx] = c_mk(re, im);
}

// z1[b,o,l,mi,ni] = deq0[l,ni] * xh1[b,l,mi] * conj(Wf1[ni,o])
__global__ void s2_z_kernel(const float2* __restrict__ xh1, const float2* __restrict__ Wf1,
                            const float* __restrict__ deq, float2* __restrict__ z) {
  int idx = blockIdx.x * blockDim.x + threadIdx.x;
  if (idx >= NBATCH * NCH * LL * NQ) return;
  int ni = idx % MM; int t = idx / MM;
  int mi = t % MM; t /= MM;
  int l = t % LL; t /= LL;
  int o = t % NCH; int b = t / NCH;
  float d0 = deq[(l * MM + ni) * MM + MOFF];
  float2 xv = xh1[(b * LL + l) * MM + mi];
  float2 wv = Wf1[ni * NCH + o];
  float re = d0 * (xv.x * wv.x + xv.y * wv.y);
  float im = d0 * (xv.y * wv.x - xv.x * wv.y);
  z[idx] = c_mk(re, im);
}

// ---------------- shared: SO(3) inverse transform ----------------
// block = (b*NCH+o)*8 + jg; handles 4 beta rows (j = jg*4..jg*4+3)
__global__ __launch_bounds__(256) void so3_ifft_kernel(const float2* __restrict__ z,
                                                       const float* __restrict__ dbeta,
                                                       const float* __restrict__ bias,
                                                       float* __restrict__ out) {
  __shared__ float2 F4[4 * NQ];   // 3844
  __shared__ float2 zl[NQ];
  __shared__ float2 G[MM * NB];   // 992
  __shared__ float2 tw[32];
  fill_tw(tw);
  int tid = threadIdx.x;
  int blk = blockIdx.x;
  int jg = blk & 7;
  int bo = blk >> 3;
  int o = bo % NCH;
  for (int e = tid; e < 4 * NQ; e += 256) F4[e] = c_mk(0.f, 0.f);
  __syncthreads();
  for (int l = 0; l < LL; ++l) {
    for (int e = tid; e < NQ; e += 256) zl[e] = z[((long long)bo * LL + l) * NQ + e];
    __syncthreads();
    float w2l = 2.f * l + 1.f;
    for (int e = tid; e < 4 * NQ; e += 256) {
      int jj = e / NQ, q = e % NQ;
      int j = jg * 4 + jj;
      float d = dbeta[(j * LL + l) * NQ + q];
      float2 zv = zl[q];
      F4[e].x += w2l * d * zv.x;
      F4[e].y += w2l * d * zv.y;
    }
    __syncthreads();
  }
  float bval = bias[o];
  for (int jj = 0; jj < 4; ++jj) {
    for (int e = tid; e < MM * NB; e += 256) {
      int mi = e >> 5, g = e & 31;
      float re = 0.f, im = 0.f;
      for (int ni = 0; ni < MM; ++ni) {
        float2 f = F4[jj * NQ + mi * MM + ni];
        float2 t = tw[((ni - MOFF) * g) & 31];   // e^{+i n g th}
        re += f.x * t.x - f.y * t.y;
        im += f.x * t.y + f.y * t.x;
      }
      G[e] = c_mk(re, im);
    }
    __syncthreads();
    int j = jg * 4 + jj;
    for (int e = tid; e < NB * NB; e += 256) {
      int a = e >> 5;
      float acc = bval;
      for (int mi = 0; mi < MM; ++mi) {
        float2 gv = G[mi * NB + (e & 31)];
        float2 t = tw[((mi - MOFF) * a) & 31];
        acc += gv.x * t.x - gv.y * t.y;    // Re
      }
      out[((long long)bo * NB + j) * 1024 + e] = acc;
    }
    __syncthreads();
  }
}

// ---------------- batchnorm ----------------

__global__ void bn_stats_kernel(const float* __restrict__ h, float2* __restrict__ partials) {
  __shared__ float s1[256], s2[256];
  int tid = threadIdx.x;
  long long base = (long long)blockIdx.x * SPAT;
  float a1 = 0.f, a2 = 0.f;
  for (int e = tid; e < SPAT; e += 256) { float v = h[base + e]; a1 += v; a2 += v * v; }
  s1[tid] = a1; s2[tid] = a2;
  __syncthreads();
  for (int s = 128; s > 0; s >>= 1) {
    if (tid < s) { s1[tid] += s1[tid + s]; s2[tid] += s2[tid + s]; }
    __syncthreads();
  }
  if (tid == 0) partials[blockIdx.x] = c_mk(s1[0], s2[0]);
}

__global__ void bn_finalize_kernel(const float2* __restrict__ partials,
                                   const float* __restrict__ g, const float* __restrict__ bb,
                                   float2* __restrict__ sc) {
  int o = threadIdx.x;
  if (o >= NCH) return;
  float s = 0.f, ss = 0.f;
  for (int b = 0; b < NBATCH; ++b) { float2 p = partials[b * NCH + o]; s += p.x; ss += p.y; }
  float inv = 1.f / (float)(NBATCH * SPAT);
  float mu = s * inv;
  float var = ss * inv - mu * mu;
  float scale = g[o] * rsqrtf(var + 1e-5f);
  sc[o] = c_mk(scale, bb[o] - mu * scale);
}

__global__ void bn_apply_relu_kernel(float* __restrict__ h, const float2* __restrict__ sc) {
  long long gid = ((long long)blockIdx.x * blockDim.x + threadIdx.x) * 4;
  if (gid >= HN) return;
  int ch = (int)((gid >> 15) % NCH);
  float2 s = sc[ch];
  float4 v = *reinterpret_cast<const float4*>(h + gid);
  v.x = fmaxf(v.x * s.x + s.y, 0.f);
  v.y = fmaxf(v.y * s.x + s.y, 0.f);
  v.z = fmaxf(v.z * s.x + s.y, 0.f);
  v.w = fmaxf(v.w * s.x + s.y, 0.f);
  *reinterpret_cast<float4*>(h + gid) = v;
}

// ---------------- SO(3) conv ----------------

// block = (b*NCH+c)*NB + j: 2D DFT of one 32x32 tile at signed orders
__global__ __launch_bounds__(256) void dft2_kernel(const float* __restrict__ h,
                                                   float2* __restrict__ Xf) {
  __shared__ float xt[NB * NB];
  __shared__ float2 P[NB * MM];   // [a][ni]
  __shared__ float2 tw[32];
  fill_tw(tw);
  int tid = threadIdx.x;
  long long blk = blockIdx.x;
  const float* src = h + blk * 1024;
  for (int e = tid; e < NB * NB; e += 256) xt[e] = src[e];
  __syncthreads();
  for (int e = tid; e < NB * MM; e += 256) {
    int a = e / MM, ni = e % MM, n = ni - MOFF;
    float re = 0.f, im = 0.f;
    const float* row = xt + a * NB;
    for (int g = 0; g < NB; ++g) {
      float v = row[g];
      float2 t = tw[(n * g) & 31];
      re += v * t.x; im -= v * t.y;
    }
    P[e] = c_mk(re, im);
  }
  __syncthreads();
  float2* dst = Xf + blk * NQ;
  for (int e = tid; e < NQ; e += 256) {
    int mi = e / MM, ni = e % MM, m = mi - MOFF;
    float re = 0.f, im = 0.f;
    for (int a = 0; a < NB; ++a) {
      float2 p = P[a * MM + ni];
      float2 t = tw[(m * a) & 31];
      re += p.x * t.x + p.y * t.y;   // p * conj(t)
      im += p.y * t.x - p.x * t.y;
    }
    dst[e] = c_mk(re, im);
  }
}

// xh[bc,l,q] = sum_j qw[j]*dbeta[j,l,q]*Xf[bc,j,q]
__global__ void xh_kernel(const float2* __restrict__ Xf, const float* __restrict__ qw,
                          const float* __restrict__ dbeta, float2* __restrict__ xh) {
  int idx = blockIdx.x * blockDim.x + threadIdx.x;
  if (idx >= NBATCH * NCH * NQ) return;
  int q = idx % NQ;
  int bc = idx / NQ;
  float2 acc[LL];
  #pragma unroll
  for (int l = 0; l < LL; ++l) acc[l] = c_mk(0.f, 0.f);
  for (int j = 0; j < NB; ++j) {
    float2 xv = Xf[((long long)bc * NB + j) * NQ + q];
    float qj = qw[j];
    const float* dbase = dbeta + (long long)(j * LL) * NQ + q;
    #pragma unroll
    for (int l = 0; l < LL; ++l) {
      float w = qj * dbase[l * NQ];
      acc[l].x += w * xv.x;
      acc[l].y += w * xv.y;
    }
  }
  #pragma unroll
  for (int l = 0; l < LL; ++l) xh[((long long)bc * LL + l) * NQ + q] = acc[l];
}

// hk[bc,l,mi,ni] = sum_k xh[bc,l,mi,k] * deq[l,ni,k]
__global__ void hk_kernel(const float2* __restrict__ xh, const float* __restrict__ deq,
                          float2* __restrict__ hk) {
  int idx = blockIdx.x * blockDim.x + threadIdx.x;
  if (idx >= NBATCH * NCH * LL * NQ) return;
  int ni = idx % MM;
  int rest = idx / MM;               // (bc*LL+l)*MM + mi
  int l = (rest / MM) % LL;
  const float2* row = xh + (long long)rest * MM;
  const float* dr = deq + (l * MM + ni) * MM;
  float re = 0.f, im = 0.f;
  for (int k = 0; k < MM; ++k) {
    float d = dr[k];
    float2 v = row[k];
    re += d * v.x; im += d * v.y;
  }
  hk[idx] = c_mk(re, im);
}

// z[b,o,l,q] = sum_i hk[b,i,l,q] * conj(Wf[ni,i,o]); thread per (b,l,q), o in chunks of 10
__global__ void z_kernel(const float2* __restrict__ hk, const float2* __restrict__ Wf,
                         float2* __restrict__ z) {
  int idx = blockIdx.x * blockDim.x + threadIdx.x;
  if (idx >= NBATCH * LL * NQ) return;
  int q = idx % NQ;
  int t = idx / NQ;
  int l = t % LL;
  int b = t / LL;
  int ni = q % MM;
  for (int oc = 0; oc < 5; ++oc) {
    float2 acc[10];
    #pragma unroll
    for (int u = 0; u < 10; ++u) acc[u] = c_mk(0.f, 0.f);
    for (int i = 0; i < NCH; ++i) {
      float2 hv = hk[((long long)(b * NCH + i) * LL + l) * NQ + q];
      const float2* wrow = Wf + (ni * NCH + i) * NCH + oc * 10;
      #pragma unroll
      for (int u = 0; u < 10; ++u) {
        float2 w = wrow[u];
        acc[u].x += hv.x * w.x + hv.y * w.y;   // hv * conj(w)
        acc[u].y += hv.y * w.x - hv.x * w.y;
      }
    }
    #pragma unroll
    for (int u = 0; u < 10; ++u) {
      int o = oc * 10 + u;
      z[((long long)(b * NCH + o) * LL + l) * NQ + q] = acc[u];
    }
  }
}

// ---------------- head ----------------

__global__ void pool_kernel(const float* __restrict__ h, float* __restrict__ pooled) {
  __shared__ float sm[256];
  int tid = threadIdx.x;
  const float* base = h + (long long)blockIdx.x * SPAT;
  float best = -1e30f;
  for (int e = tid; e < 1024; e += 256) {
    float s = 0.f;
    for (int g = 0; g < NB; ++g) s += base[e * NB + g];
    best = fmaxf(best, s * (1.f / 32.f));
  }
  sm[tid] = best;
  __syncthreads();
  for (int s = 128; s > 0; s >>= 1) {
    if (tid < s) sm[tid] = fmaxf(sm[tid], sm[tid + s]);
    __syncthreads();
  }
  if (tid == 0) pooled[blockIdx.x] = sm[0];
}

__global__ __launch_bounds__(256) void head_kernel(const float* __restrict__ pooled,
    const float* __restrict__ fc1w, const float* __restrict__ fc1b,
    const float* __restrict__ g1, const float* __restrict__ b1,
    const float* __restrict__ fc2w, const float* __restrict__ fc2b,
    const float* __restrict__ g2, const float* __restrict__ b2,
    const float* __restrict__ fc3w, const float* __restrict__ fc3b,
    float* __restrict__ out) {
  __shared__ float pin[NBATCH * NCH];
  __shared__ float A[NBATCH * 256];
  __shared__ float Bm[NBATCH * 128];
  __shared__ float Cm[NBATCH * 40];
  int tid = threadIdx.x;
  for (int e = tid; e < NBATCH * NCH; e += 256) pin[e] = pooled[e];
  __syncthreads();
  {
    float v[NBATCH];
    #pragma unroll
    for (int b = 0; b < NBATCH; ++b) {
      float acc = fc1b[tid];
      for (int c = 0; c < NCH; ++c) acc += pin[b * NCH + c] * fc1w[tid * NCH + c];
      v[b] = acc;
    }
    float s = 0.f, ss = 0.f;
    #pragma unroll
    for (int b = 0; b < NBATCH; ++b) { s += v[b]; ss += v[b] * v[b]; }
    float mu = s * 0.125f, var = ss * 0.125f - mu * mu;
    float sc = g1[tid] * rsqrtf(var + 1e-5f), sh = b1[tid] - mu * sc;
    #pragma unroll
    for (int b = 0; b < NBATCH; ++b) A[b * 256 + tid] = fmaxf(v[b] * sc + sh, 0.f);
  }
  __syncthreads();
  if (tid < 128) {
    float v[NBATCH];
    #pragma unroll
    for (int b = 0; b < NBATCH; ++b) {
      float acc = fc2b[tid];
      for (int c = 0; c < 256; ++c) acc += A[b * 256 + c] * fc2w[tid * 256 + c];
      v[b] = acc;
    }
    float s = 0.f, ss = 0.f;
    #pragma unroll
    for (int b = 0; b < NBATCH; ++b) { s += v[b]; ss += v[b] * v[b]; }
    float mu = s * 0.125f, var = ss * 0.125f - mu * mu;
    float sc = g2[tid] * rsqrtf(var + 1e-5f), sh = b2[tid] - mu * sc;
    #pragma unroll
    for (int b = 0; b < NBATCH; ++b) Bm[b * 128 + tid] = fmaxf(v[b] * sc + sh, 0.f);
  }
  __syncthreads();
  if (tid < 40) {
    #pragma unroll
    for (int b = 0; b < NBATCH; ++b) {
      float acc = fc3b[tid];
      for (int c = 0; c < 128; ++c) acc += Bm[b * 128 + c] * fc3w[tid * 128 + c];
      Cm[b * 40 + tid] = acc;
    }
  }
  __syncthreads();
  if (tid < NBATCH) {
    int b = tid;
    float mx = -1e30f;
    for (int f = 0; f < 40; ++f) mx = fmaxf(mx, Cm[b * 40 + f]);
    float se = 0.f;
    for (int f = 0; f < 40; ++f) se += expf(Cm[b * 40 + f] - mx);
    float lse = mx + logf(se);
    for (int f = 0; f < 40; ++f) out[b * 40 + f] = Cm[b * 40 + f] - lse;
  }
}

// ---------------- host ----------------

extern "C" void kernel_launch(void* const* d_in, const int* in_sizes, int n_in,
                              void* d_out, int out_size, void* d_ws, size_t ws_size,
                              hipStream_t stream) {
  (void)in_sizes; (void)n_in; (void)out_size;
  const float* x    = (const float*)d_in[0];
  const float* k1   = (const float*)d_in[1];
  const float* c1b  = (const float*)d_in[2];
  const float* bn1g = (const float*)d_in[3];
  const float* bn1b = (const float*)d_in[4];
  const float* k2   = (const float*)d_in[5];
  const float* c2b  = (const float*)d_in[6];
  const float* bn2g = (const float*)d_in[7];
  const float* bn2b = (const float*)d_in[8];
  const float* k3   = (const float*)d_in[9];
  const float* c3b  = (const float*)d_in[10];
  const float* bn3g = (const float*)d_in[11];
  const float* bn3b = (const float*)d_in[12];
  const float* fc1w = (const float*)d_in[13];
  const float* fc1b = (const float*)d_in[14];
  const float* g1   = (const float*)d_in[15];
  const float* bb1  = (const float*)d_in[16];
  const float* fc2w = (const float*)d_in[17];
  const float* fc2b = (const float*)d_in[18];
  const float* g2   = (const float*)d_in[19];
  const float* bb2  = (const float*)d_in[20];
  const float* fc3w = (const float*)d_in[21];
  const float* fc3b = (const float*)d_in[22];
  float* out = (float*)d_out;

  char* ws = (char*)d_ws;
  size_t off = 0;
  auto alloc = [&](size_t n) -> char* {
    char* p = ws + off;
    off += (n + 255) & ~(size_t)255;
    return p;
  };

  float*  dbeta  = (float*)alloc(sizeof(float) * NB * LL * NQ);      // 1.97 MB
  float*  deq    = (float*)alloc(sizeof(float) * LL * NQ);
  float*  qw     = (float*)alloc(sizeof(float) * NB);
  float2* xh1    = (float2*)alloc(sizeof(float2) * NBATCH * LL * MM);
  float2* Wf     = (float2*)alloc(sizeof(float2) * MM * NCH * NCH);  // 620 KB
  float2* parts  = (float2*)alloc(sizeof(float2) * NBATCH * NCH);
  float2* bnsc   = (float2*)alloc(sizeof(float2) * 64);
  float*  pooled = (float*)alloc(sizeof(float) * NBATCH * NCH);
  float*  HA     = (float*)alloc(sizeof(float) * (size_t)HN);        // 52.4 MB
  float*  HB     = (float*)alloc(sizeof(float) * (size_t)HN);        // 52.4 MB
  size_t XFB = (size_t)NBATCH * NCH * NB * NQ * sizeof(float2);      // 98.4 MB
  size_t XHB = (size_t)NBATCH * NCH * LL * NQ * sizeof(float2);      // 49.2 MB
  char* AR = alloc(XFB + XHB);                                       // 147.6 MB arena
  float2* Xf = (float2*)AR;            // live: dft2 -> xh
  float2* xh = (float2*)(AR + XFB);    // live: xh -> hk
  float2* hk = (float2*)AR;            // live: hk -> z   (reuses dead Xf)
  float2* zb = (float2*)(AR + XFB);    // live: z  -> ifft (reuses dead xh; also z1)

  if (ws_size < off) return;  // insufficient scratch: leave d_out zeroed (clean failure)

  const int T = 256;
  // constants
  qw_kernel<<<1, 32, 0, stream>>>(qw);
  wigner_kernel<<<(NB * LL * NQ + T - 1) / T, T, 0, stream>>>(dbeta, NB, 0);
  wigner_kernel<<<(LL * NQ + T - 1) / T, T, 0, stream>>>(deq, 1, 1);

  // ---- layer 1: S2 conv -> HA
  s2_xh_kernel<<<NBATCH, T, 0, stream>>>(x, qw, dbeta, xh1);
  wfft_kernel<<<(MM * 1 * NCH + T - 1) / T, T, 0, stream>>>(k1, 1 * NCH, Wf);
  s2_z_kernel<<<(NBATCH * NCH * LL * NQ + T - 1) / T, T, 0, stream>>>(xh1, Wf, deq, zb);
  so3_ifft_kernel<<<NBATCH * NCH * 8, T, 0, stream>>>(zb, dbeta, c1b, HA);
  bn_stats_kernel<<<NBATCH * NCH, T, 0, stream>>>(HA, parts);
  bn_finalize_kernel<<<1, 64, 0, stream>>>(parts, bn1g, bn1b, bnsc);
  bn_apply_relu_kernel<<<(int)(HN / 4 / T), T, 0, stream>>>(HA, bnsc);

  // ---- layer 2: SO(3) conv HA -> HB
  dft2_kernel<<<NBATCH * NCH * NB, T, 0, stream>>>(HA, Xf);
  xh_kernel<<<(NBATCH * NCH * NQ + T - 1) / T, T, 0, stream>>>(Xf, qw, dbeta, xh);
  wfft_kernel<<<(MM * NCH * NCH + T - 1) / T, T, 0, stream>>>(k2, NCH * NCH, Wf);
  hk_kernel<<<(NBATCH * NCH * LL * NQ + T - 1) / T, T, 0, stream>>>(xh, deq, hk);
  z_kernel<<<(NBATCH * LL * NQ + T - 1) / T, T, 0, stream>>>(hk, Wf, zb);
  so3_ifft_kernel<<<NBATCH * NCH * 8, T, 0, stream>>>(zb, dbeta, c2b, HB);
  bn_stats_kernel<<<NBATCH * NCH, T, 0, stream>>>(HB, parts);
  bn_finalize_kernel<<<1, 64, 0, stream>>>(parts, bn2g, bn2b, bnsc);
  bn_apply_relu_kernel<<<(int)(HN / 4 / T), T, 0, stream>>>(HB, bnsc);

  // ---- layer 3: SO(3) conv HB -> HA
  dft2_kernel<<<NBATCH * NCH * NB, T, 0, stream>>>(HB, Xf);
  xh_kernel<<<(NBATCH * NCH * NQ + T - 1) / T, T, 0, stream>>>(Xf, qw, dbeta, xh);
  wfft_kernel<<<(MM * NCH * NCH + T - 1) / T, T, 0, stream>>>(k3, NCH * NCH, Wf);
  hk_kernel<<<(NBATCH * NCH * LL * NQ + T - 1) / T, T, 0, stream>>>(xh, deq, hk);
  z_kernel<<<(NBATCH * LL * NQ + T - 1) / T, T, 0, stream>>>(hk, Wf, zb);
  so3_ifft_kernel<<<NBATCH * NCH * 8, T, 0, stream>>>(zb, dbeta, c3b, HA);
  bn_stats_kernel<<<NBATCH * NCH, T, 0, stream>>>(HA, parts);
  bn_finalize_kernel<<<1, 64, 0, stream>>>(parts, bn3g, bn3b, bnsc);
  bn_apply_relu_kernel<<<(int)(HN / 4 / T), T, 0, stream>>>(HA, bnsc);

  // ---- head
  pool_kernel<<<NBATCH * NCH, T, 0, stream>>>(HA, pooled);
  head_kernel<<<1, T, 0, stream>>>(pooled, fc1w, fc1b, g1, bb1,
                                   fc2w, fc2b, g2, bb2, fc3w, fc3b, out);
}

// Round 2
// 1743.860 us; speedup vs baseline: 1.8193x; 1.8193x over previous
//
#include <hip/hip_runtime.h>
#include <math.h>

constexpr int NB = 32;       // samples per angle
constexpr int LL = 16;       // bandwidth
constexpr int MM = 31;       // spectral orders (2*BW-1)
constexpr int MOFF = 15;
constexpr int NBATCH = 8;
constexpr int NCH = 50;
constexpr int NQ = MM * MM;          // 961
constexpr int SPAT = NB * NB * NB;   // 32768
constexpr long long HN = (long long)NBATCH * NCH * SPAT;  // 13,107,200

#define PI_D 3.14159265358979323846

__device__ inline float2 c_mk(float x, float y) { float2 r; r.x = x; r.y = y; return r; }

__device__ inline void fill_tw(float2* tw) {
  int t = threadIdx.x;
  if (t < 32) {
    double a = (double)t * (PI_D / 16.0);
    tw[t] = c_mk((float)cos(a), (float)sin(a));
  }
}

__device__ inline double dpow(double x, int n) {
  double r = 1.0;
  for (int i = 0; i < n; ++i) r *= x;
  return r;
}

// ---------------- constants ----------------

__global__ void qw_kernel(float* __restrict__ qw) {
  int j = threadIdx.x;
  if (j >= NB) return;
  double beta = PI_D * (2 * j + 1) / 64.0;
  double acc = 0.0;
  for (int kk = 0; kk < LL; ++kk)
    acc += sin((double)(2 * j + 1) * (2 * kk + 1) * PI_D / 64.0) / (double)(2 * kk + 1);
  qw[j] = (float)((2.0 / 16.0) * sin(beta) * acc);
}

// out layout [j][l][mp][m]; eqmode: nj==1, beta=pi/2
__global__ void wigner_kernel(float* __restrict__ out, int nj, int eqmode) {
  __shared__ double fact[66];
  int tid = threadIdx.x;
  if (tid < 66) { double f = 1.0; for (int i = 2; i <= tid; ++i) f *= (double)i; fact[tid] = f; }
  __syncthreads();
  int total = nj * LL * NQ;
  int idx = blockIdx.x * blockDim.x + tid;
  if (idx >= total) return;
  int q = idx % NQ;
  int l = (idx / NQ) % LL;
  int j = idx / (NQ * LL);
  int mp = q / MM - MOFF;
  int m  = q % MM - MOFF;
  int amp = mp < 0 ? -mp : mp, am = m < 0 ? -m : m;
  float res = 0.f;
  if (amp <= l && am <= l) {
    double beta = eqmode ? (PI_D * 0.5) : (PI_D * (2 * j + 1) / 64.0);
    double c = cos(beta * 0.5), s = sin(beta * 0.5);
    double pref = sqrt(fact[l + mp] * fact[l - mp] * fact[l + m] * fact[l - m]);
    int k0 = max(0, m - mp), k1 = min(l + m, l - mp);
    double acc = 0.0;
    for (int k = k0; k <= k1; ++k) {
      double denom = fact[l + m - k] * fact[k] * fact[l - k - mp] * fact[k - m + mp];
      double term = dpow(c, 2 * l - 2 * k + m - mp) * dpow(s, 2 * k - m + mp) / denom;
      acc += ((mp - m + k) & 1) ? -term : term;
    }
    res = (float)(pref * acc);
  }
  out[idx] = res;
}

// ---------------- layer 1 (S2 conv) ----------------

__global__ __launch_bounds__(256) void s2_xh_kernel(const float* __restrict__ x,
                                                    const float* __restrict__ qw,
                                                    const float* __restrict__ dbeta,
                                                    float2* __restrict__ xh1) {
  __shared__ float xt[NB * NB];
  __shared__ float2 Xf0[NB * MM];
  __shared__ float2 tw[32];
  fill_tw(tw);
  int tid = threadIdx.x, b = blockIdx.x;
  for (int e = tid; e < NB * NB; e += 256) xt[e] = x[b * 1024 + e];
  __syncthreads();
  for (int e = tid; e < NB * MM; e += 256) {
    int j = e / MM, mi = e % MM, m = mi - MOFF;
    float re = 0.f, im = 0.f;
    const float* row = xt + j * NB;
    for (int a = 0; a < NB; ++a) {
      float v = row[a];
      float2 t = tw[(m * a) & 31];
      re += v * t.x; im -= v * t.y;   // e^{-i m a th}
    }
    Xf0[e] = c_mk(re, im);
  }
  __syncthreads();
  for (int e = tid; e < LL * MM; e += 256) {
    int l = e / MM, mi = e % MM;
    float re = 0.f, im = 0.f;
    for (int j = 0; j < NB; ++j) {
      float w = qw[j] * dbeta[(j * LL + l) * NQ + mi * MM + MOFF];
      float2 X = Xf0[j * MM + mi];
      re += w * X.x; im += w * X.y;
    }
    xh1[(b * LL + l) * MM + mi] = c_mk(re, im);
  }
}

// Wf[ni][ic] = sum_t W[ic][t] e^{-2pi i n t/32}, ic = i*Co+o
__global__ __launch_bounds__(256) void wfft_kernel(const float* __restrict__ W, int CiCo,
                                                   float2* __restrict__ Wf) {
  __shared__ float2 tw[32];
  fill_tw(tw);
  __syncthreads();
  int idx = blockIdx.x * blockDim.x + threadIdx.x;
  if (idx >= MM * CiCo) return;
  int ni = idx / CiCo, ic = idx % CiCo;
  int n = ni - MOFF;
  float re = 0.f, im = 0.f;
  for (int t = 0; t < NB; ++t) {
    float v = W[ic * NB + t];
    float2 tt = tw[(n * t) & 31];
    re += v * tt.x; im -= v * tt.y;
  }
  Wf[idx] = c_mk(re, im);
}

// z1[b,o,l,mi,ni] = deq0[l,ni] * xh1[b,l,mi] * conj(Wf1[ni,o])
__global__ void s2_z_kernel(const float2* __restrict__ xh1, const float2* __restrict__ Wf1,
                            const float* __restrict__ deq, float2* __restrict__ z) {
  int idx = blockIdx.x * blockDim.x + threadIdx.x;
  if (idx >= NBATCH * NCH * LL * NQ) return;
  int ni = idx % MM; int t = idx / MM;
  int mi = t % MM; t /= MM;
  int l = t % LL; t /= LL;
  int o = t % NCH; int b = t / NCH;
  float d0 = deq[(l * MM + ni) * MM + MOFF];
  float2 xv = xh1[(b * LL + l) * MM + mi];
  float2 wv = Wf1[ni * NCH + o];
  float re = d0 * (xv.x * wv.x + xv.y * wv.y);
  float im = d0 * (xv.y * wv.x - xv.x * wv.y);
  z[idx] = c_mk(re, im);
}

// ---------------- shared: SO(3) inverse transform ----------------
// One block per (bo, j). LDS ~16KB. Both DFT phases use the +/-16
// decimation identity: e^{i n (g+16) th} = -(-1)^{ni} e^{i n g th}.
__global__ __launch_bounds__(256) void so3_ifft2_kernel(const float2* __restrict__ z,
                                                        const float* __restrict__ dbeta,
                                                        const float* __restrict__ bias,
                                                        float* __restrict__ out) {
  __shared__ float2 Fq[NQ];       // 7.7 KB
  __shared__ float2 G[MM * NB];   // 7.9 KB
  __shared__ float2 tw[32];
  fill_tw(tw);
  int tid = threadIdx.x;
  int blk = blockIdx.x;
  // bijective XCD swizzle (12800 % 8 == 0): keep all 32 j-blocks of one bo
  // on one XCD so the z slice is fetched into that L2 once.
  blk = (blk & 7) * 1600 + (blk >> 3);
  int j = blk & 31;
  int bo = blk >> 5;
  int o = bo % NCH;

  // F[q] = sum_l (2l+1) * d(j,l,q) * z(bo,l,q)   (global reads, coalesced)
  for (int e = tid; e < NQ; e += 256) {
    float fr = 0.f, fi = 0.f;
    const float* dptr = dbeta + (j * LL) * NQ + e;
    const float2* zptr = z + (long long)bo * LL * NQ + e;
    #pragma unroll
    for (int l = 0; l < LL; ++l) {
      float w = (2.f * l + 1.f) * dptr[l * NQ];
      float2 zv = zptr[l * NQ];
      fr += w * zv.x; fi += w * zv.y;
    }
    Fq[e] = c_mk(fr, fi);
  }
  __syncthreads();

  // G[m,g] = sum_ni F[m,ni] e^{i(ni-15) g th}; compute g and g+16 together.
  for (int e = tid; e < MM * 16; e += 256) {
    int m = e >> 4, g = e & 15;
    const float2* Fr = Fq + m * MM;
    float aex = 0.f, aey = 0.f, aox = 0.f, aoy = 0.f;
    #pragma unroll
    for (int p = 0; p < 15; ++p) {
      int ni = 2 * p;
      float2 f = Fr[ni];
      float2 t = tw[((ni - 15) * g) & 31];
      aex += f.x * t.x - f.y * t.y;
      aey += f.x * t.y + f.y * t.x;
      float2 f2 = Fr[ni + 1];
      float2 t2 = tw[((ni - 14) * g) & 31];
      aox += f2.x * t2.x - f2.y * t2.y;
      aoy += f2.x * t2.y + f2.y * t2.x;
    }
    { // ni = 30 (even)
      float2 f = Fr[30];
      float2 t = tw[(15 * g) & 31];
      aex += f.x * t.x - f.y * t.y;
      aey += f.x * t.y + f.y * t.x;
    }
    G[m * NB + g]      = c_mk(aex + aox, aey + aoy);
    G[m * NB + g + 16] = c_mk(aox - aex, aoy - aey);
  }
  __syncthreads();

  // out[a,g] = bias + Re sum_mi G[mi,g] e^{i(mi-15) a th}; a and a+16 together.
  float bval = bias[o];
  long long obase = (long long)bo * SPAT + (long long)j * 1024;
  for (int e = tid; e < 16 * NB; e += 256) {
    int a = e >> 5, g = e & 31;
    float be = 0.f, bo_ = 0.f;
    #pragma unroll
    for (int p = 0; p < 15; ++p) {
      int mi = 2 * p;
      float2 gv = G[mi * NB + g];
      float2 t = tw[((mi - 15) * a) & 31];
      be += gv.x * t.x - gv.y * t.y;
      float2 gv2 = G[(mi + 1) * NB + g];
      float2 t2 = tw[((mi - 14) * a) & 31];
      bo_ += gv2.x * t2.x - gv2.y * t2.y;
    }
    { // mi = 30 (even)
      float2 gv = G[30 * NB + g];
      float2 t = tw[(15 * a) & 31];
      be += gv.x * t.x - gv.y * t.y;
    }
    out[obase + a * 32 + g]        = bval + be + bo_;
    out[obase + (a + 16) * 32 + g] = bval + bo_ - be;
  }
}

// ---------------- batchnorm ----------------

__global__ void bn_stats_kernel(const float* __restrict__ h, float2* __restrict__ partials) {
  __shared__ float s1[256], s2[256];
  int tid = threadIdx.x;
  long long base = (long long)blockIdx.x * SPAT;
  float a1 = 0.f, a2 = 0.f;
  for (int e = tid; e < SPAT; e += 256) { float v = h[base + e]; a1 += v; a2 += v * v; }
  s1[tid] = a1; s2[tid] = a2;
  __syncthreads();
  for (int s = 128; s > 0; s >>= 1) {
    if (tid < s) { s1[tid] += s1[tid + s]; s2[tid] += s2[tid + s]; }
    __syncthreads();
  }
  if (tid == 0) partials[blockIdx.x] = c_mk(s1[0], s2[0]);
}

__global__ void bn_finalize_kernel(const float2* __restrict__ partials,
                                   const float* __restrict__ g, const float* __restrict__ bb,
                                   float2* __restrict__ sc) {
  int o = threadIdx.x;
  if (o >= NCH) return;
  float s = 0.f, ss = 0.f;
  for (int b = 0; b < NBATCH; ++b) { float2 p = partials[b * NCH + o]; s += p.x; ss += p.y; }
  float inv = 1.f / (float)(NBATCH * SPAT);
  float mu = s * inv;
  float var = ss * inv - mu * mu;
  float scale = g[o] * rsqrtf(var + 1e-5f);
  sc[o] = c_mk(scale, bb[o] - mu * scale);
}

__global__ void bn_apply_relu_kernel(float* __restrict__ h, const float2* __restrict__ sc) {
  long long gid = ((long long)blockIdx.x * blockDim.x + threadIdx.x) * 4;
  if (gid >= HN) return;
  int ch = (int)((gid >> 15) % NCH);
  float2 s = sc[ch];
  float4 v = *reinterpret_cast<const float4*>(h + gid);
  v.x = fmaxf(v.x * s.x + s.y, 0.f);
  v.y = fmaxf(v.y * s.x + s.y, 0.f);
  v.z = fmaxf(v.z * s.x + s.y, 0.f);
  v.w = fmaxf(v.w * s.x + s.y, 0.f);
  *reinterpret_cast<float4*>(h + gid) = v;
}

// ---------------- SO(3) conv ----------------

// 2D DFT of a real 32x32 tile -> 31x31 signed-order spectrum.
// Real-input symmetry: compute n=0..15 only; X[-m,-n] = conj(X[m,n]).
__global__ __launch_bounds__(256) void dft2b_kernel(const float* __restrict__ h,
                                                    float2* __restrict__ Xf) {
  __shared__ float xt[32 * 33];   // padded stride kills bank conflict
  __shared__ float2 P[32 * 16];   // [a][n], n = 0..15
  __shared__ float2 Xs[NQ];
  __shared__ float2 tw[32];
  fill_tw(tw);
  int tid = threadIdx.x;
  long long blk = blockIdx.x;
  const float* src = h + blk * 1024;
  for (int e = tid; e < 1024; e += 256) xt[(e >> 5) * 33 + (e & 31)] = src[e];
  __syncthreads();
  // P[a,n] = sum_g x[a,g] e^{-i n g th}
  for (int e = tid; e < 512; e += 256) {
    int a = e >> 4, n = e & 15;
    float re = 0.f, im = 0.f;
    const float* row = xt + a * 33;
    #pragma unroll
    for (int g = 0; g < 32; ++g) {
      float v = row[g];
      float2 t = tw[(n * g) & 31];
      re += v * t.x; im -= v * t.y;
    }
    P[a * 16 + n] = c_mk(re, im);
  }
  __syncthreads();
  // X[m,n] = sum_a P[a,n] e^{-i m a th}; compute m=+mh and m=-mh together.
  {
    int e = tid;
    if (e < 256) {
      int mh = e >> 4, n = e & 15;
      float sxx = 0.f, sxy = 0.f, syx = 0.f, syy = 0.f;
      #pragma unroll
      for (int a = 0; a < 32; ++a) {
        float2 p = P[a * 16 + n];
        float2 t = tw[(mh * a) & 31];
        sxx += p.x * t.x; sxy += p.x * t.y;
        syx += p.y * t.x; syy += p.y * t.y;
      }
      float2 Xp = c_mk(sxx + syy, syx - sxy);   // X[+mh, n]
      float2 Xm = c_mk(sxx - syy, syx + sxy);   // X[-mh, n]
      Xs[(mh + MOFF) * MM + (n + MOFF)] = Xp;
      Xs[(MOFF - mh) * MM + (n + MOFF)] = Xm;
      Xs[(MOFF - mh) * MM + (MOFF - n)] = c_mk(Xp.x, -Xp.y);
      Xs[(mh + MOFF) * MM + (MOFF - n)] = c_mk(Xm.x, -Xm.y);
    }
  }
  __syncthreads();
  float2* dst = Xf + blk * NQ;
  for (int e = tid; e < NQ; e += 256) dst[e] = Xs[e];
}

// xh[bc,l,q] = sum_j qw[j]*dbeta[j,l,q]*Xf[bc,j,q]
__global__ void xh_kernel(const float2* __restrict__ Xf, const float* __restrict__ qw,
                          const float* __restrict__ dbeta, float2* __restrict__ xh) {
  int idx = blockIdx.x * blockDim.x + threadIdx.x;
  if (idx >= NBATCH * NCH * NQ) return;
  int q = idx % NQ;
  int bc = idx / NQ;
  float2 acc[LL];
  #pragma unroll
  for (int l = 0; l < LL; ++l) acc[l] = c_mk(0.f, 0.f);
  for (int j = 0; j < NB; ++j) {
    float2 xv = Xf[((long long)bc * NB + j) * NQ + q];
    float qj = qw[j];
    const float* dbase = dbeta + (long long)(j * LL) * NQ + q;
    #pragma unroll
    for (int l = 0; l < LL; ++l) {
      float w = qj * dbase[l * NQ];
      acc[l].x += w * xv.x;
      acc[l].y += w * xv.y;
    }
  }
  #pragma unroll
  for (int l = 0; l < LL; ++l) xh[((long long)bc * LL + l) * NQ + q] = acc[l];
}

// hk[bc,l,mi,ni] = sum_k xh[bc,l,mi,k] * deq[l,ni,k]
__global__ void hk_kernel(const float2* __restrict__ xh, const float* __restrict__ deq,
                          float2* __restrict__ hk) {
  int idx = blockIdx.x * blockDim.x + threadIdx.x;
  if (idx >= NBATCH * NCH * LL * NQ) return;
  int ni = idx % MM;
  int rest = idx / MM;               // (bc*LL+l)*MM + mi
  int l = (rest / MM) % LL;
  const float2* row = xh + (long long)rest * MM;
  const float* dr = deq + (l * MM + ni) * MM;
  float re = 0.f, im = 0.f;
  for (int k = 0; k < MM; ++k) {
    float d = dr[k];
    float2 v = row[k];
    re += d * v.x; im += d * v.y;
  }
  hk[idx] = c_mk(re, im);
}

// z[b,o,l,q] = sum_i hk[b,i,l,q] * conj(Wf[ni,i,o]); o in chunks of 25
__global__ void z_kernel(const float2* __restrict__ hk, const float2* __restrict__ Wf,
                         float2* __restrict__ z) {
  int idx = blockIdx.x * blockDim.x + threadIdx.x;
  if (idx >= NBATCH * LL * NQ) return;
  int q = idx % NQ;
  int t = idx / NQ;
  int l = t % LL;
  int b = t / LL;
  int ni = q % MM;
  const float2* hbase = hk + ((long long)(b * NCH) * LL + l) * NQ + q;
  for (int oc = 0; oc < 2; ++oc) {
    float2 acc[25];
    #pragma unroll
    for (int u = 0; u < 25; ++u) acc[u] = c_mk(0.f, 0.f);
    for (int i = 0; i < NCH; ++i) {
      float2 hv = hbase[(long long)i * LL * NQ];
      const float2* wrow = Wf + (ni * NCH + i) * NCH + oc * 25;
      #pragma unroll
      for (int u = 0; u < 25; ++u) {
        float2 w = wrow[u];
        acc[u].x += hv.x * w.x + hv.y * w.y;   // hv * conj(w)
        acc[u].y += hv.y * w.x - hv.x * w.y;
      }
    }
    #pragma unroll
    for (int u = 0; u < 25; ++u) {
      int o = oc * 25 + u;
      z[((long long)(b * NCH + o) * LL + l) * NQ + q] = acc[u];
    }
  }
}

// ---------------- head ----------------

__global__ void pool_kernel(const float* __restrict__ h, float* __restrict__ pooled) {
  __shared__ float sm[256];
  int tid = threadIdx.x;
  const float* base = h + (long long)blockIdx.x * SPAT;
  float best = -1e30f;
  for (int e = tid; e < 1024; e += 256) {
    float s = 0.f;
    for (int g = 0; g < NB; ++g) s += base[e * NB + g];
    best = fmaxf(best, s * (1.f / 32.f));
  }
  sm[tid] = best;
  __syncthreads();
  for (int s = 128; s > 0; s >>= 1) {
    if (tid < s) sm[tid] = fmaxf(sm[tid], sm[tid + s]);
    __syncthreads();
  }
  if (tid == 0) pooled[blockIdx.x] = sm[0];
}

__global__ __launch_bounds__(256) void head_kernel(const float* __restrict__ pooled,
    const float* __restrict__ fc1w, const float* __restrict__ fc1b,
    const float* __restrict__ g1, const float* __restrict__ b1,
    const float* __restrict__ fc2w, const float* __restrict__ fc2b,
    const float* __restrict__ g2, const float* __restrict__ b2,
    const float* __restrict__ fc3w, const float* __restrict__ fc3b,
    float* __restrict__ out) {
  __shared__ float pin[NBATCH * NCH];
  __shared__ float A[NBATCH * 256];
  __shared__ float Bm[NBATCH * 128];
  __shared__ float Cm[NBATCH * 40];
  int tid = threadIdx.x;
  for (int e = tid; e < NBATCH * NCH; e += 256) pin[e] = pooled[e];
  __syncthreads();
  {
    float v[NBATCH];
    #pragma unroll
    for (int b = 0; b < NBATCH; ++b) {
      float acc = fc1b[tid];
      for (int c = 0; c < NCH; ++c) acc += pin[b * NCH + c] * fc1w[tid * NCH + c];
      v[b] = acc;
    }
    float s = 0.f, ss = 0.f;
    #pragma unroll
    for (int b = 0; b < NBATCH; ++b) { s += v[b]; ss += v[b] * v[b]; }
    float mu = s * 0.125f, var = ss * 0.125f - mu * mu;
    float sc = g1[tid] * rsqrtf(var + 1e-5f), sh = b1[tid] - mu * sc;
    #pragma unroll
    for (int b = 0; b < NBATCH; ++b) A[b * 256 + tid] = fmaxf(v[b] * sc + sh, 0.f);
  }
  __syncthreads();
  if (tid < 128) {
    float v[NBATCH];
    #pragma unroll
    for (int b = 0; b < NBATCH; ++b) {
      float acc = fc2b[tid];
      for (int c = 0; c < 256; ++c) acc += A[b * 256 + c] * fc2w[tid * 256 + c];
      v[b] = acc;
    }
    float s = 0.f, ss = 0.f;
    #pragma unroll
    for (int b = 0; b < NBATCH; ++b) { s += v[b]; ss += v[b] * v[b]; }
    float mu = s * 0.125f, var = ss * 0.125f - mu * mu;
    float sc = g2[tid] * rsqrtf(var + 1e-5f), sh = b2[tid] - mu * sc;
    #pragma unroll
    for (int b = 0; b < NBATCH; ++b) Bm[b * 128 + tid] = fmaxf(v[b] * sc + sh, 0.f);
  }
  __syncthreads();
  if (tid < 40) {
    #pragma unroll
    for (int b = 0; b < NBATCH; ++b) {
      float acc = fc3b[tid];
      for (int c = 0; c < 128; ++c) acc += Bm[b * 128 + c] * fc3w[tid * 128 + c];
      Cm[b * 40 + tid] = acc;
    }
  }
  __syncthreads();
  if (tid < NBATCH) {
    int b = tid;
    float mx = -1e30f;
    for (int f = 0; f < 40; ++f) mx = fmaxf(mx, Cm[b * 40 + f]);
    float se = 0.f;
    for (int f = 0; f < 40; ++f) se += expf(Cm[b * 40 + f] - mx);
    float lse = mx + logf(se);
    for (int f = 0; f < 40; ++f) out[b * 40 + f] = Cm[b * 40 + f] - lse;
  }
}

// ---------------- host ----------------

extern "C" void kernel_launch(void* const* d_in, const int* in_sizes, int n_in,
                              void* d_out, int out_size, void* d_ws, size_t ws_size,
                              hipStream_t stream) {
  (void)in_sizes; (void)n_in; (void)out_size;
  const float* x    = (const float*)d_in[0];
  const float* k1   = (const float*)d_in[1];
  const float* c1b  = (const float*)d_in[2];
  const float* bn1g = (const float*)d_in[3];
  const float* bn1b = (const float*)d_in[4];
  const float* k2   = (const float*)d_in[5];
  const float* c2b  = (const float*)d_in[6];
  const float* bn2g = (const float*)d_in[7];
  const float* bn2b = (const float*)d_in[8];
  const float* k3   = (const float*)d_in[9];
  const float* c3b  = (const float*)d_in[10];
  const float* bn3g = (const float*)d_in[11];
  const float* bn3b = (const float*)d_in[12];
  const float* fc1w = (const float*)d_in[13];
  const float* fc1b = (const float*)d_in[14];
  const float* g1   = (const float*)d_in[15];
  const float* bb1  = (const float*)d_in[16];
  const float* fc2w = (const float*)d_in[17];
  const float* fc2b = (const float*)d_in[18];
  const float* g2   = (const float*)d_in[19];
  const float* bb2  = (const float*)d_in[20];
  const float* fc3w = (const float*)d_in[21];
  const float* fc3b = (const float*)d_in[22];
  float* out = (float*)d_out;

  char* ws = (char*)d_ws;
  size_t off = 0;
  auto alloc = [&](size_t n) -> char* {
    char* p = ws + off;
    off += (n + 255) & ~(size_t)255;
    return p;
  };

  float*  dbeta  = (float*)alloc(sizeof(float) * NB * LL * NQ);      // 1.97 MB
  float*  deq    = (float*)alloc(sizeof(float) * LL * NQ);
  float*  qw     = (float*)alloc(sizeof(float) * NB);
  float2* xh1    = (float2*)alloc(sizeof(float2) * NBATCH * LL * MM);
  float2* Wf     = (float2*)alloc(sizeof(float2) * MM * NCH * NCH);  // 620 KB
  float2* parts  = (float2*)alloc(sizeof(float2) * NBATCH * NCH);
  float2* bnsc   = (float2*)alloc(sizeof(float2) * 64);
  float*  pooled = (float*)alloc(sizeof(float) * NBATCH * NCH);
  float*  HA     = (float*)alloc(sizeof(float) * (size_t)HN);        // 52.4 MB
  float*  HB     = (float*)alloc(sizeof(float) * (size_t)HN);        // 52.4 MB
  size_t XFB = (size_t)NBATCH * NCH * NB * NQ * sizeof(float2);      // 98.4 MB
  size_t XHB = (size_t)NBATCH * NCH * LL * NQ * sizeof(float2);      // 49.2 MB
  char* AR = alloc(XFB + XHB);                                       // 147.6 MB arena
  float2* Xf = (float2*)AR;            // live: dft2 -> xh
  float2* xh = (float2*)(AR + XFB);    // live: xh -> hk
  float2* hk = (float2*)AR;            // live: hk -> z   (reuses dead Xf)
  float2* zb = (float2*)(AR + XFB);    // live: z  -> ifft (reuses dead xh; also z1)

  if (ws_size < off) return;  // insufficient scratch: leave d_out zeroed (clean failure)

  const int T = 256;
  // constants
  qw_kernel<<<1, 32, 0, stream>>>(qw);
  wigner_kernel<<<(NB * LL * NQ + T - 1) / T, T, 0, stream>>>(dbeta, NB, 0);
  wigner_kernel<<<(LL * NQ + T - 1) / T, T, 0, stream>>>(deq, 1, 1);

  // ---- layer 1: S2 conv -> HA
  s2_xh_kernel<<<NBATCH, T, 0, stream>>>(x, qw, dbeta, xh1);
  wfft_kernel<<<(MM * 1 * NCH + T - 1) / T, T, 0, stream>>>(k1, 1 * NCH, Wf);
  s2_z_kernel<<<(NBATCH * NCH * LL * NQ + T - 1) / T, T, 0, stream>>>(xh1, Wf, deq, zb);
  so3_ifft2_kernel<<<NBATCH * NCH * NB, T, 0, stream>>>(zb, dbeta, c1b, HA);
  bn_stats_kernel<<<NBATCH * NCH, T, 0, stream>>>(HA, parts);
  bn_finalize_kernel<<<1, 64, 0, stream>>>(parts, bn1g, bn1b, bnsc);
  bn_apply_relu_kernel<<<(int)(HN / 4 / T), T, 0, stream>>>(HA, bnsc);

  // ---- layer 2: SO(3) conv HA -> HB
  dft2b_kernel<<<NBATCH * NCH * NB, T, 0, stream>>>(HA, Xf);
  xh_kernel<<<(NBATCH * NCH * NQ + T - 1) / T, T, 0, stream>>>(Xf, qw, dbeta, xh);
  wfft_kernel<<<(MM * NCH * NCH + T - 1) / T, T, 0, stream>>>(k2, NCH * NCH, Wf);
  hk_kernel<<<(NBATCH * NCH * LL * NQ + T - 1) / T, T, 0, stream>>>(xh, deq, hk);
  z_kernel<<<(NBATCH * LL * NQ + T - 1) / T, T, 0, stream>>>(hk, Wf, zb);
  so3_ifft2_kernel<<<NBATCH * NCH * NB, T, 0, stream>>>(zb, dbeta, c2b, HB);
  bn_stats_kernel<<<NBATCH * NCH, T, 0, stream>>>(HB, parts);
  bn_finalize_kernel<<<1, 64, 0, stream>>>(parts, bn2g, bn2b, bnsc);
  bn_apply_relu_kernel<<<(int)(HN / 4 / T), T, 0, stream>>>(HB, bnsc);

  // ---- layer 3: SO(3) conv HB -> HA
  dft2b_kernel<<<NBATCH * NCH * NB, T, 0, stream>>>(HB, Xf);
  xh_kernel<<<(NBATCH * NCH * NQ + T - 1) / T, T, 0, stream>>>(Xf, qw, dbeta, xh);
  wfft_kernel<<<(MM * NCH * NCH + T - 1) / T, T, 0, stream>>>(k3, NCH * NCH, Wf);
  hk_kernel<<<(NBATCH * NCH * LL * NQ + T - 1) / T, T, 0, stream>>>(xh, deq, hk);
  z_kernel<<<(NBATCH * LL * NQ + T - 1) / T, T, 0, stream>>>(hk, Wf, zb);
  so3_ifft2_kernel<<<NBATCH * NCH * NB, T, 0, stream>>>(zb, dbeta, c3b, HA);
  bn_stats_kernel<<<NBATCH * NCH, T, 0, stream>>>(HA, parts);
  bn_finalize_kernel<<<1, 64, 0, stream>>>(parts, bn3g, bn3b, bnsc);
  bn_apply_relu_kernel<<<(int)(HN / 4 / T), T, 0, stream>>>(HA, bnsc);

  // ---- head
  pool_kernel<<<NBATCH * NCH, T, 0, stream>>>(HA, pooled);
  head_kernel<<<1, T, 0, stream>>>(pooled, fc1w, fc1b, g1, bb1,
                                   fc2w, fc2b, g2, bb2, fc3w, fc3b, out);
}

// Round 3
// 1699.019 us; speedup vs baseline: 1.8673x; 1.0264x over previous
//
#include <hip/hip_runtime.h>
#include <math.h>

constexpr int NB = 32;       // samples per angle
constexpr int LL = 16;       // bandwidth
constexpr int MM = 31;       // spectral orders (2*BW-1)
constexpr int MOFF = 15;
constexpr int NBATCH = 8;
constexpr int NCH = 50;
constexpr int NQ = MM * MM;          // 961
constexpr int SPAT = NB * NB * NB;   // 32768
constexpr long long HN = (long long)NBATCH * NCH * SPAT;  // 13,107,200

#define PI_D 3.14159265358979323846

__device__ inline float2 c_mk(float x, float y) { float2 r; r.x = x; r.y = y; return r; }

__device__ inline void fill_tw(float2* tw) {
  int t = threadIdx.x;
  if (t < 32) {
    double a = (double)t * (PI_D / 16.0);
    tw[t] = c_mk((float)cos(a), (float)sin(a));
  }
}

__device__ inline double dpow(double x, int n) {
  double r = 1.0;
  for (int i = 0; i < n; ++i) r *= x;
  return r;
}

// ---------------- constants ----------------

__global__ void qw_kernel(float* __restrict__ qw) {
  int j = threadIdx.x;
  if (j >= NB) return;
  double beta = PI_D * (2 * j + 1) / 64.0;
  double acc = 0.0;
  for (int kk = 0; kk < LL; ++kk)
    acc += sin((double)(2 * j + 1) * (2 * kk + 1) * PI_D / 64.0) / (double)(2 * kk + 1);
  qw[j] = (float)((2.0 / 16.0) * sin(beta) * acc);
}

// out layout [j][l][mp][m]; eqmode: nj==1, beta=pi/2
__global__ void wigner_kernel(float* __restrict__ out, int nj, int eqmode) {
  __shared__ double fact[66];
  int tid = threadIdx.x;
  if (tid < 66) { double f = 1.0; for (int i = 2; i <= tid; ++i) f *= (double)i; fact[tid] = f; }
  __syncthreads();
  int total = nj * LL * NQ;
  int idx = blockIdx.x * blockDim.x + tid;
  if (idx >= total) return;
  int q = idx % NQ;
  int l = (idx / NQ) % LL;
  int j = idx / (NQ * LL);
  int mp = q / MM - MOFF;
  int m  = q % MM - MOFF;
  int amp = mp < 0 ? -mp : mp, am = m < 0 ? -m : m;
  float res = 0.f;
  if (amp <= l && am <= l) {
    double beta = eqmode ? (PI_D * 0.5) : (PI_D * (2 * j + 1) / 64.0);
    double c = cos(beta * 0.5), s = sin(beta * 0.5);
    double pref = sqrt(fact[l + mp] * fact[l - mp] * fact[l + m] * fact[l - m]);
    int k0 = max(0, m - mp), k1 = min(l + m, l - mp);
    double acc = 0.0;
    for (int k = k0; k <= k1; ++k) {
      double denom = fact[l + m - k] * fact[k] * fact[l - k - mp] * fact[k - m + mp];
      double term = dpow(c, 2 * l - 2 * k + m - mp) * dpow(s, 2 * k - m + mp) / denom;
      acc += ((mp - m + k) & 1) ? -term : term;
    }
    res = (float)(pref * acc);
  }
  out[idx] = res;
}

// dbT[j][l][n][m] = dbeta[j][l][m][n]
__global__ void transpose_d_kernel(const float* __restrict__ dbeta, float* __restrict__ dbT) {
  int idx = blockIdx.x * blockDim.x + threadIdx.x;
  if (idx >= NB * LL * NQ) return;
  int m = idx % MM;
  int n = (idx / MM) % MM;
  int jl = idx / NQ;
  dbT[idx] = dbeta[jl * NQ + m * MM + n];
}

// ---------------- layer 1 (S2 conv) ----------------

__global__ __launch_bounds__(256) void s2_xh_kernel(const float* __restrict__ x,
                                                    const float* __restrict__ qw,
                                                    const float* __restrict__ dbeta,
                                                    float2* __restrict__ xh1) {
  __shared__ float xt[NB * NB];
  __shared__ float2 Xf0[NB * MM];
  __shared__ float2 tw[32];
  fill_tw(tw);
  int tid = threadIdx.x, b = blockIdx.x;
  for (int e = tid; e < NB * NB; e += 256) xt[e] = x[b * 1024 + e];
  __syncthreads();
  for (int e = tid; e < NB * MM; e += 256) {
    int j = e / MM, mi = e % MM, m = mi - MOFF;
    float re = 0.f, im = 0.f;
    const float* row = xt + j * NB;
    for (int a = 0; a < NB; ++a) {
      float v = row[a];
      float2 t = tw[(m * a) & 31];
      re += v * t.x; im -= v * t.y;   // e^{-i m a th}
    }
    Xf0[e] = c_mk(re, im);
  }
  __syncthreads();
  for (int e = tid; e < LL * MM; e += 256) {
    int l = e / MM, mi = e % MM;
    float re = 0.f, im = 0.f;
    for (int j = 0; j < NB; ++j) {
      float w = qw[j] * dbeta[(j * LL + l) * NQ + mi * MM + MOFF];
      float2 X = Xf0[j * MM + mi];
      re += w * X.x; im += w * X.y;
    }
    xh1[(b * LL + l) * MM + mi] = c_mk(re, im);
  }
}

// Wf[ni][ic] = sum_t W[ic][t] e^{-2pi i n t/32}, ic = i*Co+o
__global__ __launch_bounds__(256) void wfft_kernel(const float* __restrict__ W, int CiCo,
                                                   float2* __restrict__ Wf) {
  __shared__ float2 tw[32];
  fill_tw(tw);
  __syncthreads();
  int idx = blockIdx.x * blockDim.x + threadIdx.x;
  if (idx >= MM * CiCo) return;
  int ni = idx / CiCo, ic = idx % CiCo;
  int n = ni - MOFF;
  float re = 0.f, im = 0.f;
  for (int t = 0; t < NB; ++t) {
    float v = W[ic * NB + t];
    float2 tt = tw[(n * t) & 31];
    re += v * tt.x; im -= v * tt.y;
  }
  Wf[idx] = c_mk(re, im);
}

// z layout: [b][o][l][ni][mi].  z = deq0[l,ni] * xh1[b,l,mi] * conj(Wf1[ni,o])
__global__ void s2_z_kernel(const float2* __restrict__ xh1, const float2* __restrict__ Wf1,
                            const float* __restrict__ deq, float2* __restrict__ z) {
  int idx = blockIdx.x * blockDim.x + threadIdx.x;
  if (idx >= NBATCH * NCH * LL * NQ) return;
  int mi = idx % MM; int t = idx / MM;
  int ni = t % MM; t /= MM;
  int l = t % LL; t /= LL;
  int o = t % NCH; int b = t / NCH;
  float d0 = deq[(l * MM + ni) * MM + MOFF];
  float2 xv = xh1[(b * LL + l) * MM + mi];
  float2 wv = Wf1[ni * NCH + o];
  float re = d0 * (xv.x * wv.x + xv.y * wv.y);
  float im = d0 * (xv.y * wv.x - xv.x * wv.y);
  z[idx] = c_mk(re, im);
}

// ---------------- shared: SO(3) inverse transform ----------------
// One block per (bo, j).  z and dbT are in [n][m] inner layout.
__global__ __launch_bounds__(256) void so3_ifft2_kernel(const float2* __restrict__ z,
                                                        const float* __restrict__ dbT,
                                                        const float* __restrict__ bias,
                                                        float* __restrict__ out) {
  __shared__ float2 Fq[NQ];       // [ni][mi], 7.7 KB
  __shared__ float2 G[MM * NB];   // [m][g], 7.9 KB
  __shared__ float2 tw[32];
  fill_tw(tw);
  int tid = threadIdx.x;
  int blk = blockIdx.x;
  // bijective XCD swizzle (12800 % 8 == 0)
  blk = (blk & 7) * 1600 + (blk >> 3);
  int j = blk & 31;
  int bo = blk >> 5;
  int o = bo % NCH;

  // F[n,m] = sum_l (2l+1) * d^l_{m,n}(beta_j) * z(bo,l,n,m)
  for (int e = tid; e < NQ; e += 256) {
    float fr = 0.f, fi = 0.f;
    const float* dptr = dbT + (j * LL) * NQ + e;
    const float2* zptr = z + (long long)bo * LL * NQ + e;
    #pragma unroll
    for (int l = 0; l < LL; ++l) {
      float w = (2.f * l + 1.f) * dptr[l * NQ];
      float2 zv = zptr[l * NQ];
      fr += w * zv.x; fi += w * zv.y;
    }
    Fq[e] = c_mk(fr, fi);
  }
  __syncthreads();

  // G[m,g] = sum_ni F[ni,m] e^{i(ni-15) g th}; g and g+16 together.
  for (int e = tid; e < MM * 16; e += 256) {
    int m = e >> 4, g = e & 15;
    float aex = 0.f, aey = 0.f, aox = 0.f, aoy = 0.f;
    #pragma unroll
    for (int p = 0; p < 15; ++p) {
      int ni = 2 * p;
      float2 f = Fq[ni * MM + m];
      float2 t = tw[((ni - 15) * g) & 31];
      aex += f.x * t.x - f.y * t.y;
      aey += f.x * t.y + f.y * t.x;
      float2 f2 = Fq[(ni + 1) * MM + m];
      float2 t2 = tw[((ni - 14) * g) & 31];
      aox += f2.x * t2.x - f2.y * t2.y;
      aoy += f2.x * t2.y + f2.y * t2.x;
    }
    { // ni = 30 (even)
      float2 f = Fq[30 * MM + m];
      float2 t = tw[(15 * g) & 31];
      aex += f.x * t.x - f.y * t.y;
      aey += f.x * t.y + f.y * t.x;
    }
    G[m * NB + g]      = c_mk(aex + aox, aey + aoy);
    G[m * NB + g + 16] = c_mk(aox - aex, aoy - aey);
  }
  __syncthreads();

  // out[a,g] = bias + Re sum_mi G[mi,g] e^{i(mi-15) a th}; a and a+16 together.
  float bval = bias[o];
  long long obase = (long long)bo * SPAT + (long long)j * 1024;
  for (int e = tid; e < 16 * NB; e += 256) {
    int a = e >> 5, g = e & 31;
    float be = 0.f, bo_ = 0.f;
    #pragma unroll
    for (int p = 0; p < 15; ++p) {
      int mi = 2 * p;
      float2 gv = G[mi * NB + g];
      float2 t = tw[((mi - 15) * a) & 31];
      be += gv.x * t.x - gv.y * t.y;
      float2 gv2 = G[(mi + 1) * NB + g];
      float2 t2 = tw[((mi - 14) * a) & 31];
      bo_ += gv2.x * t2.x - gv2.y * t2.y;
    }
    { // mi = 30 (even)
      float2 gv = G[30 * NB + g];
      float2 t = tw[(15 * a) & 31];
      be += gv.x * t.x - gv.y * t.y;
    }
    out[obase + a * 32 + g]        = bval + be + bo_;
    out[obase + (a + 16) * 32 + g] = bval + bo_ - be;
  }
}

// ---------------- batchnorm ----------------

__global__ void bn_stats_kernel(const float* __restrict__ h, float2* __restrict__ partials) {
  __shared__ float s1[256], s2[256];
  int tid = threadIdx.x;
  long long base = (long long)blockIdx.x * SPAT;
  float a1 = 0.f, a2 = 0.f;
  for (int e = tid; e < SPAT; e += 256) { float v = h[base + e]; a1 += v; a2 += v * v; }
  s1[tid] = a1; s2[tid] = a2;
  __syncthreads();
  for (int s = 128; s > 0; s >>= 1) {
    if (tid < s) { s1[tid] += s1[tid + s]; s2[tid] += s2[tid + s]; }
    __syncthreads();
  }
  if (tid == 0) partials[blockIdx.x] = c_mk(s1[0], s2[0]);
}

__global__ void bn_finalize_kernel(const float2* __restrict__ partials,
                                   const float* __restrict__ g, const float* __restrict__ bb,
                                   float2* __restrict__ sc) {
  int o = threadIdx.x;
  if (o >= NCH) return;
  float s = 0.f, ss = 0.f;
  for (int b = 0; b < NBATCH; ++b) { float2 p = partials[b * NCH + o]; s += p.x; ss += p.y; }
  float inv = 1.f / (float)(NBATCH * SPAT);
  float mu = s * inv;
  float var = ss * inv - mu * mu;
  float scale = g[o] * rsqrtf(var + 1e-5f);
  sc[o] = c_mk(scale, bb[o] - mu * scale);
}

__global__ void bn_apply_relu_kernel(float* __restrict__ h, const float2* __restrict__ sc) {
  long long gid = ((long long)blockIdx.x * blockDim.x + threadIdx.x) * 4;
  if (gid >= HN) return;
  int ch = (int)((gid >> 15) % NCH);
  float2 s = sc[ch];
  float4 v = *reinterpret_cast<const float4*>(h + gid);
  v.x = fmaxf(v.x * s.x + s.y, 0.f);
  v.y = fmaxf(v.y * s.x + s.y, 0.f);
  v.z = fmaxf(v.z * s.x + s.y, 0.f);
  v.w = fmaxf(v.w * s.x + s.y, 0.f);
  *reinterpret_cast<float4*>(h + gid) = v;
}

// ---------------- SO(3) conv ----------------

// 2D DFT of a real 32x32 tile -> 31x31 signed-order spectrum.
__global__ __launch_bounds__(256) void dft2b_kernel(const float* __restrict__ h,
                                                    float2* __restrict__ Xf) {
  __shared__ float xt[32 * 33];   // padded stride kills bank conflict
  __shared__ float2 P[32 * 16];   // [a][n], n = 0..15
  __shared__ float2 Xs[NQ];
  __shared__ float2 tw[32];
  fill_tw(tw);
  int tid = threadIdx.x;
  long long blk = blockIdx.x;
  const float* src = h + blk * 1024;
  for (int e = tid; e < 1024; e += 256) xt[(e >> 5) * 33 + (e & 31)] = src[e];
  __syncthreads();
  // P[a,n] = sum_g x[a,g] e^{-i n g th}
  for (int e = tid; e < 512; e += 256) {
    int a = e >> 4, n = e & 15;
    float re = 0.f, im = 0.f;
    const float* row = xt + a * 33;
    #pragma unroll
    for (int g = 0; g < 32; ++g) {
      float v = row[g];
      float2 t = tw[(n * g) & 31];
      re += v * t.x; im -= v * t.y;
    }
    P[a * 16 + n] = c_mk(re, im);
  }
  __syncthreads();
  // X[m,n] = sum_a P[a,n] e^{-i m a th}; m=+mh and m=-mh together.
  {
    int e = tid;
    if (e < 256) {
      int mh = e >> 4, n = e & 15;
      float sxx = 0.f, sxy = 0.f, syx = 0.f, syy = 0.f;
      #pragma unroll
      for (int a = 0; a < 32; ++a) {
        float2 p = P[a * 16 + n];
        float2 t = tw[(mh * a) & 31];
        sxx += p.x * t.x; sxy += p.x * t.y;
        syx += p.y * t.x; syy += p.y * t.y;
      }
      float2 Xp = c_mk(sxx + syy, syx - sxy);   // X[+mh, n]
      float2 Xm = c_mk(sxx - syy, syx + sxy);   // X[-mh, n]
      Xs[(mh + MOFF) * MM + (n + MOFF)] = Xp;
      Xs[(MOFF - mh) * MM + (n + MOFF)] = Xm;
      Xs[(MOFF - mh) * MM + (MOFF - n)] = c_mk(Xp.x, -Xp.y);
      Xs[(mh + MOFF) * MM + (MOFF - n)] = c_mk(Xm.x, -Xm.y);
    }
  }
  __syncthreads();
  float2* dst = Xf + blk * NQ;
  for (int e = tid; e < NQ; e += 256) dst[e] = Xs[e];
}

// xh[bc,l,q] = sum_j qw[j]*dbeta[j,l,q]*Xf[bc,j,q]   (q = mi*MM+ni)
__global__ void xh_kernel(const float2* __restrict__ Xf, const float* __restrict__ qw,
                          const float* __restrict__ dbeta, float2* __restrict__ xh) {
  int idx = blockIdx.x * blockDim.x + threadIdx.x;
  if (idx >= NBATCH * NCH * NQ) return;
  int q = idx % NQ;
  int bc = idx / NQ;
  float2 acc[LL];
  #pragma unroll
  for (int l = 0; l < LL; ++l) acc[l] = c_mk(0.f, 0.f);
  for (int j = 0; j < NB; ++j) {
    float2 xv = Xf[((long long)bc * NB + j) * NQ + q];
    float qj = qw[j];
    const float* dbase = dbeta + (long long)(j * LL) * NQ + q;
    #pragma unroll
    for (int l = 0; l < LL; ++l) {
      float w = qj * dbase[l * NQ];
      acc[l].x += w * xv.x;
      acc[l].y += w * xv.y;
    }
  }
  #pragma unroll
  for (int l = 0; l < LL; ++l) xh[((long long)bc * LL + l) * NQ + q] = acc[l];
}

// hk2[b][l][mi][ni][ich] = sum_k xh[(b*50+ich),l,mi,k] * deq[l,ni,k]
__global__ void hk_kernel(const float2* __restrict__ xh, const float* __restrict__ deq,
                          float2* __restrict__ hk2) {
  int idx = blockIdx.x * blockDim.x + threadIdx.x;
  // total = 8*16*31*31*50 = 6,150,400
  int ich = idx % NCH; int t = idx / NCH;
  int ni = t % MM; t /= MM;
  int mi = t % MM; t /= MM;
  int l = t % LL; int b = t / LL;
  const float2* row = xh + ((long long)((b * NCH + ich) * LL + l)) * NQ + mi * MM;
  const float* dr = deq + (l * MM + ni) * MM;
  float re = 0.f, im = 0.f;
  #pragma unroll
  for (int k = 0; k < MM; ++k) {
    float d = dr[k];
    float2 v = row[k];
    re += d * v.x; im += d * v.y;
  }
  hk2[idx] = c_mk(re, im);
}

// z[b][o][l][ni][mi] = sum_i hk2[(r*31+ni)*50+i] * conj(Wf[ni,i,o]), r=(b,l,mi)
// block = (ni, rowtile of 128 rows); tid: row_local = tid&127, ohalf = tid>>7
__global__ __launch_bounds__(256) void z_kernel(const float2* __restrict__ hk2,
                                                const float2* __restrict__ Wf,
                                                float2* __restrict__ z) {
  int ni = blockIdx.x / MM;          // 0..30
  int rowtile = blockIdx.x % MM;     // 0..30
  int tid = threadIdx.x;
  int r = rowtile * 128 + (tid & 127);   // 0..3967 = (b,l,mi)
  int o0 = (tid >> 7) * 25;
  int b = r / (LL * MM);
  int rem = r % (LL * MM);
  int l = rem / MM;
  int mi = rem % MM;

  const float4* h4 = reinterpret_cast<const float4*>(hk2 + ((long long)r * MM + ni) * NCH);
  const float2* wbase = Wf + ni * (NCH * NCH) + o0;

  float2 acc[25];
  #pragma unroll
  for (int u = 0; u < 25; ++u) acc[u] = c_mk(0.f, 0.f);

  for (int ih = 0; ih < 25; ++ih) {     // 2 channels per iteration
    float4 hv = h4[ih];
    const float2* w0 = wbase + (2 * ih) * NCH;
    #pragma unroll
    for (int u = 0; u < 25; ++u) {
      float2 w = w0[u];
      acc[u].x += hv.x * w.x + hv.y * w.y;
      acc[u].y += hv.y * w.x - hv.x * w.y;
    }
    const float2* w1 = w0 + NCH;
    #pragma unroll
    for (int u = 0; u < 25; ++u) {
      float2 w = w1[u];
      acc[u].x += hv.z * w.x + hv.w * w.y;
      acc[u].y += hv.w * w.x - hv.z * w.y;
    }
  }

  long long zb = (((long long)(b * NCH + o0) * LL + l) * NQ) + ni * MM + mi;
  #pragma unroll
  for (int u = 0; u < 25; ++u)
    z[zb + (long long)u * LL * NQ] = acc[u];
}

// ---------------- head ----------------

__global__ void pool_kernel(const float* __restrict__ h, float* __restrict__ pooled) {
  __shared__ float sm[256];
  int tid = threadIdx.x;
  const float* base = h + (long long)blockIdx.x * SPAT;
  float best = -1e30f;
  for (int e = tid; e < 1024; e += 256) {
    float s = 0.f;
    for (int g = 0; g < NB; ++g) s += base[e * NB + g];
    best = fmaxf(best, s * (1.f / 32.f));
  }
  sm[tid] = best;
  __syncthreads();
  for (int s = 128; s > 0; s >>= 1) {
    if (tid < s) sm[tid] = fmaxf(sm[tid], sm[tid + s]);
    __syncthreads();
  }
  if (tid == 0) pooled[blockIdx.x] = sm[0];
}

__global__ __launch_bounds__(256) void head_kernel(const float* __restrict__ pooled,
    const float* __restrict__ fc1w, const float* __restrict__ fc1b,
    const float* __restrict__ g1, const float* __restrict__ b1,
    const float* __restrict__ fc2w, const float* __restrict__ fc2b,
    const float* __restrict__ g2, const float* __restrict__ b2,
    const float* __restrict__ fc3w, const float* __restrict__ fc3b,
    float* __restrict__ out) {
  __shared__ float pin[NBATCH * NCH];
  __shared__ float A[NBATCH * 256];
  __shared__ float Bm[NBATCH * 128];
  __shared__ float Cm[NBATCH * 40];
  int tid = threadIdx.x;
  for (int e = tid; e < NBATCH * NCH; e += 256) pin[e] = pooled[e];
  __syncthreads();
  {
    float v[NBATCH];
    #pragma unroll
    for (int b = 0; b < NBATCH; ++b) {
      float acc = fc1b[tid];
      for (int c = 0; c < NCH; ++c) acc += pin[b * NCH + c] * fc1w[tid * NCH + c];
      v[b] = acc;
    }
    float s = 0.f, ss = 0.f;
    #pragma unroll
    for (int b = 0; b < NBATCH; ++b) { s += v[b]; ss += v[b] * v[b]; }
    float mu = s * 0.125f, var = ss * 0.125f - mu * mu;
    float sc = g1[tid] * rsqrtf(var + 1e-5f), sh = b1[tid] - mu * sc;
    #pragma unroll
    for (int b = 0; b < NBATCH; ++b) A[b * 256 + tid] = fmaxf(v[b] * sc + sh, 0.f);
  }
  __syncthreads();
  if (tid < 128) {
    float v[NBATCH];
    #pragma unroll
    for (int b = 0; b < NBATCH; ++b) {
      float acc = fc2b[tid];
      for (int c = 0; c < 256; ++c) acc += A[b * 256 + c] * fc2w[tid * 256 + c];
      v[b] = acc;
    }
    float s = 0.f, ss = 0.f;
    #pragma unroll
    for (int b = 0; b < NBATCH; ++b) { s += v[b]; ss += v[b] * v[b]; }
    float mu = s * 0.125f, var = ss * 0.125f - mu * mu;
    float sc = g2[tid] * rsqrtf(var + 1e-5f), sh = b2[tid] - mu * sc;
    #pragma unroll
    for (int b = 0; b < NBATCH; ++b) Bm[b * 128 + tid] = fmaxf(v[b] * sc + sh, 0.f);
  }
  __syncthreads();
  if (tid < 40) {
    #pragma unroll
    for (int b = 0; b < NBATCH; ++b) {
      float acc = fc3b[tid];
      for (int c = 0; c < 128; ++c) acc += Bm[b * 128 + c] * fc3w[tid * 128 + c];
      Cm[b * 40 + tid] = acc;
    }
  }
  __syncthreads();
  if (tid < NBATCH) {
    int b = tid;
    float mx = -1e30f;
    for (int f = 0; f < 40; ++f) mx = fmaxf(mx, Cm[b * 40 + f]);
    float se = 0.f;
    for (int f = 0; f < 40; ++f) se += expf(Cm[b * 40 + f] - mx);
    float lse = mx + logf(se);
    for (int f = 0; f < 40; ++f) out[b * 40 + f] = Cm[b * 40 + f] - lse;
  }
}

// ---------------- host ----------------

extern "C" void kernel_launch(void* const* d_in, const int* in_sizes, int n_in,
                              void* d_out, int out_size, void* d_ws, size_t ws_size,
                              hipStream_t stream) {
  (void)in_sizes; (void)n_in; (void)out_size;
  const float* x    = (const float*)d_in[0];
  const float* k1   = (const float*)d_in[1];
  const float* c1b  = (const float*)d_in[2];
  const float* bn1g = (const float*)d_in[3];
  const float* bn1b = (const float*)d_in[4];
  const float* k2   = (const float*)d_in[5];
  const float* c2b  = (const float*)d_in[6];
  const float* bn2g = (const float*)d_in[7];
  const float* bn2b = (const float*)d_in[8];
  const float* k3   = (const float*)d_in[9];
  const float* c3b  = (const float*)d_in[10];
  const float* bn3g = (const float*)d_in[11];
  const float* bn3b = (const float*)d_in[12];
  const float* fc1w = (const float*)d_in[13];
  const float* fc1b = (const float*)d_in[14];
  const float* g1   = (const float*)d_in[15];
  const float* bb1  = (const float*)d_in[16];
  const float* fc2w = (const float*)d_in[17];
  const float* fc2b = (const float*)d_in[18];
  const float* g2   = (const float*)d_in[19];
  const float* bb2  = (const float*)d_in[20];
  const float* fc3w = (const float*)d_in[21];
  const float* fc3b = (const float*)d_in[22];
  float* out = (float*)d_out;

  char* ws = (char*)d_ws;
  size_t off = 0;
  auto alloc = [&](size_t n) -> char* {
    char* p = ws + off;
    off += (n + 255) & ~(size_t)255;
    return p;
  };

  float*  dbeta  = (float*)alloc(sizeof(float) * NB * LL * NQ);      // 1.97 MB
  float*  dbT    = (float*)alloc(sizeof(float) * NB * LL * NQ);      // 1.97 MB
  float*  deq    = (float*)alloc(sizeof(float) * LL * NQ);
  float*  qw     = (float*)alloc(sizeof(float) * NB);
  float2* xh1    = (float2*)alloc(sizeof(float2) * NBATCH * LL * MM);
  float2* Wf     = (float2*)alloc(sizeof(float2) * MM * NCH * NCH);  // 620 KB
  float2* parts  = (float2*)alloc(sizeof(float2) * NBATCH * NCH);
  float2* bnsc   = (float2*)alloc(sizeof(float2) * 64);
  float*  pooled = (float*)alloc(sizeof(float) * NBATCH * NCH);
  float*  HA     = (float*)alloc(sizeof(float) * (size_t)HN);        // 52.4 MB
  float*  HB     = (float*)alloc(sizeof(float) * (size_t)HN);        // 52.4 MB
  size_t XFB = (size_t)NBATCH * NCH * NB * NQ * sizeof(float2);      // 98.4 MB
  size_t XHB = (size_t)NBATCH * NCH * LL * NQ * sizeof(float2);      // 49.2 MB
  char* AR = alloc(XFB + XHB);                                       // 147.6 MB arena
  float2* Xf = (float2*)AR;            // live: dft2 -> xh
  float2* xh = (float2*)(AR + XFB);    // live: xh -> hk
  float2* hk2 = (float2*)AR;           // live: hk -> z   (reuses dead Xf)
  float2* zb = (float2*)(AR + XFB);    // live: z  -> ifft (reuses dead xh; also z1)

  if (ws_size < off) return;  // insufficient scratch: leave d_out zeroed

  const int T = 256;
  // constants
  qw_kernel<<<1, 32, 0, stream>>>(qw);
  wigner_kernel<<<(NB * LL * NQ + T - 1) / T, T, 0, stream>>>(dbeta, NB, 0);
  wigner_kernel<<<(LL * NQ + T - 1) / T, T, 0, stream>>>(deq, 1, 1);
  transpose_d_kernel<<<(NB * LL * NQ + T - 1) / T, T, 0, stream>>>(dbeta, dbT);

  // ---- layer 1: S2 conv -> HA
  s2_xh_kernel<<<NBATCH, T, 0, stream>>>(x, qw, dbeta, xh1);
  wfft_kernel<<<(MM * 1 * NCH + T - 1) / T, T, 0, stream>>>(k1, 1 * NCH, Wf);
  s2_z_kernel<<<(NBATCH * NCH * LL * NQ + T - 1) / T, T, 0, stream>>>(xh1, Wf, deq, zb);
  so3_ifft2_kernel<<<NBATCH * NCH * NB, T, 0, stream>>>(zb, dbT, c1b, HA);
  bn_stats_kernel<<<NBATCH * NCH, T, 0, stream>>>(HA, parts);
  bn_finalize_kernel<<<1, 64, 0, stream>>>(parts, bn1g, bn1b, bnsc);
  bn_apply_relu_kernel<<<(int)(HN / 4 / T), T, 0, stream>>>(HA, bnsc);

  // ---- layer 2: SO(3) conv HA -> HB
  dft2b_kernel<<<NBATCH * NCH * NB, T, 0, stream>>>(HA, Xf);
  xh_kernel<<<(NBATCH * NCH * NQ + T - 1) / T, T, 0, stream>>>(Xf, qw, dbeta, xh);
  wfft_kernel<<<(MM * NCH * NCH + T - 1) / T, T, 0, stream>>>(k2, NCH * NCH, Wf);
  hk_kernel<<<(NBATCH * LL * MM * MM * NCH) / T, T, 0, stream>>>(xh, deq, hk2);
  z_kernel<<<MM * MM, T, 0, stream>>>(hk2, Wf, zb);
  so3_ifft2_kernel<<<NBATCH * NCH * NB, T, 0, stream>>>(zb, dbT, c2b, HB);
  bn_stats_kernel<<<NBATCH * NCH, T, 0, stream>>>(HB, parts);
  bn_finalize_kernel<<<1, 64, 0, stream>>>(parts, bn2g, bn2b, bnsc);
  bn_apply_relu_kernel<<<(int)(HN / 4 / T), T, 0, stream>>>(HB, bnsc);

  // ---- layer 3: SO(3) conv HB -> HA
  dft2b_kernel<<<NBATCH * NCH * NB, T, 0, stream>>>(HB, Xf);
  xh_kernel<<<(NBATCH * NCH * NQ + T - 1) / T, T, 0, stream>>>(Xf, qw, dbeta, xh);
  wfft_kernel<<<(MM * NCH * NCH + T - 1) / T, T, 0, stream>>>(k3, NCH * NCH, Wf);
  hk_kernel<<<(NBATCH * LL * MM * MM * NCH) / T, T, 0, stream>>>(xh, deq, hk2);
  z_kernel<<<MM * MM, T, 0, stream>>>(hk2, Wf, zb);
  so3_ifft2_kernel<<<NBATCH * NCH * NB, T, 0, stream>>>(zb, dbT, c3b, HA);
  bn_stats_kernel<<<NBATCH * NCH, T, 0, stream>>>(HA, parts);
  bn_finalize_kernel<<<1, 64, 0, stream>>>(parts, bn3g, bn3b, bnsc);
  bn_apply_relu_kernel<<<(int)(HN / 4 / T), T, 0, stream>>>(HA, bnsc);

  // ---- head
  pool_kernel<<<NBATCH * NCH, T, 0, stream>>>(HA, pooled);
  head_kernel<<<1, T, 0, stream>>>(pooled, fc1w, fc1b, g1, bb1,
                                   fc2w, fc2b, g2, bb2, fc3w, fc3b, out);
}

// Round 4
// 1649.683 us; speedup vs baseline: 1.9231x; 1.0299x over previous
//
#include <hip/hip_runtime.h>
#include <math.h>

constexpr int NB = 32;       // samples per angle
constexpr int LL = 16;       // bandwidth
constexpr int MM = 31;       // spectral orders (2*BW-1)
constexpr int MOFF = 15;
constexpr int NBATCH = 8;
constexpr int NCH = 50;
constexpr int NQ = MM * MM;          // 961
constexpr int SPAT = NB * NB * NB;   // 32768
constexpr long long HN = (long long)NBATCH * NCH * SPAT;  // 13,107,200

#define PI_D 3.14159265358979323846

__device__ inline float2 c_mk(float x, float y) { float2 r; r.x = x; r.y = y; return r; }

__device__ inline void fill_tw(float2* tw) {
  int t = threadIdx.x;
  if (t < 32) {
    double a = (double)t * (PI_D / 16.0);
    tw[t] = c_mk((float)cos(a), (float)sin(a));
  }
}

__device__ inline double dpow(double x, int n) {
  double r = 1.0;
  for (int i = 0; i < n; ++i) r *= x;
  return r;
}

// ---------------- constants ----------------

__global__ void qw_kernel(float* __restrict__ qw) {
  int j = threadIdx.x;
  if (j >= NB) return;
  double beta = PI_D * (2 * j + 1) / 64.0;
  double acc = 0.0;
  for (int kk = 0; kk < LL; ++kk)
    acc += sin((double)(2 * j + 1) * (2 * kk + 1) * PI_D / 64.0) / (double)(2 * kk + 1);
  qw[j] = (float)((2.0 / 16.0) * sin(beta) * acc);
}

// out layout [j][l][mp][m]; eqmode: nj==1, beta=pi/2
__global__ void wigner_kernel(float* __restrict__ out, int nj, int eqmode) {
  __shared__ double fact[66];
  int tid = threadIdx.x;
  if (tid < 66) { double f = 1.0; for (int i = 2; i <= tid; ++i) f *= (double)i; fact[tid] = f; }
  __syncthreads();
  int total = nj * LL * NQ;
  int idx = blockIdx.x * blockDim.x + tid;
  if (idx >= total) return;
  int q = idx % NQ;
  int l = (idx / NQ) % LL;
  int j = idx / (NQ * LL);
  int mp = q / MM - MOFF;
  int m  = q % MM - MOFF;
  int amp = mp < 0 ? -mp : mp, am = m < 0 ? -m : m;
  float res = 0.f;
  if (amp <= l && am <= l) {
    double beta = eqmode ? (PI_D * 0.5) : (PI_D * (2 * j + 1) / 64.0);
    double c = cos(beta * 0.5), s = sin(beta * 0.5);
    double pref = sqrt(fact[l + mp] * fact[l - mp] * fact[l + m] * fact[l - m]);
    int k0 = max(0, m - mp), k1 = min(l + m, l - mp);
    double acc = 0.0;
    for (int k = k0; k <= k1; ++k) {
      double denom = fact[l + m - k] * fact[k] * fact[l - k - mp] * fact[k - m + mp];
      double term = dpow(c, 2 * l - 2 * k + m - mp) * dpow(s, 2 * k - m + mp) / denom;
      acc += ((mp - m + k) & 1) ? -term : term;
    }
    res = (float)(pref * acc);
  }
  out[idx] = res;
}

// dbT[j][l][n][m] = dbeta[j][l][m][n]
__global__ void transpose_d_kernel(const float* __restrict__ dbeta, float* __restrict__ dbT) {
  int idx = blockIdx.x * blockDim.x + threadIdx.x;
  if (idx >= NB * LL * NQ) return;
  int m = idx % MM;
  int n = (idx / MM) % MM;
  int jl = idx / NQ;
  dbT[idx] = dbeta[jl * NQ + m * MM + n];
}

// ---------------- layer 1 (S2 conv) ----------------

__global__ __launch_bounds__(256) void s2_xh_kernel(const float* __restrict__ x,
                                                    const float* __restrict__ qw,
                                                    const float* __restrict__ dbeta,
                                                    float2* __restrict__ xh1) {
  __shared__ float xt[NB * NB];
  __shared__ float2 Xf0[NB * MM];
  __shared__ float2 tw[32];
  fill_tw(tw);
  int tid = threadIdx.x, b = blockIdx.x;
  for (int e = tid; e < NB * NB; e += 256) xt[e] = x[b * 1024 + e];
  __syncthreads();
  for (int e = tid; e < NB * MM; e += 256) {
    int j = e / MM, mi = e % MM, m = mi - MOFF;
    float re = 0.f, im = 0.f;
    const float* row = xt + j * NB;
    for (int a = 0; a < NB; ++a) {
      float v = row[a];
      float2 t = tw[(m * a) & 31];
      re += v * t.x; im -= v * t.y;   // e^{-i m a th}
    }
    Xf0[e] = c_mk(re, im);
  }
  __syncthreads();
  for (int e = tid; e < LL * MM; e += 256) {
    int l = e / MM, mi = e % MM;
    float re = 0.f, im = 0.f;
    for (int j = 0; j < NB; ++j) {
      float w = qw[j] * dbeta[(j * LL + l) * NQ + mi * MM + MOFF];
      float2 X = Xf0[j * MM + mi];
      re += w * X.x; im += w * X.y;
    }
    xh1[(b * LL + l) * MM + mi] = c_mk(re, im);
  }
}

// Wf[ni][ic] = sum_t W[ic][t] e^{-2pi i n t/32}, ic = i*Co+o
__global__ __launch_bounds__(256) void wfft_kernel(const float* __restrict__ W, int CiCo,
                                                   float2* __restrict__ Wf) {
  __shared__ float2 tw[32];
  fill_tw(tw);
  __syncthreads();
  int idx = blockIdx.x * blockDim.x + threadIdx.x;
  if (idx >= MM * CiCo) return;
  int ni = idx / CiCo, ic = idx % CiCo;
  int n = ni - MOFF;
  float re = 0.f, im = 0.f;
  for (int t = 0; t < NB; ++t) {
    float v = W[ic * NB + t];
    float2 tt = tw[(n * t) & 31];
    re += v * tt.x; im -= v * tt.y;
  }
  Wf[idx] = c_mk(re, im);
}

// z layout: [b][o][l][ni][mi].  z = deq0[l,ni] * xh1[b,l,mi] * conj(Wf1[ni,o])
__global__ void s2_z_kernel(const float2* __restrict__ xh1, const float2* __restrict__ Wf1,
                            const float* __restrict__ deq, float2* __restrict__ z) {
  int idx = blockIdx.x * blockDim.x + threadIdx.x;
  if (idx >= NBATCH * NCH * LL * NQ) return;
  int mi = idx % MM; int t = idx / MM;
  int ni = t % MM; t /= MM;
  int l = t % LL; t /= LL;
  int o = t % NCH; int b = t / NCH;
  float d0 = deq[(l * MM + ni) * MM + MOFF];
  float2 xv = xh1[(b * LL + l) * MM + mi];
  float2 wv = Wf1[ni * NCH + o];
  float re = d0 * (xv.x * wv.x + xv.y * wv.y);
  float im = d0 * (xv.y * wv.x - xv.x * wv.y);
  z[idx] = c_mk(re, im);
}

// ---------------- SO(3) inverse transform: split into fjq + dft ----------------

// F[bo][j][q] = sum_l (2l+1) * d^l_{m,n}(beta_j) * z[bo][l][q], q = ni*31+mi.
// Grid: (121 q-groups) x (16 bo-groups of 25). Threads 256 = 32 j x 8 q.
// z read exactly once overall; d per thread from L2 (2 MB table).
__global__ __launch_bounds__(256) void fjq_kernel(const float2* __restrict__ z,
                                                  const float* __restrict__ dbT,
                                                  float2* __restrict__ F) {
  __shared__ float2 zs[2][LL][8];
  int qg = blockIdx.x % 121;
  int bg = blockIdx.x / 121;
  int tid = threadIdx.x;
  int j = tid >> 3, ql = tid & 7;
  int q = qg * 8 + ql;
  bool qok = q < NQ;
  int qc = qok ? q : NQ - 1;
  float w[LL];
  #pragma unroll
  for (int l = 0; l < LL; ++l)
    w[l] = (2.f * l + 1.f) * dbT[(j * LL + l) * NQ + qc];
  int bo0 = bg * 25;
  if (tid < 128) {
    int l = tid >> 3, qq = qg * 8 + (tid & 7);
    zs[0][l][tid & 7] = (qq < NQ) ? z[((long long)bo0 * LL + l) * NQ + qq] : c_mk(0.f, 0.f);
  }
  __syncthreads();
  for (int i = 0; i < 25; ++i) {
    int bo = bo0 + i;
    if (i < 24 && tid < 128) {
      int l = tid >> 3, qq = qg * 8 + (tid & 7);
      zs[(i + 1) & 1][l][tid & 7] =
          (qq < NQ) ? z[((long long)(bo + 1) * LL + l) * NQ + qq] : c_mk(0.f, 0.f);
    }
    float fr = 0.f, fi = 0.f;
    #pragma unroll
    for (int l = 0; l < LL; ++l) {
      float2 zv = zs[i & 1][l][ql];
      fr += w[l] * zv.x; fi += w[l] * zv.y;
    }
    if (qok) F[((long long)bo * NB + j) * NQ + q] = c_mk(fr, fi);
    __syncthreads();
  }
}

// One block per (bo, j): load F row, 2 LDS DFT phases with +/-16 decimation.
__global__ __launch_bounds__(256) void so3_dft_kernel(const float2* __restrict__ F,
                                                      const float* __restrict__ bias,
                                                      float* __restrict__ out) {
  __shared__ float2 Fq[NQ];       // [ni][mi], 7.7 KB
  __shared__ float2 G[MM * NB];   // [m][g], 7.9 KB
  __shared__ float2 tw[32];
  fill_tw(tw);
  int tid = threadIdx.x;
  int blk = blockIdx.x;
  int j = blk & 31;
  int bo = blk >> 5;
  int o = bo % NCH;

  const float2* src = F + ((long long)bo * NB + j) * NQ;
  for (int e = tid; e < NQ; e += 256) Fq[e] = src[e];
  __syncthreads();

  // G[m,g] = sum_ni F[ni,m] e^{i(ni-15) g th}; g and g+16 together.
  for (int e = tid; e < MM * 16; e += 256) {
    int m = e >> 4, g = e & 15;
    float aex = 0.f, aey = 0.f, aox = 0.f, aoy = 0.f;
    #pragma unroll
    for (int p = 0; p < 15; ++p) {
      int ni = 2 * p;
      float2 f = Fq[ni * MM + m];
      float2 t = tw[((ni - 15) * g) & 31];
      aex += f.x * t.x - f.y * t.y;
      aey += f.x * t.y + f.y * t.x;
      float2 f2 = Fq[(ni + 1) * MM + m];
      float2 t2 = tw[((ni - 14) * g) & 31];
      aox += f2.x * t2.x - f2.y * t2.y;
      aoy += f2.x * t2.y + f2.y * t2.x;
    }
    { // ni = 30 (even)
      float2 f = Fq[30 * MM + m];
      float2 t = tw[(15 * g) & 31];
      aex += f.x * t.x - f.y * t.y;
      aey += f.x * t.y + f.y * t.x;
    }
    G[m * NB + g]      = c_mk(aex + aox, aey + aoy);
    G[m * NB + g + 16] = c_mk(aox - aex, aoy - aey);
  }
  __syncthreads();

  // out[a,g] = bias + Re sum_mi G[mi,g] e^{i(mi-15) a th}; a and a+16 together.
  float bval = bias[o];
  long long obase = (long long)bo * SPAT + (long long)j * 1024;
  for (int e = tid; e < 16 * NB; e += 256) {
    int a = e >> 5, g = e & 31;
    float be = 0.f, bo_ = 0.f;
    #pragma unroll
    for (int p = 0; p < 15; ++p) {
      int mi = 2 * p;
      float2 gv = G[mi * NB + g];
      float2 t = tw[((mi - 15) * a) & 31];
      be += gv.x * t.x - gv.y * t.y;
      float2 gv2 = G[(mi + 1) * NB + g];
      float2 t2 = tw[((mi - 14) * a) & 31];
      bo_ += gv2.x * t2.x - gv2.y * t2.y;
    }
    { // mi = 30 (even)
      float2 gv = G[30 * NB + g];
      float2 t = tw[(15 * a) & 31];
      be += gv.x * t.x - gv.y * t.y;
    }
    out[obase + a * 32 + g]        = bval + be + bo_;
    out[obase + (a + 16) * 32 + g] = bval + bo_ - be;
  }
}

// ---------------- batchnorm ----------------

__global__ void bn_stats_kernel(const float* __restrict__ h, float2* __restrict__ partials) {
  __shared__ float s1[256], s2[256];
  int tid = threadIdx.x;
  long long base = (long long)blockIdx.x * SPAT;
  float a1 = 0.f, a2 = 0.f;
  for (int e = tid; e < SPAT; e += 256) { float v = h[base + e]; a1 += v; a2 += v * v; }
  s1[tid] = a1; s2[tid] = a2;
  __syncthreads();
  for (int s = 128; s > 0; s >>= 1) {
    if (tid < s) { s1[tid] += s1[tid + s]; s2[tid] += s2[tid + s]; }
    __syncthreads();
  }
  if (tid == 0) partials[blockIdx.x] = c_mk(s1[0], s2[0]);
}

__global__ void bn_finalize_kernel(const float2* __restrict__ partials,
                                   const float* __restrict__ g, const float* __restrict__ bb,
                                   float2* __restrict__ sc) {
  int o = threadIdx.x;
  if (o >= NCH) return;
  float s = 0.f, ss = 0.f;
  for (int b = 0; b < NBATCH; ++b) { float2 p = partials[b * NCH + o]; s += p.x; ss += p.y; }
  float inv = 1.f / (float)(NBATCH * SPAT);
  float mu = s * inv;
  float var = ss * inv - mu * mu;
  float scale = g[o] * rsqrtf(var + 1e-5f);
  sc[o] = c_mk(scale, bb[o] - mu * scale);
}

// ---------------- SO(3) conv ----------------

// 2D DFT of a real 32x32 tile -> 31x31 signed-order spectrum.
// Fused bn+relu applied on load (sc indexed by channel).
__global__ __launch_bounds__(256) void dft2b_kernel(const float* __restrict__ h,
                                                    const float2* __restrict__ sc,
                                                    float2* __restrict__ Xf) {
  __shared__ float xt[32 * 33];   // padded stride kills bank conflict
  __shared__ float2 P[32 * 16];   // [a][n], n = 0..15
  __shared__ float2 Xs[NQ];
  __shared__ float2 tw[32];
  fill_tw(tw);
  int tid = threadIdx.x;
  long long blk = blockIdx.x;
  int c = (int)((blk >> 5) % NCH);
  float2 s = sc[c];
  const float* src = h + blk * 1024;
  for (int e = tid; e < 1024; e += 256) {
    float v = src[e];
    xt[(e >> 5) * 33 + (e & 31)] = fmaxf(v * s.x + s.y, 0.f);
  }
  __syncthreads();
  // P[a,n] = sum_g x[a,g] e^{-i n g th}
  for (int e = tid; e < 512; e += 256) {
    int a = e >> 4, n = e & 15;
    float re = 0.f, im = 0.f;
    const float* row = xt + a * 33;
    #pragma unroll
    for (int g = 0; g < 32; ++g) {
      float v = row[g];
      float2 t = tw[(n * g) & 31];
      re += v * t.x; im -= v * t.y;
    }
    P[a * 16 + n] = c_mk(re, im);
  }
  __syncthreads();
  // X[m,n] = sum_a P[a,n] e^{-i m a th}; m=+mh and m=-mh together.
  {
    int e = tid;
    if (e < 256) {
      int mh = e >> 4, n = e & 15;
      float sxx = 0.f, sxy = 0.f, syx = 0.f, syy = 0.f;
      #pragma unroll
      for (int a = 0; a < 32; ++a) {
        float2 p = P[a * 16 + n];
        float2 t = tw[(mh * a) & 31];
        sxx += p.x * t.x; sxy += p.x * t.y;
        syx += p.y * t.x; syy += p.y * t.y;
      }
      float2 Xp = c_mk(sxx + syy, syx - sxy);   // X[+mh, n]
      float2 Xm = c_mk(sxx - syy, syx + sxy);   // X[-mh, n]
      Xs[(mh + MOFF) * MM + (n + MOFF)] = Xp;
      Xs[(MOFF - mh) * MM + (n + MOFF)] = Xm;
      Xs[(MOFF - mh) * MM + (MOFF - n)] = c_mk(Xp.x, -Xp.y);
      Xs[(mh + MOFF) * MM + (MOFF - n)] = c_mk(Xm.x, -Xm.y);
    }
  }
  __syncthreads();
  float2* dst = Xf + blk * NQ;
  for (int e = tid; e < NQ; e += 256) dst[e] = Xs[e];
}

// xh[bc,l,q] = sum_j qw[j]*dbeta[j,l,q]*Xf[bc,j,q]   (q = mi*MM+ni)
__global__ void xh_kernel(const float2* __restrict__ Xf, const float* __restrict__ qw,
                          const float* __restrict__ dbeta, float2* __restrict__ xh) {
  int idx = blockIdx.x * blockDim.x + threadIdx.x;
  if (idx >= NBATCH * NCH * NQ) return;
  int q = idx % NQ;
  int bc = idx / NQ;
  float2 acc[LL];
  #pragma unroll
  for (int l = 0; l < LL; ++l) acc[l] = c_mk(0.f, 0.f);
  for (int j = 0; j < NB; ++j) {
    float2 xv = Xf[((long long)bc * NB + j) * NQ + q];
    float qj = qw[j];
    const float* dbase = dbeta + (long long)(j * LL) * NQ + q;
    #pragma unroll
    for (int l = 0; l < LL; ++l) {
      float w = qj * dbase[l * NQ];
      acc[l].x += w * xv.x;
      acc[l].y += w * xv.y;
    }
  }
  #pragma unroll
  for (int l = 0; l < LL; ++l) xh[((long long)bc * LL + l) * NQ + q] = acc[l];
}

// hk2[b][l][mi][ni][ich] = sum_k xh[(b*50+ich),l,mi,k] * deq[l,ni,k]
__global__ void hk_kernel(const float2* __restrict__ xh, const float* __restrict__ deq,
                          float2* __restrict__ hk2) {
  int idx = blockIdx.x * blockDim.x + threadIdx.x;
  // total = 8*16*31*31*50 = 6,150,400
  int ich = idx % NCH; int t = idx / NCH;
  int ni = t % MM; t /= MM;
  int mi = t % MM; t /= MM;
  int l = t % LL; int b = t / LL;
  const float2* row = xh + ((long long)((b * NCH + ich) * LL + l)) * NQ + mi * MM;
  const float* dr = deq + (l * MM + ni) * MM;
  float re = 0.f, im = 0.f;
  #pragma unroll
  for (int k = 0; k < MM; ++k) {
    float d = dr[k];
    float2 v = row[k];
    re += d * v.x; im += d * v.y;
  }
  hk2[idx] = c_mk(re, im);
}

// z[b][o][l][ni][mi] = sum_i hk2[(r*31+ni)*50+i] * conj(Wf[ni,i,o]), r=(b,l,mi)
__global__ __launch_bounds__(256) void z_kernel(const float2* __restrict__ hk2,
                                                const float2* __restrict__ Wf,
                                                float2* __restrict__ z) {
  int ni = blockIdx.x / MM;          // 0..30
  int rowtile = blockIdx.x % MM;     // 0..30
  int tid = threadIdx.x;
  int r = rowtile * 128 + (tid & 127);   // 0..3967 = (b,l,mi)
  int o0 = (tid >> 7) * 25;
  int b = r / (LL * MM);
  int rem = r % (LL * MM);
  int l = rem / MM;
  int mi = rem % MM;

  const float4* h4 = reinterpret_cast<const float4*>(hk2 + ((long long)r * MM + ni) * NCH);
  const float2* wbase = Wf + ni * (NCH * NCH) + o0;

  float2 acc[25];
  #pragma unroll
  for (int u = 0; u < 25; ++u) acc[u] = c_mk(0.f, 0.f);

  for (int ih = 0; ih < 25; ++ih) {     // 2 channels per iteration
    float4 hv = h4[ih];
    const float2* w0 = wbase + (2 * ih) * NCH;
    #pragma unroll
    for (int u = 0; u < 25; ++u) {
      float2 w = w0[u];
      acc[u].x += hv.x * w.x + hv.y * w.y;
      acc[u].y += hv.y * w.x - hv.x * w.y;
    }
    const float2* w1 = w0 + NCH;
    #pragma unroll
    for (int u = 0; u < 25; ++u) {
      float2 w = w1[u];
      acc[u].x += hv.z * w.x + hv.w * w.y;
      acc[u].y += hv.w * w.x - hv.z * w.y;
    }
  }

  long long zb = (((long long)(b * NCH + o0) * LL + l) * NQ) + ni * MM + mi;
  #pragma unroll
  for (int u = 0; u < 25; ++u)
    z[zb + (long long)u * LL * NQ] = acc[u];
}

// ---------------- head ----------------

// pool with fused bn+relu (layer-3 scale/shift applied per element)
__global__ void pool_kernel(const float* __restrict__ h, const float2* __restrict__ sc,
                            float* __restrict__ pooled) {
  __shared__ float sm[256];
  int tid = threadIdx.x;
  int o = blockIdx.x % NCH;
  float2 s = sc[o];
  const float* base = h + (long long)blockIdx.x * SPAT;
  float best = -1e30f;
  for (int e = tid; e < 1024; e += 256) {
    float acc = 0.f;
    for (int g = 0; g < NB; ++g) {
      float v = base[e * NB + g];
      acc += fmaxf(v * s.x + s.y, 0.f);
    }
    best = fmaxf(best, acc * (1.f / 32.f));
  }
  sm[tid] = best;
  __syncthreads();
  for (int st = 128; st > 0; st >>= 1) {
    if (tid < st) sm[tid] = fmaxf(sm[tid], sm[tid + st]);
    __syncthreads();
  }
  if (tid == 0) pooled[blockIdx.x] = sm[0];
}

__global__ __launch_bounds__(256) void head_kernel(const float* __restrict__ pooled,
    const float* __restrict__ fc1w, const float* __restrict__ fc1b,
    const float* __restrict__ g1, const float* __restrict__ b1,
    const float* __restrict__ fc2w, const float* __restrict__ fc2b,
    const float* __restrict__ g2, const float* __restrict__ b2,
    const float* __restrict__ fc3w, const float* __restrict__ fc3b,
    float* __restrict__ out) {
  __shared__ float pin[NBATCH * NCH];
  __shared__ float A[NBATCH * 256];
  __shared__ float Bm[NBATCH * 128];
  __shared__ float Cm[NBATCH * 40];
  int tid = threadIdx.x;
  for (int e = tid; e < NBATCH * NCH; e += 256) pin[e] = pooled[e];
  __syncthreads();
  {
    float v[NBATCH];
    #pragma unroll
    for (int b = 0; b < NBATCH; ++b) {
      float acc = fc1b[tid];
      for (int c = 0; c < NCH; ++c) acc += pin[b * NCH + c] * fc1w[tid * NCH + c];
      v[b] = acc;
    }
    float s = 0.f, ss = 0.f;
    #pragma unroll
    for (int b = 0; b < NBATCH; ++b) { s += v[b]; ss += v[b] * v[b]; }
    float mu = s * 0.125f, var = ss * 0.125f - mu * mu;
    float sc = g1[tid] * rsqrtf(var + 1e-5f), sh = b1[tid] - mu * sc;
    #pragma unroll
    for (int b = 0; b < NBATCH; ++b) A[b * 256 + tid] = fmaxf(v[b] * sc + sh, 0.f);
  }
  __syncthreads();
  if (tid < 128) {
    float v[NBATCH];
    #pragma unroll
    for (int b = 0; b < NBATCH; ++b) {
      float acc = fc2b[tid];
      for (int c = 0; c < 256; ++c) acc += A[b * 256 + c] * fc2w[tid * 256 + c];
      v[b] = acc;
    }
    float s = 0.f, ss = 0.f;
    #pragma unroll
    for (int b = 0; b < NBATCH; ++b) { s += v[b]; ss += v[b] * v[b]; }
    float mu = s * 0.125f, var = ss * 0.125f - mu * mu;
    float sc = g2[tid] * rsqrtf(var + 1e-5f), sh = b2[tid] - mu * sc;
    #pragma unroll
    for (int b = 0; b < NBATCH; ++b) Bm[b * 128 + tid] = fmaxf(v[b] * sc + sh, 0.f);
  }
  __syncthreads();
  if (tid < 40) {
    #pragma unroll
    for (int b = 0; b < NBATCH; ++b) {
      float acc = fc3b[tid];
      for (int c = 0; c < 128; ++c) acc += Bm[b * 128 + c] * fc3w[tid * 128 + c];
      Cm[b * 40 + tid] = acc;
    }
  }
  __syncthreads();
  if (tid < NBATCH) {
    int b = tid;
    float mx = -1e30f;
    for (int f = 0; f < 40; ++f) mx = fmaxf(mx, Cm[b * 40 + f]);
    float se = 0.f;
    for (int f = 0; f < 40; ++f) se += expf(Cm[b * 40 + f] - mx);
    float lse = mx + logf(se);
    for (int f = 0; f < 40; ++f) out[b * 40 + f] = Cm[b * 40 + f] - lse;
  }
}

// ---------------- host ----------------

extern "C" void kernel_launch(void* const* d_in, const int* in_sizes, int n_in,
                              void* d_out, int out_size, void* d_ws, size_t ws_size,
                              hipStream_t stream) {
  (void)in_sizes; (void)n_in; (void)out_size;
  const float* x    = (const float*)d_in[0];
  const float* k1   = (const float*)d_in[1];
  const float* c1b  = (const float*)d_in[2];
  const float* bn1g = (const float*)d_in[3];
  const float* bn1b = (const float*)d_in[4];
  const float* k2   = (const float*)d_in[5];
  const float* c2b  = (const float*)d_in[6];
  const float* bn2g = (const float*)d_in[7];
  const float* bn2b = (const float*)d_in[8];
  const float* k3   = (const float*)d_in[9];
  const float* c3b  = (const float*)d_in[10];
  const float* bn3g = (const float*)d_in[11];
  const float* bn3b = (const float*)d_in[12];
  const float* fc1w = (const float*)d_in[13];
  const float* fc1b = (const float*)d_in[14];
  const float* g1   = (const float*)d_in[15];
  const float* bb1  = (const float*)d_in[16];
  const float* fc2w = (const float*)d_in[17];
  const float* fc2b = (const float*)d_in[18];
  const float* g2   = (const float*)d_in[19];
  const float* bb2  = (const float*)d_in[20];
  const float* fc3w = (const float*)d_in[21];
  const float* fc3b = (const float*)d_in[22];
  float* out = (float*)d_out;

  char* ws = (char*)d_ws;
  size_t off = 0;
  auto alloc = [&](size_t n) -> char* {
    char* p = ws + off;
    off += (n + 255) & ~(size_t)255;
    return p;
  };

  float*  dbeta  = (float*)alloc(sizeof(float) * NB * LL * NQ);      // 1.97 MB
  float*  dbT    = (float*)alloc(sizeof(float) * NB * LL * NQ);      // 1.97 MB
  float*  deq    = (float*)alloc(sizeof(float) * LL * NQ);
  float*  qw     = (float*)alloc(sizeof(float) * NB);
  float2* xh1    = (float2*)alloc(sizeof(float2) * NBATCH * LL * MM);
  float2* Wf     = (float2*)alloc(sizeof(float2) * MM * NCH * NCH);  // 620 KB
  float2* parts  = (float2*)alloc(sizeof(float2) * NBATCH * NCH);
  float2* bnsc   = (float2*)alloc(sizeof(float2) * 64);
  float*  pooled = (float*)alloc(sizeof(float) * NBATCH * NCH);
  float*  HA     = (float*)alloc(sizeof(float) * (size_t)HN);        // 52.4 MB
  float*  HB     = (float*)alloc(sizeof(float) * (size_t)HN);        // 52.4 MB
  size_t XFB = (size_t)NBATCH * NCH * NB * NQ * sizeof(float2);      // 98.4 MB
  size_t XHB = (size_t)NBATCH * NCH * LL * NQ * sizeof(float2);      // 49.2 MB
  char* AR = alloc(XFB + XHB);                                       // 147.6 MB arena
  float2* Xf  = (float2*)AR;           // live: dft2 -> xh
  float2* xh  = (float2*)(AR + XFB);   // live: xh -> hk
  float2* hk2 = (float2*)AR;           // live: hk -> z    (reuses dead Xf)
  float2* zb  = (float2*)(AR + XFB);   // live: z -> fjq   (reuses dead xh; also z1)
  float2* Fb  = (float2*)AR;           // live: fjq -> dft (reuses dead hk2/Xf; 98.4 MB exact)

  if (ws_size < off) return;  // insufficient scratch: leave d_out zeroed

  const int T = 256;
  // constants
  qw_kernel<<<1, 32, 0, stream>>>(qw);
  wigner_kernel<<<(NB * LL * NQ + T - 1) / T, T, 0, stream>>>(dbeta, NB, 0);
  wigner_kernel<<<(LL * NQ + T - 1) / T, T, 0, stream>>>(deq, 1, 1);
  transpose_d_kernel<<<(NB * LL * NQ + T - 1) / T, T, 0, stream>>>(dbeta, dbT);

  // ---- layer 1: S2 conv -> HA
  s2_xh_kernel<<<NBATCH, T, 0, stream>>>(x, qw, dbeta, xh1);
  wfft_kernel<<<(MM * 1 * NCH + T - 1) / T, T, 0, stream>>>(k1, 1 * NCH, Wf);
  s2_z_kernel<<<(NBATCH * NCH * LL * NQ + T - 1) / T, T, 0, stream>>>(xh1, Wf, deq, zb);
  fjq_kernel<<<121 * 16, T, 0, stream>>>(zb, dbT, Fb);
  so3_dft_kernel<<<NBATCH * NCH * NB, T, 0, stream>>>(Fb, c1b, HA);
  bn_stats_kernel<<<NBATCH * NCH, T, 0, stream>>>(HA, parts);
  bn_finalize_kernel<<<1, 64, 0, stream>>>(parts, bn1g, bn1b, bnsc);

  // ---- layer 2: SO(3) conv HA -> HB (bn1+relu fused into dft2b load)
  dft2b_kernel<<<NBATCH * NCH * NB, T, 0, stream>>>(HA, bnsc, Xf);
  xh_kernel<<<(NBATCH * NCH * NQ + T - 1) / T, T, 0, stream>>>(Xf, qw, dbeta, xh);
  wfft_kernel<<<(MM * NCH * NCH + T - 1) / T, T, 0, stream>>>(k2, NCH * NCH, Wf);
  hk_kernel<<<(NBATCH * LL * MM * MM * NCH) / T, T, 0, stream>>>(xh, deq, hk2);
  z_kernel<<<MM * MM, T, 0, stream>>>(hk2, Wf, zb);
  fjq_kernel<<<121 * 16, T, 0, stream>>>(zb, dbT, Fb);
  so3_dft_kernel<<<NBATCH * NCH * NB, T, 0, stream>>>(Fb, c2b, HB);
  bn_stats_kernel<<<NBATCH * NCH, T, 0, stream>>>(HB, parts);
  bn_finalize_kernel<<<1, 64, 0, stream>>>(parts, bn2g, bn2b, bnsc);

  // ---- layer 3: SO(3) conv HB -> HA (bn2+relu fused into dft2b load)
  dft2b_kernel<<<NBATCH * NCH * NB, T, 0, stream>>>(HB, bnsc, Xf);
  xh_kernel<<<(NBATCH * NCH * NQ + T - 1) / T, T, 0, stream>>>(Xf, qw, dbeta, xh);
  wfft_kernel<<<(MM * NCH * NCH + T - 1) / T, T, 0, stream>>>(k3, NCH * NCH, Wf);
  hk_kernel<<<(NBATCH * LL * MM * MM * NCH) / T, T, 0, stream>>>(xh, deq, hk2);
  z_kernel<<<MM * MM, T, 0, stream>>>(hk2, Wf, zb);
  fjq_kernel<<<121 * 16, T, 0, stream>>>(zb, dbT, Fb);
  so3_dft_kernel<<<NBATCH * NCH * NB, T, 0, stream>>>(Fb, c3b, HA);
  bn_stats_kernel<<<NBATCH * NCH, T, 0, stream>>>(HA, parts);
  bn_finalize_kernel<<<1, 64, 0, stream>>>(parts, bn3g, bn3b, bnsc);

  // ---- head (bn3+relu fused into pool)
  pool_kernel<<<NBATCH * NCH, T, 0, stream>>>(HA, bnsc, pooled);
  head_kernel<<<1, T, 0, stream>>>(pooled, fc1w, fc1b, g1, bb1,
                                   fc2w, fc2b, g2, bb2, fc3w, fc3b, out);
}

// Round 5
// 1340.383 us; speedup vs baseline: 2.3669x; 1.2308x over previous
//
#include <hip/hip_runtime.h>
#include <math.h>

constexpr int NB = 32;       // samples per angle
constexpr int LL = 16;       // bandwidth
constexpr int MM = 31;       // spectral orders (2*BW-1)
constexpr int MOFF = 15;
constexpr int NBATCH = 8;
constexpr int NCH = 50;
constexpr int NQ = MM * MM;          // 961
constexpr int SPAT = NB * NB * NB;   // 32768
constexpr long long HN = (long long)NBATCH * NCH * SPAT;  // 13,107,200

#define PI_D 3.14159265358979323846

__device__ inline float2 c_mk(float x, float y) { float2 r; r.x = x; r.y = y; return r; }

__device__ inline void fill_tw(float2* tw) {
  int t = threadIdx.x;
  if (t < 32) {
    double a = (double)t * (PI_D / 16.0);
    tw[t] = c_mk((float)cos(a), (float)sin(a));
  }
}

__device__ inline double dpow(double x, int n) {
  double r = 1.0;
  for (int i = 0; i < n; ++i) r *= x;
  return r;
}

// ---------------- constants ----------------

__global__ void qw_kernel(float* __restrict__ qw) {
  int j = threadIdx.x;
  if (j >= NB) return;
  double beta = PI_D * (2 * j + 1) / 64.0;
  double acc = 0.0;
  for (int kk = 0; kk < LL; ++kk)
    acc += sin((double)(2 * j + 1) * (2 * kk + 1) * PI_D / 64.0) / (double)(2 * kk + 1);
  qw[j] = (float)((2.0 / 16.0) * sin(beta) * acc);
}

// out layout [j][l][mp][m]; eqmode: nj==1, beta=pi/2
__global__ void wigner_kernel(float* __restrict__ out, int nj, int eqmode) {
  __shared__ double fact[66];
  int tid = threadIdx.x;
  if (tid < 66) { double f = 1.0; for (int i = 2; i <= tid; ++i) f *= (double)i; fact[tid] = f; }
  __syncthreads();
  int total = nj * LL * NQ;
  int idx = blockIdx.x * blockDim.x + tid;
  if (idx >= total) return;
  int q = idx % NQ;
  int l = (idx / NQ) % LL;
  int j = idx / (NQ * LL);
  int mp = q / MM - MOFF;
  int m  = q % MM - MOFF;
  int amp = mp < 0 ? -mp : mp, am = m < 0 ? -m : m;
  float res = 0.f;
  if (amp <= l && am <= l) {
    double beta = eqmode ? (PI_D * 0.5) : (PI_D * (2 * j + 1) / 64.0);
    double c = cos(beta * 0.5), s = sin(beta * 0.5);
    double pref = sqrt(fact[l + mp] * fact[l - mp] * fact[l + m] * fact[l - m]);
    int k0 = max(0, m - mp), k1 = min(l + m, l - mp);
    double acc = 0.0;
    for (int k = k0; k <= k1; ++k) {
      double denom = fact[l + m - k] * fact[k] * fact[l - k - mp] * fact[k - m + mp];
      double term = dpow(c, 2 * l - 2 * k + m - mp) * dpow(s, 2 * k - m + mp) / denom;
      acc += ((mp - m + k) & 1) ? -term : term;
    }
    res = (float)(pref * acc);
  }
  out[idx] = res;
}

// dbT[j][l][n][m] = dbeta[j][l][m][n]
__global__ void transpose_d_kernel(const float* __restrict__ dbeta, float* __restrict__ dbT) {
  int idx = blockIdx.x * blockDim.x + threadIdx.x;
  if (idx >= NB * LL * NQ) return;
  int m = idx % MM;
  int n = (idx / MM) % MM;
  int jl = idx / NQ;
  dbT[idx] = dbeta[jl * NQ + m * MM + n];
}

// ---------------- layer 1 (S2 conv) ----------------

__global__ __launch_bounds__(256) void s2_xh_kernel(const float* __restrict__ x,
                                                    const float* __restrict__ qw,
                                                    const float* __restrict__ dbeta,
                                                    float2* __restrict__ xh1) {
  __shared__ float xt[NB * NB];
  __shared__ float2 Xf0[NB * MM];
  __shared__ float2 tw[32];
  fill_tw(tw);
  int tid = threadIdx.x, b = blockIdx.x;
  for (int e = tid; e < NB * NB; e += 256) xt[e] = x[b * 1024 + e];
  __syncthreads();
  for (int e = tid; e < NB * MM; e += 256) {
    int j = e / MM, mi = e % MM, m = mi - MOFF;
    float re = 0.f, im = 0.f;
    const float* row = xt + j * NB;
    for (int a = 0; a < NB; ++a) {
      float v = row[a];
      float2 t = tw[(m * a) & 31];
      re += v * t.x; im -= v * t.y;   // e^{-i m a th}
    }
    Xf0[e] = c_mk(re, im);
  }
  __syncthreads();
  for (int e = tid; e < LL * MM; e += 256) {
    int l = e / MM, mi = e % MM;
    float re = 0.f, im = 0.f;
    for (int j = 0; j < NB; ++j) {
      float w = qw[j] * dbeta[(j * LL + l) * NQ + mi * MM + MOFF];
      float2 X = Xf0[j * MM + mi];
      re += w * X.x; im += w * X.y;
    }
    xh1[(b * LL + l) * MM + mi] = c_mk(re, im);
  }
}

// Wf[ni][ic] = sum_t W[ic][t] e^{-2pi i n t/32}, ic = i*Co+o
__global__ __launch_bounds__(256) void wfft_kernel(const float* __restrict__ W, int CiCo,
                                                   float2* __restrict__ Wf) {
  __shared__ float2 tw[32];
  fill_tw(tw);
  __syncthreads();
  int idx = blockIdx.x * blockDim.x + threadIdx.x;
  if (idx >= MM * CiCo) return;
  int ni = idx / CiCo, ic = idx % CiCo;
  int n = ni - MOFF;
  float re = 0.f, im = 0.f;
  for (int t = 0; t < NB; ++t) {
    float v = W[ic * NB + t];
    float2 tt = tw[(n * t) & 31];
    re += v * tt.x; im -= v * tt.y;
  }
  Wf[idx] = c_mk(re, im);
}

// z layout: [b][o][l][ni][mi].  z = deq0[l,ni] * xh1[b,l,mi] * conj(Wf1[ni,o])
__global__ void s2_z_kernel(const float2* __restrict__ xh1, const float2* __restrict__ Wf1,
                            const float* __restrict__ deq, float2* __restrict__ z) {
  int idx = blockIdx.x * blockDim.x + threadIdx.x;
  if (idx >= NBATCH * NCH * LL * NQ) return;
  int mi = idx % MM; int t = idx / MM;
  int ni = t % MM; t /= MM;
  int l = t % LL; t /= LL;
  int o = t % NCH; int b = t / NCH;
  float d0 = deq[(l * MM + ni) * MM + MOFF];
  float2 xv = xh1[(b * LL + l) * MM + mi];
  float2 wv = Wf1[ni * NCH + o];
  float re = d0 * (xv.x * wv.x + xv.y * wv.y);
  float im = d0 * (xv.y * wv.x - xv.x * wv.y);
  z[idx] = c_mk(re, im);
}

// ---------------- SO(3) inverse transform: split into fjq + dft ----------------

// F[bo][j][q] = sum_l (2l+1) * d^l_{m,n}(beta_j) * z[bo][l][q], q = ni*31+mi.
__global__ __launch_bounds__(256) void fjq_kernel(const float2* __restrict__ z,
                                                  const float* __restrict__ dbT,
                                                  float2* __restrict__ F) {
  __shared__ float2 zs[2][LL][8];
  int qg = blockIdx.x % 121;
  int bg = blockIdx.x / 121;
  int tid = threadIdx.x;
  int j = tid >> 3, ql = tid & 7;
  int q = qg * 8 + ql;
  bool qok = q < NQ;
  int qc = qok ? q : NQ - 1;
  float w[LL];
  #pragma unroll
  for (int l = 0; l < LL; ++l)
    w[l] = (2.f * l + 1.f) * dbT[(j * LL + l) * NQ + qc];
  int bo0 = bg * 25;
  if (tid < 128) {
    int l = tid >> 3, qq = qg * 8 + (tid & 7);
    zs[0][l][tid & 7] = (qq < NQ) ? z[((long long)bo0 * LL + l) * NQ + qq] : c_mk(0.f, 0.f);
  }
  __syncthreads();
  for (int i = 0; i < 25; ++i) {
    int bo = bo0 + i;
    if (i < 24 && tid < 128) {
      int l = tid >> 3, qq = qg * 8 + (tid & 7);
      zs[(i + 1) & 1][l][tid & 7] =
          (qq < NQ) ? z[((long long)(bo + 1) * LL + l) * NQ + qq] : c_mk(0.f, 0.f);
    }
    float fr = 0.f, fi = 0.f;
    #pragma unroll
    for (int l = 0; l < LL; ++l) {
      float2 zv = zs[i & 1][l][ql];
      fr += w[l] * zv.x; fi += w[l] * zv.y;
    }
    if (qok) F[((long long)bo * NB + j) * NQ + q] = c_mk(fr, fi);
    __syncthreads();
  }
}

// One block per (bo, j): load F row, 2 LDS DFT phases with +/-16 decimation.
__global__ __launch_bounds__(256) void so3_dft_kernel(const float2* __restrict__ F,
                                                      const float* __restrict__ bias,
                                                      float* __restrict__ out) {
  __shared__ float2 Fq[NQ];       // [ni][mi], 7.7 KB
  __shared__ float2 G[MM * NB];   // [m][g], 7.9 KB
  __shared__ float2 tw[32];
  fill_tw(tw);
  int tid = threadIdx.x;
  int blk = blockIdx.x;
  int j = blk & 31;
  int bo = blk >> 5;
  int o = bo % NCH;

  const float2* src = F + ((long long)bo * NB + j) * NQ;
  for (int e = tid; e < NQ; e += 256) Fq[e] = src[e];
  __syncthreads();

  // G[m,g] = sum_ni F[ni,m] e^{i(ni-15) g th}; g and g+16 together.
  for (int e = tid; e < MM * 16; e += 256) {
    int m = e >> 4, g = e & 15;
    float aex = 0.f, aey = 0.f, aox = 0.f, aoy = 0.f;
    #pragma unroll
    for (int p = 0; p < 15; ++p) {
      int ni = 2 * p;
      float2 f = Fq[ni * MM + m];
      float2 t = tw[((ni - 15) * g) & 31];
      aex += f.x * t.x - f.y * t.y;
      aey += f.x * t.y + f.y * t.x;
      float2 f2 = Fq[(ni + 1) * MM + m];
      float2 t2 = tw[((ni - 14) * g) & 31];
      aox += f2.x * t2.x - f2.y * t2.y;
      aoy += f2.x * t2.y + f2.y * t2.x;
    }
    { // ni = 30 (even)
      float2 f = Fq[30 * MM + m];
      float2 t = tw[(15 * g) & 31];
      aex += f.x * t.x - f.y * t.y;
      aey += f.x * t.y + f.y * t.x;
    }
    G[m * NB + g]      = c_mk(aex + aox, aey + aoy);
    G[m * NB + g + 16] = c_mk(aox - aex, aoy - aey);
  }
  __syncthreads();

  // out[a,g] = bias + Re sum_mi G[mi,g] e^{i(mi-15) a th}; a and a+16 together.
  float bval = bias[o];
  long long obase = (long long)bo * SPAT + (long long)j * 1024;
  for (int e = tid; e < 16 * NB; e += 256) {
    int a = e >> 5, g = e & 31;
    float be = 0.f, bo_ = 0.f;
    #pragma unroll
    for (int p = 0; p < 15; ++p) {
      int mi = 2 * p;
      float2 gv = G[mi * NB + g];
      float2 t = tw[((mi - 15) * a) & 31];
      be += gv.x * t.x - gv.y * t.y;
      float2 gv2 = G[(mi + 1) * NB + g];
      float2 t2 = tw[((mi - 14) * a) & 31];
      bo_ += gv2.x * t2.x - gv2.y * t2.y;
    }
    { // mi = 30 (even)
      float2 gv = G[30 * NB + g];
      float2 t = tw[(15 * a) & 31];
      be += gv.x * t.x - gv.y * t.y;
    }
    out[obase + a * 32 + g]        = bval + be + bo_;
    out[obase + (a + 16) * 32 + g] = bval + bo_ - be;
  }
}

// ---------------- batchnorm ----------------

__global__ void bn_stats_kernel(const float* __restrict__ h, float2* __restrict__ partials) {
  __shared__ float s1[256], s2[256];
  int tid = threadIdx.x;
  long long base = (long long)blockIdx.x * SPAT;
  float a1 = 0.f, a2 = 0.f;
  for (int e = tid; e < SPAT; e += 256) { float v = h[base + e]; a1 += v; a2 += v * v; }
  s1[tid] = a1; s2[tid] = a2;
  __syncthreads();
  for (int s = 128; s > 0; s >>= 1) {
    if (tid < s) { s1[tid] += s1[tid + s]; s2[tid] += s2[tid + s]; }
    __syncthreads();
  }
  if (tid == 0) partials[blockIdx.x] = c_mk(s1[0], s2[0]);
}

__global__ void bn_finalize_kernel(const float2* __restrict__ partials,
                                   const float* __restrict__ g, const float* __restrict__ bb,
                                   float2* __restrict__ sc) {
  int o = threadIdx.x;
  if (o >= NCH) return;
  float s = 0.f, ss = 0.f;
  for (int b = 0; b < NBATCH; ++b) { float2 p = partials[b * NCH + o]; s += p.x; ss += p.y; }
  float inv = 1.f / (float)(NBATCH * SPAT);
  float mu = s * inv;
  float var = ss * inv - mu * mu;
  float scale = g[o] * rsqrtf(var + 1e-5f);
  sc[o] = c_mk(scale, bb[o] - mu * scale);
}

// ---------------- SO(3) conv ----------------

// 2D DFT of a real 32x32 tile -> 31x31 signed-order spectrum.
// Fused bn+relu applied on load (sc indexed by channel).
__global__ __launch_bounds__(256) void dft2b_kernel(const float* __restrict__ h,
                                                    const float2* __restrict__ sc,
                                                    float2* __restrict__ Xf) {
  __shared__ float xt[32 * 33];   // padded stride kills bank conflict
  __shared__ float2 P[32 * 16];   // [a][n], n = 0..15
  __shared__ float2 Xs[NQ];
  __shared__ float2 tw[32];
  fill_tw(tw);
  int tid = threadIdx.x;
  long long blk = blockIdx.x;
  int c = (int)((blk >> 5) % NCH);
  float2 s = sc[c];
  const float* src = h + blk * 1024;
  for (int e = tid; e < 1024; e += 256) {
    float v = src[e];
    xt[(e >> 5) * 33 + (e & 31)] = fmaxf(v * s.x + s.y, 0.f);
  }
  __syncthreads();
  // P[a,n] = sum_g x[a,g] e^{-i n g th}
  for (int e = tid; e < 512; e += 256) {
    int a = e >> 4, n = e & 15;
    float re = 0.f, im = 0.f;
    const float* row = xt + a * 33;
    #pragma unroll
    for (int g = 0; g < 32; ++g) {
      float v = row[g];
      float2 t = tw[(n * g) & 31];
      re += v * t.x; im -= v * t.y;
    }
    P[a * 16 + n] = c_mk(re, im);
  }
  __syncthreads();
  // X[m,n] = sum_a P[a,n] e^{-i m a th}; m=+mh and m=-mh together.
  {
    int e = tid;
    if (e < 256) {
      int mh = e >> 4, n = e & 15;
      float sxx = 0.f, sxy = 0.f, syx = 0.f, syy = 0.f;
      #pragma unroll
      for (int a = 0; a < 32; ++a) {
        float2 p = P[a * 16 + n];
        float2 t = tw[(mh * a) & 31];
        sxx += p.x * t.x; sxy += p.x * t.y;
        syx += p.y * t.x; syy += p.y * t.y;
      }
      float2 Xp = c_mk(sxx + syy, syx - sxy);   // X[+mh, n]
      float2 Xm = c_mk(sxx - syy, syx + sxy);   // X[-mh, n]
      Xs[(mh + MOFF) * MM + (n + MOFF)] = Xp;
      Xs[(MOFF - mh) * MM + (n + MOFF)] = Xm;
      Xs[(MOFF - mh) * MM + (MOFF - n)] = c_mk(Xp.x, -Xp.y);
      Xs[(mh + MOFF) * MM + (MOFF - n)] = c_mk(Xm.x, -Xm.y);
    }
  }
  __syncthreads();
  float2* dst = Xf + blk * NQ;
  for (int e = tid; e < NQ; e += 256) dst[e] = Xs[e];
}

// xh[bc,l,q] = sum_j qw[j]*dbeta[j,l,q]*Xf[bc,j,q]   (q = mi*MM+ni)
__global__ void xh_kernel(const float2* __restrict__ Xf, const float* __restrict__ qw,
                          const float* __restrict__ dbeta, float2* __restrict__ xh) {
  int idx = blockIdx.x * blockDim.x + threadIdx.x;
  if (idx >= NBATCH * NCH * NQ) return;
  int q = idx % NQ;
  int bc = idx / NQ;
  float2 acc[LL];
  #pragma unroll
  for (int l = 0; l < LL; ++l) acc[l] = c_mk(0.f, 0.f);
  for (int j = 0; j < NB; ++j) {
    float2 xv = Xf[((long long)bc * NB + j) * NQ + q];
    float qj = qw[j];
    const float* dbase = dbeta + (long long)(j * LL) * NQ + q;
    #pragma unroll
    for (int l = 0; l < LL; ++l) {
      float w = qj * dbase[l * NQ];
      acc[l].x += w * xv.x;
      acc[l].y += w * xv.y;
    }
  }
  #pragma unroll
  for (int l = 0; l < LL; ++l) xh[((long long)bc * LL + l) * NQ + q] = acc[l];
}

// hk2[r][ni][ich] = sum_k xh[(b*NCH+ich),l,mi,k] * deq[l,ni,k], r=(b*LL+l)*MM+mi.
// One wave per r; lane = ich. xh k-row held in registers (read once);
// deq accesses are lane-uniform (scalar); stores lane-contiguous.
__global__ __launch_bounds__(64) void hk_kernel(const float2* __restrict__ xh,
                                                const float* __restrict__ deq,
                                                float2* __restrict__ hk2) {
  int r = blockIdx.x;                 // 0..3967
  int mi = r % MM;
  int bl = r / MM;                    // b*LL + l
  int l = bl % LL;
  int b = bl / LL;
  int ich = threadIdx.x;
  if (ich >= NCH) return;
  float2 row[MM];
  const float2* src = xh + ((long long)(b * NCH + ich) * LL + l) * NQ + mi * MM;
  #pragma unroll
  for (int k = 0; k < MM; ++k) row[k] = src[k];
  const float* dl = deq + l * NQ;
  long long obase = (long long)r * MM * NCH + ich;
  for (int ni = 0; ni < MM; ++ni) {
    const float* dr = dl + ni * MM;
    float re = 0.f, im = 0.f;
    #pragma unroll
    for (int k = 0; k < MM; ++k) {
      float d = dr[k];
      re += d * row[k].x;
      im += d * row[k].y;
    }
    hk2[obase + (long long)ni * NCH] = c_mk(re, im);
  }
}

// z[b][o][l][ni][mi] = sum_i hk2[(r*31+ni)*50+i] * conj(Wf[ni,i,o]), r=(b,l,mi)
__global__ __launch_bounds__(256) void z_kernel(const float2* __restrict__ hk2,
                                                const float2* __restrict__ Wf,
                                                float2* __restrict__ z) {
  int ni = blockIdx.x / MM;          // 0..30
  int rowtile = blockIdx.x % MM;     // 0..30
  int tid = threadIdx.x;
  int r = rowtile * 128 + (tid & 127);   // 0..3967 = (b,l,mi)
  int o0 = (tid >> 7) * 25;
  int b = r / (LL * MM);
  int rem = r % (LL * MM);
  int l = rem / MM;
  int mi = rem % MM;

  const float4* h4 = reinterpret_cast<const float4*>(hk2 + ((long long)r * MM + ni) * NCH);
  const float2* wbase = Wf + ni * (NCH * NCH) + o0;

  float2 acc[25];
  #pragma unroll
  for (int u = 0; u < 25; ++u) acc[u] = c_mk(0.f, 0.f);

  for (int ih = 0; ih < 25; ++ih) {     // 2 channels per iteration
    float4 hv = h4[ih];
    const float2* w0 = wbase + (2 * ih) * NCH;
    #pragma unroll
    for (int u = 0; u < 25; ++u) {
      float2 w = w0[u];
      acc[u].x += hv.x * w.x + hv.y * w.y;
      acc[u].y += hv.y * w.x - hv.x * w.y;
    }
    const float2* w1 = w0 + NCH;
    #pragma unroll
    for (int u = 0; u < 25; ++u) {
      float2 w = w1[u];
      acc[u].x += hv.z * w.x + hv.w * w.y;
      acc[u].y += hv.w * w.x - hv.z * w.y;
    }
  }

  long long zb = (((long long)(b * NCH + o0) * LL + l) * NQ) + ni * MM + mi;
  #pragma unroll
  for (int u = 0; u < 25; ++u)
    z[zb + (long long)u * LL * NQ] = acc[u];
}

// ---------------- head ----------------

// pool with fused bn+relu (layer-3 scale/shift applied per element)
__global__ void pool_kernel(const float* __restrict__ h, const float2* __restrict__ sc,
                            float* __restrict__ pooled) {
  __shared__ float sm[256];
  int tid = threadIdx.x;
  int o = blockIdx.x % NCH;
  float2 s = sc[o];
  const float* base = h + (long long)blockIdx.x * SPAT;
  float best = -1e30f;
  for (int e = tid; e < 1024; e += 256) {
    float acc = 0.f;
    for (int g = 0; g < NB; ++g) {
      float v = base[e * NB + g];
      acc += fmaxf(v * s.x + s.y, 0.f);
    }
    best = fmaxf(best, acc * (1.f / 32.f));
  }
  sm[tid] = best;
  __syncthreads();
  for (int st = 128; st > 0; st >>= 1) {
    if (tid < st) sm[tid] = fmaxf(sm[tid], sm[tid + st]);
    __syncthreads();
  }
  if (tid == 0) pooled[blockIdx.x] = sm[0];
}

__global__ __launch_bounds__(256) void head_kernel(const float* __restrict__ pooled,
    const float* __restrict__ fc1w, const float* __restrict__ fc1b,
    const float* __restrict__ g1, const float* __restrict__ b1,
    const float* __restrict__ fc2w, const float* __restrict__ fc2b,
    const float* __restrict__ g2, const float* __restrict__ b2,
    const float* __restrict__ fc3w, const float* __restrict__ fc3b,
    float* __restrict__ out) {
  __shared__ float pin[NBATCH * NCH];
  __shared__ float A[NBATCH * 256];
  __shared__ float Bm[NBATCH * 128];
  __shared__ float Cm[NBATCH * 40];
  int tid = threadIdx.x;
  for (int e = tid; e < NBATCH * NCH; e += 256) pin[e] = pooled[e];
  __syncthreads();
  {
    float v[NBATCH];
    #pragma unroll
    for (int b = 0; b < NBATCH; ++b) {
      float acc = fc1b[tid];
      for (int c = 0; c < NCH; ++c) acc += pin[b * NCH + c] * fc1w[tid * NCH + c];
      v[b] = acc;
    }
    float s = 0.f, ss = 0.f;
    #pragma unroll
    for (int b = 0; b < NBATCH; ++b) { s += v[b]; ss += v[b] * v[b]; }
    float mu = s * 0.125f, var = ss * 0.125f - mu * mu;
    float sc = g1[tid] * rsqrtf(var + 1e-5f), sh = b1[tid] - mu * sc;
    #pragma unroll
    for (int b = 0; b < NBATCH; ++b) A[b * 256 + tid] = fmaxf(v[b] * sc + sh, 0.f);
  }
  __syncthreads();
  if (tid < 128) {
    float v[NBATCH];
    #pragma unroll
    for (int b = 0; b < NBATCH; ++b) {
      float acc = fc2b[tid];
      for (int c = 0; c < 256; ++c) acc += A[b * 256 + c] * fc2w[tid * 256 + c];
      v[b] = acc;
    }
    float s = 0.f, ss = 0.f;
    #pragma unroll
    for (int b = 0; b < NBATCH; ++b) { s += v[b]; ss += v[b] * v[b]; }
    float mu = s * 0.125f, var = ss * 0.125f - mu * mu;
    float sc = g2[tid] * rsqrtf(var + 1e-5f), sh = b2[tid] - mu * sc;
    #pragma unroll
    for (int b = 0; b < NBATCH; ++b) Bm[b * 128 + tid] = fmaxf(v[b] * sc + sh, 0.f);
  }
  __syncthreads();
  if (tid < 40) {
    #pragma unroll
    for (int b = 0; b < NBATCH; ++b) {
      float acc = fc3b[tid];
      for (int c = 0; c < 128; ++c) acc += Bm[b * 128 + c] * fc3w[tid * 128 + c];
      Cm[b * 40 + tid] = acc;
    }
  }
  __syncthreads();
  if (tid < NBATCH) {
    int b = tid;
    float mx = -1e30f;
    for (int f = 0; f < 40; ++f) mx = fmaxf(mx, Cm[b * 40 + f]);
    float se = 0.f;
    for (int f = 0; f < 40; ++f) se += expf(Cm[b * 40 + f] - mx);
    float lse = mx + logf(se);
    for (int f = 0; f < 40; ++f) out[b * 40 + f] = Cm[b * 40 + f] - lse;
  }
}

// ---------------- host ----------------

extern "C" void kernel_launch(void* const* d_in, const int* in_sizes, int n_in,
                              void* d_out, int out_size, void* d_ws, size_t ws_size,
                              hipStream_t stream) {
  (void)in_sizes; (void)n_in; (void)out_size;
  const float* x    = (const float*)d_in[0];
  const float* k1   = (const float*)d_in[1];
  const float* c1b  = (const float*)d_in[2];
  const float* bn1g = (const float*)d_in[3];
  const float* bn1b = (const float*)d_in[4];
  const float* k2   = (const float*)d_in[5];
  const float* c2b  = (const float*)d_in[6];
  const float* bn2g = (const float*)d_in[7];
  const float* bn2b = (const float*)d_in[8];
  const float* k3   = (const float*)d_in[9];
  const float* c3b  = (const float*)d_in[10];
  const float* bn3g = (const float*)d_in[11];
  const float* bn3b = (const float*)d_in[12];
  const float* fc1w = (const float*)d_in[13];
  const float* fc1b = (const float*)d_in[14];
  const float* g1   = (const float*)d_in[15];
  const float* bb1  = (const float*)d_in[16];
  const float* fc2w = (const float*)d_in[17];
  const float* fc2b = (const float*)d_in[18];
  const float* g2   = (const float*)d_in[19];
  const float* bb2  = (const float*)d_in[20];
  const float* fc3w = (const float*)d_in[21];
  const float* fc3b = (const float*)d_in[22];
  float* out = (float*)d_out;

  char* ws = (char*)d_ws;
  size_t off = 0;
  auto alloc = [&](size_t n) -> char* {
    char* p = ws + off;
    off += (n + 255) & ~(size_t)255;
    return p;
  };

  float*  dbeta  = (float*)alloc(sizeof(float) * NB * LL * NQ);      // 1.97 MB
  float*  dbT    = (float*)alloc(sizeof(float) * NB * LL * NQ);      // 1.97 MB
  float*  deq    = (float*)alloc(sizeof(float) * LL * NQ);
  float*  qw     = (float*)alloc(sizeof(float) * NB);
  float2* xh1    = (float2*)alloc(sizeof(float2) * NBATCH * LL * MM);
  float2* Wf     = (float2*)alloc(sizeof(float2) * MM * NCH * NCH);  // 620 KB
  float2* parts  = (float2*)alloc(sizeof(float2) * NBATCH * NCH);
  float2* bnsc   = (float2*)alloc(sizeof(float2) * 64);
  float*  pooled = (float*)alloc(sizeof(float) * NBATCH * NCH);
  float*  HA     = (float*)alloc(sizeof(float) * (size_t)HN);        // 52.4 MB
  float*  HB     = (float*)alloc(sizeof(float) * (size_t)HN);        // 52.4 MB
  size_t XFB = (size_t)NBATCH * NCH * NB * NQ * sizeof(float2);      // 98.4 MB
  size_t XHB = (size_t)NBATCH * NCH * LL * NQ * sizeof(float2);      // 49.2 MB
  char* AR = alloc(XFB + XHB);                                       // 147.6 MB arena
  float2* Xf  = (float2*)AR;           // live: dft2 -> xh
  float2* xh  = (float2*)(AR + XFB);   // live: xh -> hk
  float2* hk2 = (float2*)AR;           // live: hk -> z    (reuses dead Xf)
  float2* zb  = (float2*)(AR + XFB);   // live: z -> fjq   (reuses dead xh; also z1)
  float2* Fb  = (float2*)AR;           // live: fjq -> dft (reuses dead hk2/Xf; 98.4 MB exact)

  if (ws_size < off) return;  // insufficient scratch: leave d_out zeroed

  const int T = 256;
  // constants
  qw_kernel<<<1, 32, 0, stream>>>(qw);
  wigner_kernel<<<(NB * LL * NQ + T - 1) / T, T, 0, stream>>>(dbeta, NB, 0);
  wigner_kernel<<<(LL * NQ + T - 1) / T, T, 0, stream>>>(deq, 1, 1);
  transpose_d_kernel<<<(NB * LL * NQ + T - 1) / T, T, 0, stream>>>(dbeta, dbT);

  // ---- layer 1: S2 conv -> HA
  s2_xh_kernel<<<NBATCH, T, 0, stream>>>(x, qw, dbeta, xh1);
  wfft_kernel<<<(MM * 1 * NCH + T - 1) / T, T, 0, stream>>>(k1, 1 * NCH, Wf);
  s2_z_kernel<<<(NBATCH * NCH * LL * NQ + T - 1) / T, T, 0, stream>>>(xh1, Wf, deq, zb);
  fjq_kernel<<<121 * 16, T, 0, stream>>>(zb, dbT, Fb);
  so3_dft_kernel<<<NBATCH * NCH * NB, T, 0, stream>>>(Fb, c1b, HA);
  bn_stats_kernel<<<NBATCH * NCH, T, 0, stream>>>(HA, parts);
  bn_finalize_kernel<<<1, 64, 0, stream>>>(parts, bn1g, bn1b, bnsc);

  // ---- layer 2: SO(3) conv HA -> HB (bn1+relu fused into dft2b load)
  dft2b_kernel<<<NBATCH * NCH * NB, T, 0, stream>>>(HA, bnsc, Xf);
  xh_kernel<<<(NBATCH * NCH * NQ + T - 1) / T, T, 0, stream>>>(Xf, qw, dbeta, xh);
  wfft_kernel<<<(MM * NCH * NCH + T - 1) / T, T, 0, stream>>>(k2, NCH * NCH, Wf);
  hk_kernel<<<NBATCH * LL * MM, 64, 0, stream>>>(xh, deq, hk2);
  z_kernel<<<MM * MM, T, 0, stream>>>(hk2, Wf, zb);
  fjq_kernel<<<121 * 16, T, 0, stream>>>(zb, dbT, Fb);
  so3_dft_kernel<<<NBATCH * NCH * NB, T, 0, stream>>>(Fb, c2b, HB);
  bn_stats_kernel<<<NBATCH * NCH, T, 0, stream>>>(HB, parts);
  bn_finalize_kernel<<<1, 64, 0, stream>>>(parts, bn2g, bn2b, bnsc);

  // ---- layer 3: SO(3) conv HB -> HA (bn2+relu fused into dft2b load)
  dft2b_kernel<<<NBATCH * NCH * NB, T, 0, stream>>>(HB, bnsc, Xf);
  xh_kernel<<<(NBATCH * NCH * NQ + T - 1) / T, T, 0, stream>>>(Xf, qw, dbeta, xh);
  wfft_kernel<<<(MM * NCH * NCH + T - 1) / T, T, 0, stream>>>(k3, NCH * NCH, Wf);
  hk_kernel<<<NBATCH * LL * MM, 64, 0, stream>>>(xh, deq, hk2);
  z_kernel<<<MM * MM, T, 0, stream>>>(hk2, Wf, zb);
  fjq_kernel<<<121 * 16, T, 0, stream>>>(zb, dbT, Fb);
  so3_dft_kernel<<<NBATCH * NCH * NB, T, 0, stream>>>(Fb, c3b, HA);
  bn_stats_kernel<<<NBATCH * NCH, T, 0, stream>>>(HA, parts);
  bn_finalize_kernel<<<1, 64, 0, stream>>>(parts, bn3g, bn3b, bnsc);

  // ---- head (bn3+relu fused into pool)
  pool_kernel<<<NBATCH * NCH, T, 0, stream>>>(HA, bnsc, pooled);
  head_kernel<<<1, T, 0, stream>>>(pooled, fc1w, fc1b, g1, bb1,
                                   fc2w, fc2b, g2, bb2, fc3w, fc3b, out);
}

// Round 6
// 1235.911 us; speedup vs baseline: 2.5670x; 1.0845x over previous
//
#include <hip/hip_runtime.h>
#include <math.h>

constexpr int NB = 32;       // samples per angle
constexpr int LL = 16;       // bandwidth
constexpr int MM = 31;       // spectral orders (2*BW-1)
constexpr int MOFF = 15;
constexpr int NBATCH = 8;
constexpr int NCH = 50;
constexpr int NQ = MM * MM;          // 961
constexpr int SPAT = NB * NB * NB;   // 32768
constexpr long long HN = (long long)NBATCH * NCH * SPAT;  // 13,107,200

#define PI_D 3.14159265358979323846

__device__ inline float2 c_mk(float x, float y) { float2 r; r.x = x; r.y = y; return r; }

__device__ inline void fill_tw(float2* tw) {
  int t = threadIdx.x;
  if (t < 32) {
    double a = (double)t * (PI_D / 16.0);
    tw[t] = c_mk((float)cos(a), (float)sin(a));
  }
}

__device__ inline double dpow(double x, int n) {
  double r = 1.0;
  for (int i = 0; i < n; ++i) r *= x;
  return r;
}

// ---------------- constants ----------------

__global__ void qw_kernel(float* __restrict__ qw) {
  int j = threadIdx.x;
  if (j >= NB) return;
  double beta = PI_D * (2 * j + 1) / 64.0;
  double acc = 0.0;
  for (int kk = 0; kk < LL; ++kk)
    acc += sin((double)(2 * j + 1) * (2 * kk + 1) * PI_D / 64.0) / (double)(2 * kk + 1);
  qw[j] = (float)((2.0 / 16.0) * sin(beta) * acc);
}

// out layout [j][l][mp][m]; eqmode: nj==1, beta=pi/2
__global__ void wigner_kernel(float* __restrict__ out, int nj, int eqmode) {
  __shared__ double fact[66];
  int tid = threadIdx.x;
  if (tid < 66) { double f = 1.0; for (int i = 2; i <= tid; ++i) f *= (double)i; fact[tid] = f; }
  __syncthreads();
  int total = nj * LL * NQ;
  int idx = blockIdx.x * blockDim.x + tid;
  if (idx >= total) return;
  int q = idx % NQ;
  int l = (idx / NQ) % LL;
  int j = idx / (NQ * LL);
  int mp = q / MM - MOFF;
  int m  = q % MM - MOFF;
  int amp = mp < 0 ? -mp : mp, am = m < 0 ? -m : m;
  float res = 0.f;
  if (amp <= l && am <= l) {
    double beta = eqmode ? (PI_D * 0.5) : (PI_D * (2 * j + 1) / 64.0);
    double c = cos(beta * 0.5), s = sin(beta * 0.5);
    double pref = sqrt(fact[l + mp] * fact[l - mp] * fact[l + m] * fact[l - m]);
    int k0 = max(0, m - mp), k1 = min(l + m, l - mp);
    double acc = 0.0;
    for (int k = k0; k <= k1; ++k) {
      double denom = fact[l + m - k] * fact[k] * fact[l - k - mp] * fact[k - m + mp];
      double term = dpow(c, 2 * l - 2 * k + m - mp) * dpow(s, 2 * k - m + mp) / denom;
      acc += ((mp - m + k) & 1) ? -term : term;
    }
    res = (float)(pref * acc);
  }
  out[idx] = res;
}

// dbT[j][l][n][m] = dbeta[j][l][m][n]
__global__ void transpose_d_kernel(const float* __restrict__ dbeta, float* __restrict__ dbT) {
  int idx = blockIdx.x * blockDim.x + threadIdx.x;
  if (idx >= NB * LL * NQ) return;
  int m = idx % MM;
  int n = (idx / MM) % MM;
  int jl = idx / NQ;
  dbT[idx] = dbeta[jl * NQ + m * MM + n];
}

// ---------------- layer 1 (S2 conv) ----------------

__global__ __launch_bounds__(256) void s2_xh_kernel(const float* __restrict__ x,
                                                    const float* __restrict__ qw,
                                                    const float* __restrict__ dbeta,
                                                    float2* __restrict__ xh1) {
  __shared__ float xt[NB * NB];
  __shared__ float2 Xf0[NB * MM];
  __shared__ float2 tw[32];
  fill_tw(tw);
  int tid = threadIdx.x, b = blockIdx.x;
  for (int e = tid; e < NB * NB; e += 256) xt[e] = x[b * 1024 + e];
  __syncthreads();
  for (int e = tid; e < NB * MM; e += 256) {
    int j = e / MM, mi = e % MM, m = mi - MOFF;
    float re = 0.f, im = 0.f;
    const float* row = xt + j * NB;
    for (int a = 0; a < NB; ++a) {
      float v = row[a];
      float2 t = tw[(m * a) & 31];
      re += v * t.x; im -= v * t.y;   // e^{-i m a th}
    }
    Xf0[e] = c_mk(re, im);
  }
  __syncthreads();
  for (int e = tid; e < LL * MM; e += 256) {
    int l = e / MM, mi = e % MM;
    float re = 0.f, im = 0.f;
    for (int j = 0; j < NB; ++j) {
      float w = qw[j] * dbeta[(j * LL + l) * NQ + mi * MM + MOFF];
      float2 X = Xf0[j * MM + mi];
      re += w * X.x; im += w * X.y;
    }
    xh1[(b * LL + l) * MM + mi] = c_mk(re, im);
  }
}

// Wf[ni][ic] = sum_t W[ic][t] e^{-2pi i n t/32}, ic = i*Co+o
__global__ __launch_bounds__(256) void wfft_kernel(const float* __restrict__ W, int CiCo,
                                                   float2* __restrict__ Wf) {
  __shared__ float2 tw[32];
  fill_tw(tw);
  __syncthreads();
  int idx = blockIdx.x * blockDim.x + threadIdx.x;
  if (idx >= MM * CiCo) return;
  int ni = idx / CiCo, ic = idx % CiCo;
  int n = ni - MOFF;
  float re = 0.f, im = 0.f;
  for (int t = 0; t < NB; ++t) {
    float v = W[ic * NB + t];
    float2 tt = tw[(n * t) & 31];
    re += v * tt.x; im -= v * tt.y;
  }
  Wf[idx] = c_mk(re, im);
}

// z layout: [b][o][l][ni][mi].  z = deq0[l,ni] * xh1[b,l,mi] * conj(Wf1[ni,o])
__global__ void s2_z_kernel(const float2* __restrict__ xh1, const float2* __restrict__ Wf1,
                            const float* __restrict__ deq, float2* __restrict__ z) {
  int idx = blockIdx.x * blockDim.x + threadIdx.x;
  if (idx >= NBATCH * NCH * LL * NQ) return;
  int mi = idx % MM; int t = idx / MM;
  int ni = t % MM; t /= MM;
  int l = t % LL; t /= LL;
  int o = t % NCH; int b = t / NCH;
  float d0 = deq[(l * MM + ni) * MM + MOFF];
  float2 xv = xh1[(b * LL + l) * MM + mi];
  float2 wv = Wf1[ni * NCH + o];
  float re = d0 * (xv.x * wv.x + xv.y * wv.y);
  float im = d0 * (xv.y * wv.x - xv.x * wv.y);
  z[idx] = c_mk(re, im);
}

// ---------------- SO(3) inverse transform: split into fjq + dft ----------------

// F[bo][j][q] = sum_l (2l+1) * d^l_{m,n}(beta_j) * z[bo][l][q], q = ni*31+mi.
__global__ __launch_bounds__(256) void fjq_kernel(const float2* __restrict__ z,
                                                  const float* __restrict__ dbT,
                                                  float2* __restrict__ F) {
  __shared__ float2 zs[2][LL][8];
  int qg = blockIdx.x % 121;
  int bg = blockIdx.x / 121;
  int tid = threadIdx.x;
  int j = tid >> 3, ql = tid & 7;
  int q = qg * 8 + ql;
  bool qok = q < NQ;
  int qc = qok ? q : NQ - 1;
  float w[LL];
  #pragma unroll
  for (int l = 0; l < LL; ++l)
    w[l] = (2.f * l + 1.f) * dbT[(j * LL + l) * NQ + qc];
  int bo0 = bg * 25;
  if (tid < 128) {
    int l = tid >> 3, qq = qg * 8 + (tid & 7);
    zs[0][l][tid & 7] = (qq < NQ) ? z[((long long)bo0 * LL + l) * NQ + qq] : c_mk(0.f, 0.f);
  }
  __syncthreads();
  for (int i = 0; i < 25; ++i) {
    int bo = bo0 + i;
    if (i < 24 && tid < 128) {
      int l = tid >> 3, qq = qg * 8 + (tid & 7);
      zs[(i + 1) & 1][l][tid & 7] =
          (qq < NQ) ? z[((long long)(bo + 1) * LL + l) * NQ + qq] : c_mk(0.f, 0.f);
    }
    float fr = 0.f, fi = 0.f;
    #pragma unroll
    for (int l = 0; l < LL; ++l) {
      float2 zv = zs[i & 1][l][ql];
      fr += w[l] * zv.x; fi += w[l] * zv.y;
    }
    if (qok) F[((long long)bo * NB + j) * NQ + q] = c_mk(fr, fi);
    __syncthreads();
  }
}

// One block per (bo, j): load F row, 2 LDS DFT phases with +/-16 decimation.
// Also accumulates per-block sum/sumsq of the produced tile into parts[bo]
// (bn_stats fused; parts must be zeroed before launch).
__global__ __launch_bounds__(256) void so3_dft_kernel(const float2* __restrict__ F,
                                                      const float* __restrict__ bias,
                                                      float* __restrict__ out,
                                                      float2* __restrict__ parts) {
  __shared__ float2 Fq[NQ];       // [ni][mi], 7.7 KB
  __shared__ float2 G[MM * NB];   // [m][g], 7.9 KB
  __shared__ float2 tw[32];
  __shared__ float red[256];
  fill_tw(tw);
  int tid = threadIdx.x;
  int blk = blockIdx.x;
  int j = blk & 31;
  int bo = blk >> 5;
  int o = bo % NCH;

  const float2* src = F + ((long long)bo * NB + j) * NQ;
  for (int e = tid; e < NQ; e += 256) Fq[e] = src[e];
  __syncthreads();

  // G[m,g] = sum_ni F[ni,m] e^{i(ni-15) g th}; g and g+16 together.
  for (int e = tid; e < MM * 16; e += 256) {
    int m = e >> 4, g = e & 15;
    float aex = 0.f, aey = 0.f, aox = 0.f, aoy = 0.f;
    #pragma unroll
    for (int p = 0; p < 15; ++p) {
      int ni = 2 * p;
      float2 f = Fq[ni * MM + m];
      float2 t = tw[((ni - 15) * g) & 31];
      aex += f.x * t.x - f.y * t.y;
      aey += f.x * t.y + f.y * t.x;
      float2 f2 = Fq[(ni + 1) * MM + m];
      float2 t2 = tw[((ni - 14) * g) & 31];
      aox += f2.x * t2.x - f2.y * t2.y;
      aoy += f2.x * t2.y + f2.y * t2.x;
    }
    { // ni = 30 (even)
      float2 f = Fq[30 * MM + m];
      float2 t = tw[(15 * g) & 31];
      aex += f.x * t.x - f.y * t.y;
      aey += f.x * t.y + f.y * t.x;
    }
    G[m * NB + g]      = c_mk(aex + aox, aey + aoy);
    G[m * NB + g + 16] = c_mk(aox - aex, aoy - aey);
  }
  __syncthreads();

  // out[a,g] = bias + Re sum_mi G[mi,g] e^{i(mi-15) a th}; a and a+16 together.
  float bval = bias[o];
  long long obase = (long long)bo * SPAT + (long long)j * 1024;
  float s1 = 0.f, s2 = 0.f;
  for (int e = tid; e < 16 * NB; e += 256) {
    int a = e >> 5, g = e & 31;
    float be = 0.f, bo_ = 0.f;
    #pragma unroll
    for (int p = 0; p < 15; ++p) {
      int mi = 2 * p;
      float2 gv = G[mi * NB + g];
      float2 t = tw[((mi - 15) * a) & 31];
      be += gv.x * t.x - gv.y * t.y;
      float2 gv2 = G[(mi + 1) * NB + g];
      float2 t2 = tw[((mi - 14) * a) & 31];
      bo_ += gv2.x * t2.x - gv2.y * t2.y;
    }
    { // mi = 30 (even)
      float2 gv = G[30 * NB + g];
      float2 t = tw[(15 * a) & 31];
      be += gv.x * t.x - gv.y * t.y;
    }
    float v0 = bval + be + bo_;
    float v1 = bval + bo_ - be;
    out[obase + a * 32 + g]        = v0;
    out[obase + (a + 16) * 32 + g] = v1;
    s1 += v0 + v1;
    s2 += v0 * v0 + v1 * v1;
  }
  // block reduction of (s1, s2) -> one atomic per block
  red[tid] = s1;
  __syncthreads();
  for (int st = 128; st > 0; st >>= 1) {
    if (tid < st) red[tid] += red[tid + st];
    __syncthreads();
  }
  float bs1 = red[0];
  __syncthreads();
  red[tid] = s2;
  __syncthreads();
  for (int st = 128; st > 0; st >>= 1) {
    if (tid < st) red[tid] += red[tid + st];
    __syncthreads();
  }
  if (tid == 0) {
    atomicAdd(&parts[bo].x, bs1);
    atomicAdd(&parts[bo].y, red[0]);
  }
}

// ---------------- batchnorm ----------------

__global__ void bn_finalize_kernel(const float2* __restrict__ partials,
                                   const float* __restrict__ g, const float* __restrict__ bb,
                                   float2* __restrict__ sc) {
  int o = threadIdx.x;
  if (o >= NCH) return;
  float s = 0.f, ss = 0.f;
  for (int b = 0; b < NBATCH; ++b) { float2 p = partials[b * NCH + o]; s += p.x; ss += p.y; }
  float inv = 1.f / (float)(NBATCH * SPAT);
  float mu = s * inv;
  float var = ss * inv - mu * mu;
  float scale = g[o] * rsqrtf(var + 1e-5f);
  sc[o] = c_mk(scale, bb[o] - mu * scale);
}

// ---------------- SO(3) conv ----------------

// 2D DFT of a real 32x32 tile -> 31x31 signed-order spectrum.
// Fused bn+relu applied on load (sc indexed by channel).
__global__ __launch_bounds__(256) void dft2b_kernel(const float* __restrict__ h,
                                                    const float2* __restrict__ sc,
                                                    float2* __restrict__ Xf) {
  __shared__ float xt[32 * 33];   // padded stride kills bank conflict
  __shared__ float2 P[32 * 16];   // [a][n], n = 0..15
  __shared__ float2 Xs[NQ];
  __shared__ float2 tw[32];
  fill_tw(tw);
  int tid = threadIdx.x;
  long long blk = blockIdx.x;
  int c = (int)((blk >> 5) % NCH);
  float2 s = sc[c];
  const float* src = h + blk * 1024;
  for (int e = tid; e < 1024; e += 256) {
    float v = src[e];
    xt[(e >> 5) * 33 + (e & 31)] = fmaxf(v * s.x + s.y, 0.f);
  }
  __syncthreads();
  // P[a,n] = sum_g x[a,g] e^{-i n g th}
  for (int e = tid; e < 512; e += 256) {
    int a = e >> 4, n = e & 15;
    float re = 0.f, im = 0.f;
    const float* row = xt + a * 33;
    #pragma unroll
    for (int g = 0; g < 32; ++g) {
      float v = row[g];
      float2 t = tw[(n * g) & 31];
      re += v * t.x; im -= v * t.y;
    }
    P[a * 16 + n] = c_mk(re, im);
  }
  __syncthreads();
  // X[m,n] = sum_a P[a,n] e^{-i m a th}; m=+mh and m=-mh together.
  {
    int e = tid;
    if (e < 256) {
      int mh = e >> 4, n = e & 15;
      float sxx = 0.f, sxy = 0.f, syx = 0.f, syy = 0.f;
      #pragma unroll
      for (int a = 0; a < 32; ++a) {
        float2 p = P[a * 16 + n];
        float2 t = tw[(mh * a) & 31];
        sxx += p.x * t.x; sxy += p.x * t.y;
        syx += p.y * t.x; syy += p.y * t.y;
      }
      float2 Xp = c_mk(sxx + syy, syx - sxy);   // X[+mh, n]
      float2 Xm = c_mk(sxx - syy, syx + sxy);   // X[-mh, n]
      Xs[(mh + MOFF) * MM + (n + MOFF)] = Xp;
      Xs[(MOFF - mh) * MM + (n + MOFF)] = Xm;
      Xs[(MOFF - mh) * MM + (MOFF - n)] = c_mk(Xp.x, -Xp.y);
      Xs[(mh + MOFF) * MM + (MOFF - n)] = c_mk(Xm.x, -Xm.y);
    }
  }
  __syncthreads();
  float2* dst = Xf + blk * NQ;
  for (int e = tid; e < NQ; e += 256) dst[e] = Xs[e];
}

// xh[bc,l,q] = sum_j qw[j]*dbeta[j,l,q]*Xf[bc,j,q]   (q = mi*MM+ni)
__global__ void xh_kernel(const float2* __restrict__ Xf, const float* __restrict__ qw,
                          const float* __restrict__ dbeta, float2* __restrict__ xh) {
  int idx = blockIdx.x * blockDim.x + threadIdx.x;
  if (idx >= NBATCH * NCH * NQ) return;
  int q = idx % NQ;
  int bc = idx / NQ;
  float2 acc[LL];
  #pragma unroll
  for (int l = 0; l < LL; ++l) acc[l] = c_mk(0.f, 0.f);
  for (int j = 0; j < NB; ++j) {
    float2 xv = Xf[((long long)bc * NB + j) * NQ + q];
    float qj = qw[j];
    const float* dbase = dbeta + (long long)(j * LL) * NQ + q;
    #pragma unroll
    for (int l = 0; l < LL; ++l) {
      float w = qj * dbase[l * NQ];
      acc[l].x += w * xv.x;
      acc[l].y += w * xv.y;
    }
  }
  #pragma unroll
  for (int l = 0; l < LL; ++l) xh[((long long)bc * LL + l) * NQ + q] = acc[l];
}

// hk2[r][ni][ich] = sum_k xh[(b*NCH+ich),l,mi,k] * deq[l,ni,k], r=(b*LL+l)*MM+mi.
__global__ __launch_bounds__(64) void hk_kernel(const float2* __restrict__ xh,
                                                const float* __restrict__ deq,
                                                float2* __restrict__ hk2) {
  int r = blockIdx.x;                 // 0..3967
  int mi = r % MM;
  int bl = r / MM;                    // b*LL + l
  int l = bl % LL;
  int b = bl / LL;
  int ich = threadIdx.x;
  if (ich >= NCH) return;
  float2 row[MM];
  const float2* src = xh + ((long long)(b * NCH + ich) * LL + l) * NQ + mi * MM;
  #pragma unroll
  for (int k = 0; k < MM; ++k) row[k] = src[k];
  const float* dl = deq + l * NQ;
  long long obase = (long long)r * MM * NCH + ich;
  for (int ni = 0; ni < MM; ++ni) {
    const float* dr = dl + ni * MM;
    float re = 0.f, im = 0.f;
    #pragma unroll
    for (int k = 0; k < MM; ++k) {
      float d = dr[k];
      re += d * row[k].x;
      im += d * row[k].y;
    }
    hk2[obase + (long long)ni * NCH] = c_mk(re, im);
  }
}

// z[b][o][l][ni][mi] = sum_i hk2[(r*31+ni)*50+i] * conj(Wf[ni,i,o]), r=(b,l,mi)
// Wf[ni] slice (50x50 float2 = 20 KB) staged in LDS; inner-loop w reads are
// wave-uniform broadcasts. hk2 float4 loads are the only VMEM in the loop.
__global__ __launch_bounds__(256) void z_kernel(const float2* __restrict__ hk2,
                                                const float2* __restrict__ Wf,
                                                float2* __restrict__ z) {
  __shared__ float2 ws[NCH * NCH];   // 20 KB
  int ni = blockIdx.x / MM;          // 0..30
  int rowtile = blockIdx.x % MM;     // 0..30
  int tid = threadIdx.x;
  {
    const float4* s4 = reinterpret_cast<const float4*>(Wf + ni * (NCH * NCH));
    float4* d4 = reinterpret_cast<float4*>(ws);
    for (int e = tid; e < NCH * NCH / 2; e += 256) d4[e] = s4[e];
  }
  __syncthreads();
  int r = rowtile * 128 + (tid & 127);   // 0..3967 = (b,l,mi)
  int o0 = (tid >> 7) * 25;
  int b = r / (LL * MM);
  int rem = r % (LL * MM);
  int l = rem / MM;
  int mi = rem % MM;

  const float4* h4 = reinterpret_cast<const float4*>(hk2 + ((long long)r * MM + ni) * NCH);

  float2 acc[25];
  #pragma unroll
  for (int u = 0; u < 25; ++u) acc[u] = c_mk(0.f, 0.f);

  for (int ih = 0; ih < 25; ++ih) {     // 2 channels per iteration
    float4 hv = h4[ih];
    const float2* w0 = ws + (2 * ih) * NCH + o0;
    #pragma unroll
    for (int u = 0; u < 25; ++u) {
      float2 w = w0[u];
      acc[u].x += hv.x * w.x + hv.y * w.y;
      acc[u].y += hv.y * w.x - hv.x * w.y;
    }
    const float2* w1 = w0 + NCH;
    #pragma unroll
    for (int u = 0; u < 25; ++u) {
      float2 w = w1[u];
      acc[u].x += hv.z * w.x + hv.w * w.y;
      acc[u].y += hv.w * w.x - hv.z * w.y;
    }
  }

  long long zb = (((long long)(b * NCH + o0) * LL + l) * NQ) + ni * MM + mi;
  #pragma unroll
  for (int u = 0; u < 25; ++u)
    z[zb + (long long)u * LL * NQ] = acc[u];
}

// ---------------- head ----------------

// pool with fused bn+relu (layer-3 scale/shift applied per element)
__global__ void pool_kernel(const float* __restrict__ h, const float2* __restrict__ sc,
                            float* __restrict__ pooled) {
  __shared__ float sm[256];
  int tid = threadIdx.x;
  int o = blockIdx.x % NCH;
  float2 s = sc[o];
  const float* base = h + (long long)blockIdx.x * SPAT;
  float best = -1e30f;
  for (int e = tid; e < 1024; e += 256) {
    float acc = 0.f;
    for (int g = 0; g < NB; ++g) {
      float v = base[e * NB + g];
      acc += fmaxf(v * s.x + s.y, 0.f);
    }
    best = fmaxf(best, acc * (1.f / 32.f));
  }
  sm[tid] = best;
  __syncthreads();
  for (int st = 128; st > 0; st >>= 1) {
    if (tid < st) sm[tid] = fmaxf(sm[tid], sm[tid + st]);
    __syncthreads();
  }
  if (tid == 0) pooled[blockIdx.x] = sm[0];
}

__global__ __launch_bounds__(256) void head_kernel(const float* __restrict__ pooled,
    const float* __restrict__ fc1w, const float* __restrict__ fc1b,
    const float* __restrict__ g1, const float* __restrict__ b1,
    const float* __restrict__ fc2w, const float* __restrict__ fc2b,
    const float* __restrict__ g2, const float* __restrict__ b2,
    const float* __restrict__ fc3w, const float* __restrict__ fc3b,
    float* __restrict__ out) {
  __shared__ float pin[NBATCH * NCH];
  __shared__ float A[NBATCH * 256];
  __shared__ float Bm[NBATCH * 128];
  __shared__ float Cm[NBATCH * 40];
  int tid = threadIdx.x;
  for (int e = tid; e < NBATCH * NCH; e += 256) pin[e] = pooled[e];
  __syncthreads();
  {
    float v[NBATCH];
    #pragma unroll
    for (int b = 0; b < NBATCH; ++b) {
      float acc = fc1b[tid];
      for (int c = 0; c < NCH; ++c) acc += pin[b * NCH + c] * fc1w[tid * NCH + c];
      v[b] = acc;
    }
    float s = 0.f, ss = 0.f;
    #pragma unroll
    for (int b = 0; b < NBATCH; ++b) { s += v[b]; ss += v[b] * v[b]; }
    float mu = s * 0.125f, var = ss * 0.125f - mu * mu;
    float sc = g1[tid] * rsqrtf(var + 1e-5f), sh = b1[tid] - mu * sc;
    #pragma unroll
    for (int b = 0; b < NBATCH; ++b) A[b * 256 + tid] = fmaxf(v[b] * sc + sh, 0.f);
  }
  __syncthreads();
  if (tid < 128) {
    float v[NBATCH];
    #pragma unroll
    for (int b = 0; b < NBATCH; ++b) {
      float acc = fc2b[tid];
      for (int c = 0; c < 256; ++c) acc += A[b * 256 + c] * fc2w[tid * 256 + c];
      v[b] = acc;
    }
    float s = 0.f, ss = 0.f;
    #pragma unroll
    for (int b = 0; b < NBATCH; ++b) { s += v[b]; ss += v[b] * v[b]; }
    float mu = s * 0.125f, var = ss * 0.125f - mu * mu;
    float sc = g2[tid] * rsqrtf(var + 1e-5f), sh = b2[tid] - mu * sc;
    #pragma unroll
    for (int b = 0; b < NBATCH; ++b) Bm[b * 128 + tid] = fmaxf(v[b] * sc + sh, 0.f);
  }
  __syncthreads();
  if (tid < 40) {
    #pragma unroll
    for (int b = 0; b < NBATCH; ++b) {
      float acc = fc3b[tid];
      for (int c = 0; c < 128; ++c) acc += Bm[b * 128 + c] * fc3w[tid * 128 + c];
      Cm[b * 40 + tid] = acc;
    }
  }
  __syncthreads();
  if (tid < NBATCH) {
    int b = tid;
    float mx = -1e30f;
    for (int f = 0; f < 40; ++f) mx = fmaxf(mx, Cm[b * 40 + f]);
    float se = 0.f;
    for (int f = 0; f < 40; ++f) se += expf(Cm[b * 40 + f] - mx);
    float lse = mx + logf(se);
    for (int f = 0; f < 40; ++f) out[b * 40 + f] = Cm[b * 40 + f] - lse;
  }
}

// ---------------- host ----------------

extern "C" void kernel_launch(void* const* d_in, const int* in_sizes, int n_in,
                              void* d_out, int out_size, void* d_ws, size_t ws_size,
                              hipStream_t stream) {
  (void)in_sizes; (void)n_in; (void)out_size;
  const float* x    = (const float*)d_in[0];
  const float* k1   = (const float*)d_in[1];
  const float* c1b  = (const float*)d_in[2];
  const float* bn1g = (const float*)d_in[3];
  const float* bn1b = (const float*)d_in[4];
  const float* k2   = (const float*)d_in[5];
  const float* c2b  = (const float*)d_in[6];
  const float* bn2g = (const float*)d_in[7];
  const float* bn2b = (const float*)d_in[8];
  const float* k3   = (const float*)d_in[9];
  const float* c3b  = (const float*)d_in[10];
  const float* bn3g = (const float*)d_in[11];
  const float* bn3b = (const float*)d_in[12];
  const float* fc1w = (const float*)d_in[13];
  const float* fc1b = (const float*)d_in[14];
  const float* g1   = (const float*)d_in[15];
  const float* bb1  = (const float*)d_in[16];
  const float* fc2w = (const float*)d_in[17];
  const float* fc2b = (const float*)d_in[18];
  const float* g2   = (const float*)d_in[19];
  const float* bb2  = (const float*)d_in[20];
  const float* fc3w = (const float*)d_in[21];
  const float* fc3b = (const float*)d_in[22];
  float* out = (float*)d_out;

  char* ws = (char*)d_ws;
  size_t off = 0;
  auto alloc = [&](size_t n) -> char* {
    char* p = ws + off;
    off += (n + 255) & ~(size_t)255;
    return p;
  };

  float*  dbeta  = (float*)alloc(sizeof(float) * NB * LL * NQ);      // 1.97 MB
  float*  dbT    = (float*)alloc(sizeof(float) * NB * LL * NQ);      // 1.97 MB
  float*  deq    = (float*)alloc(sizeof(float) * LL * NQ);
  float*  qw     = (float*)alloc(sizeof(float) * NB);
  float2* xh1    = (float2*)alloc(sizeof(float2) * NBATCH * LL * MM);
  float2* Wf     = (float2*)alloc(sizeof(float2) * MM * NCH * NCH);  // 620 KB
  float2* parts  = (float2*)alloc(sizeof(float2) * NBATCH * NCH);
  float2* bnsc   = (float2*)alloc(sizeof(float2) * 64);
  float*  pooled = (float*)alloc(sizeof(float) * NBATCH * NCH);
  float*  HA     = (float*)alloc(sizeof(float) * (size_t)HN);        // 52.4 MB
  float*  HB     = (float*)alloc(sizeof(float) * (size_t)HN);        // 52.4 MB
  size_t XFB = (size_t)NBATCH * NCH * NB * NQ * sizeof(float2);      // 98.4 MB
  size_t XHB = (size_t)NBATCH * NCH * LL * NQ * sizeof(float2);      // 49.2 MB
  char* AR = alloc(XFB + XHB);                                       // 147.6 MB arena
  float2* Xf  = (float2*)AR;           // live: dft2 -> xh
  float2* xh  = (float2*)(AR + XFB);   // live: xh -> hk
  float2* hk2 = (float2*)AR;           // live: hk -> z    (reuses dead Xf)
  float2* zb  = (float2*)(AR + XFB);   // live: z -> fjq   (reuses dead xh; also z1)
  float2* Fb  = (float2*)AR;           // live: fjq -> dft (reuses dead hk2/Xf; 98.4 MB exact)

  if (ws_size < off) return;  // insufficient scratch: leave d_out zeroed

  const int T = 256;
  const size_t PARTS_B = sizeof(float2) * NBATCH * NCH;
  // constants
  qw_kernel<<<1, 32, 0, stream>>>(qw);
  wigner_kernel<<<(NB * LL * NQ + T - 1) / T, T, 0, stream>>>(dbeta, NB, 0);
  wigner_kernel<<<(LL * NQ + T - 1) / T, T, 0, stream>>>(deq, 1, 1);
  transpose_d_kernel<<<(NB * LL * NQ + T - 1) / T, T, 0, stream>>>(dbeta, dbT);

  // ---- layer 1: S2 conv -> HA
  s2_xh_kernel<<<NBATCH, T, 0, stream>>>(x, qw, dbeta, xh1);
  wfft_kernel<<<(MM * 1 * NCH + T - 1) / T, T, 0, stream>>>(k1, 1 * NCH, Wf);
  s2_z_kernel<<<(NBATCH * NCH * LL * NQ + T - 1) / T, T, 0, stream>>>(xh1, Wf, deq, zb);
  fjq_kernel<<<121 * 16, T, 0, stream>>>(zb, dbT, Fb);
  hipMemsetAsync(parts, 0, PARTS_B, stream);
  so3_dft_kernel<<<NBATCH * NCH * NB, T, 0, stream>>>(Fb, c1b, HA, parts);
  bn_finalize_kernel<<<1, 64, 0, stream>>>(parts, bn1g, bn1b, bnsc);

  // ---- layer 2: SO(3) conv HA -> HB (bn1+relu fused into dft2b load)
  dft2b_kernel<<<NBATCH * NCH * NB, T, 0, stream>>>(HA, bnsc, Xf);
  xh_kernel<<<(NBATCH * NCH * NQ + T - 1) / T, T, 0, stream>>>(Xf, qw, dbeta, xh);
  wfft_kernel<<<(MM * NCH * NCH + T - 1) / T, T, 0, stream>>>(k2, NCH * NCH, Wf);
  hk_kernel<<<NBATCH * LL * MM, 64, 0, stream>>>(xh, deq, hk2);
  z_kernel<<<MM * MM, T, 0, stream>>>(hk2, Wf, zb);
  fjq_kernel<<<121 * 16, T, 0, stream>>>(zb, dbT, Fb);
  hipMemsetAsync(parts, 0, PARTS_B, stream);
  so3_dft_kernel<<<NBATCH * NCH * NB, T, 0, stream>>>(Fb, c2b, HB, parts);
  bn_finalize_kernel<<<1, 64, 0, stream>>>(parts, bn2g, bn2b, bnsc);

  // ---- layer 3: SO(3) conv HB -> HA (bn2+relu fused into dft2b load)
  dft2b_kernel<<<NBATCH * NCH * NB, T, 0, stream>>>(HB, bnsc, Xf);
  xh_kernel<<<(NBATCH * NCH * NQ + T - 1) / T, T, 0, stream>>>(Xf, qw, dbeta, xh);
  wfft_kernel<<<(MM * NCH * NCH + T - 1) / T, T, 0, stream>>>(k3, NCH * NCH, Wf);
  hk_kernel<<<NBATCH * LL * MM, 64, 0, stream>>>(xh, deq, hk2);
  z_kernel<<<MM * MM, T, 0, stream>>>(hk2, Wf, zb);
  fjq_kernel<<<121 * 16, T, 0, stream>>>(zb, dbT, Fb);
  hipMemsetAsync(parts, 0, PARTS_B, stream);
  so3_dft_kernel<<<NBATCH * NCH * NB, T, 0, stream>>>(Fb, c3b, HA, parts);
  bn_finalize_kernel<<<1, 64, 0, stream>>>(parts, bn3g, bn3b, bnsc);

  // ---- head (bn3+relu fused into pool)
  pool_kernel<<<NBATCH * NCH, T, 0, stream>>>(HA, bnsc, pooled);
  head_kernel<<<1, T, 0, stream>>>(pooled, fc1w, fc1b, g1, bb1,
                                   fc2w, fc2b, g2, bb2, fc3w, fc3b, out);
}

// Round 7
// 1031.203 us; speedup vs baseline: 3.0766x; 1.1985x over previous
//
#include <hip/hip_runtime.h>
#include <math.h>

constexpr int NB = 32;       // samples per angle
constexpr int LL = 16;       // bandwidth
constexpr int MM = 31;       // spectral orders (2*BW-1)
constexpr int MOFF = 15;
constexpr int NBATCH = 8;
constexpr int NCH = 50;
constexpr int NQ = MM * MM;          // 961
constexpr int SPAT = NB * NB * NB;   // 32768
constexpr long long HN = (long long)NBATCH * NCH * SPAT;  // 13,107,200

#define PI_D 3.14159265358979323846

__device__ inline float2 c_mk(float x, float y) { float2 r; r.x = x; r.y = y; return r; }

__device__ inline void fill_tw(float2* tw) {
  int t = threadIdx.x;
  if (t < 32) {
    double a = (double)t * (PI_D / 16.0);
    tw[t] = c_mk((float)cos(a), (float)sin(a));
  }
}

__device__ inline int bitrev5(int n) {
  return ((n & 1) << 4) | ((n & 2) << 2) | (n & 4) | ((n & 8) >> 2) | ((n & 16) >> 4);
}

__device__ inline double dpow(double x, int n) {
  double r = 1.0;
  for (int i = 0; i < n; ++i) r *= x;
  return r;
}

// ---------------- constants ----------------

__global__ void qw_kernel(float* __restrict__ qw) {
  int j = threadIdx.x;
  if (j >= NB) return;
  double beta = PI_D * (2 * j + 1) / 64.0;
  double acc = 0.0;
  for (int kk = 0; kk < LL; ++kk)
    acc += sin((double)(2 * j + 1) * (2 * kk + 1) * PI_D / 64.0) / (double)(2 * kk + 1);
  qw[j] = (float)((2.0 / 16.0) * sin(beta) * acc);
}

// out layout [j][l][mp][m]; eqmode: nj==1, beta=pi/2
__global__ void wigner_kernel(float* __restrict__ out, int nj, int eqmode) {
  __shared__ double fact[66];
  int tid = threadIdx.x;
  if (tid < 66) { double f = 1.0; for (int i = 2; i <= tid; ++i) f *= (double)i; fact[tid] = f; }
  __syncthreads();
  int total = nj * LL * NQ;
  int idx = blockIdx.x * blockDim.x + tid;
  if (idx >= total) return;
  int q = idx % NQ;
  int l = (idx / NQ) % LL;
  int j = idx / (NQ * LL);
  int mp = q / MM - MOFF;
  int m  = q % MM - MOFF;
  int amp = mp < 0 ? -mp : mp, am = m < 0 ? -m : m;
  float res = 0.f;
  if (amp <= l && am <= l) {
    double beta = eqmode ? (PI_D * 0.5) : (PI_D * (2 * j + 1) / 64.0);
    double c = cos(beta * 0.5), s = sin(beta * 0.5);
    double pref = sqrt(fact[l + mp] * fact[l - mp] * fact[l + m] * fact[l - m]);
    int k0 = max(0, m - mp), k1 = min(l + m, l - mp);
    double acc = 0.0;
    for (int k = k0; k <= k1; ++k) {
      double denom = fact[l + m - k] * fact[k] * fact[l - k - mp] * fact[k - m + mp];
      double term = dpow(c, 2 * l - 2 * k + m - mp) * dpow(s, 2 * k - m + mp) / denom;
      acc += ((mp - m + k) & 1) ? -term : term;
    }
    res = (float)(pref * acc);
  }
  out[idx] = res;
}

// dbT[j][l][n][m] = dbeta[j][l][m][n]
__global__ void transpose_d_kernel(const float* __restrict__ dbeta, float* __restrict__ dbT) {
  int idx = blockIdx.x * blockDim.x + threadIdx.x;
  if (idx >= NB * LL * NQ) return;
  int m = idx % MM;
  int n = (idx / MM) % MM;
  int jl = idx / NQ;
  dbT[idx] = dbeta[jl * NQ + m * MM + n];
}

// ---------------- layer 1 (S2 conv) ----------------

__global__ __launch_bounds__(256) void s2_xh_kernel(const float* __restrict__ x,
                                                    const float* __restrict__ qw,
                                                    const float* __restrict__ dbeta,
                                                    float2* __restrict__ xh1) {
  __shared__ float xt[NB * NB];
  __shared__ float2 Xf0[NB * MM];
  __shared__ float2 tw[32];
  fill_tw(tw);
  int tid = threadIdx.x, b = blockIdx.x;
  for (int e = tid; e < NB * NB; e += 256) xt[e] = x[b * 1024 + e];
  __syncthreads();
  for (int e = tid; e < NB * MM; e += 256) {
    int j = e / MM, mi = e % MM, m = mi - MOFF;
    float re = 0.f, im = 0.f;
    const float* row = xt + j * NB;
    for (int a = 0; a < NB; ++a) {
      float v = row[a];
      float2 t = tw[(m * a) & 31];
      re += v * t.x; im -= v * t.y;   // e^{-i m a th}
    }
    Xf0[e] = c_mk(re, im);
  }
  __syncthreads();
  for (int e = tid; e < LL * MM; e += 256) {
    int l = e / MM, mi = e % MM;
    float re = 0.f, im = 0.f;
    for (int j = 0; j < NB; ++j) {
      float w = qw[j] * dbeta[(j * LL + l) * NQ + mi * MM + MOFF];
      float2 X = Xf0[j * MM + mi];
      re += w * X.x; im += w * X.y;
    }
    xh1[(b * LL + l) * MM + mi] = c_mk(re, im);
  }
}

// Wf[ni][ic] = sum_t W[ic][t] e^{-2pi i n t/32}, ic = i*Co+o
__global__ __launch_bounds__(256) void wfft_kernel(const float* __restrict__ W, int CiCo,
                                                   float2* __restrict__ Wf) {
  __shared__ float2 tw[32];
  fill_tw(tw);
  __syncthreads();
  int idx = blockIdx.x * blockDim.x + threadIdx.x;
  if (idx >= MM * CiCo) return;
  int ni = idx / CiCo, ic = idx % CiCo;
  int n = ni - MOFF;
  float re = 0.f, im = 0.f;
  for (int t = 0; t < NB; ++t) {
    float v = W[ic * NB + t];
    float2 tt = tw[(n * t) & 31];
    re += v * tt.x; im -= v * tt.y;
  }
  Wf[idx] = c_mk(re, im);
}

// z layout: [b][o][l][ni][mi].  z = deq0[l,ni] * xh1[b,l,mi] * conj(Wf1[ni,o])
__global__ void s2_z_kernel(const float2* __restrict__ xh1, const float2* __restrict__ Wf1,
                            const float* __restrict__ deq, float2* __restrict__ z) {
  int idx = blockIdx.x * blockDim.x + threadIdx.x;
  if (idx >= NBATCH * NCH * LL * NQ) return;
  int mi = idx % MM; int t = idx / MM;
  int ni = t % MM; t /= MM;
  int l = t % LL; t /= LL;
  int o = t % NCH; int b = t / NCH;
  float d0 = deq[(l * MM + ni) * MM + MOFF];
  float2 xv = xh1[(b * LL + l) * MM + mi];
  float2 wv = Wf1[ni * NCH + o];
  float re = d0 * (xv.x * wv.x + xv.y * wv.y);
  float im = d0 * (xv.y * wv.x - xv.x * wv.y);
  z[idx] = c_mk(re, im);
}

// ---------------- SO(3) inverse transform: split into fjq + dft ----------------

// F[bo][j][q] = sum_l (2l+1) * d^l_{m,n}(beta_j) * z[bo][l][q], q = ni*31+mi.
__global__ __launch_bounds__(256) void fjq_kernel(const float2* __restrict__ z,
                                                  const float* __restrict__ dbT,
                                                  float2* __restrict__ F) {
  __shared__ float2 zs[2][LL][8];
  int qg = blockIdx.x % 121;
  int bg = blockIdx.x / 121;
  int tid = threadIdx.x;
  int j = tid >> 3, ql = tid & 7;
  int q = qg * 8 + ql;
  bool qok = q < NQ;
  int qc = qok ? q : NQ - 1;
  float w[LL];
  #pragma unroll
  for (int l = 0; l < LL; ++l)
    w[l] = (2.f * l + 1.f) * dbT[(j * LL + l) * NQ + qc];
  int bo0 = bg * 25;
  if (tid < 128) {
    int l = tid >> 3, qq = qg * 8 + (tid & 7);
    zs[0][l][tid & 7] = (qq < NQ) ? z[((long long)bo0 * LL + l) * NQ + qq] : c_mk(0.f, 0.f);
  }
  __syncthreads();
  for (int i = 0; i < 25; ++i) {
    int bo = bo0 + i;
    if (i < 24 && tid < 128) {
      int l = tid >> 3, qq = qg * 8 + (tid & 7);
      zs[(i + 1) & 1][l][tid & 7] =
          (qq < NQ) ? z[((long long)(bo + 1) * LL + l) * NQ + qq] : c_mk(0.f, 0.f);
    }
    float fr = 0.f, fi = 0.f;
    #pragma unroll
    for (int l = 0; l < LL; ++l) {
      float2 zv = zs[i & 1][l][ql];
      fr += w[l] * zv.x; fi += w[l] * zv.y;
    }
    if (qok) F[((long long)bo * NB + j) * NQ + q] = c_mk(fr, fi);
    __syncthreads();
  }
}

// One block per (bo, j): bin-map F row into a 32x32 grid, then two radix-2
// 32-point DIF FFTs (sign +i) along each dim in LDS. Outputs come out
// bit-reversed in both indices; un-reversed at the final coalesced store.
// Also accumulates per-(bo) sum/sumsq into parts (bn_stats fused).
__global__ __launch_bounds__(256) void so3_dft_kernel(const float2* __restrict__ F,
                                                      const float* __restrict__ bias,
                                                      float* __restrict__ out,
                                                      float2* __restrict__ parts) {
  __shared__ float2 S[32][33];    // padded: 8.25 KB
  __shared__ float2 tw[32];
  __shared__ float red[256];
  fill_tw(tw);
  int tid = threadIdx.x;
  int blk = blockIdx.x;
  int j = blk & 31;
  int bo = blk >> 5;
  int o = bo % NCH;

  // zero grid (rows/cols for bin 16 stay zero)
  for (int e = tid; e < 32 * 33; e += 256) (&S[0][0])[e] = c_mk(0.f, 0.f);
  __syncthreads();
  // load F row, bin-mapped: S[(ni-15)&31][(mi-15)&31]
  const float2* src = F + ((long long)bo * NB + j) * NQ;
  for (int e = tid; e < NQ; e += 256) {
    int ni = e / MM, mi = e % MM;
    S[(ni + 17) & 31][(mi + 17) & 31] = src[e];
  }
  __syncthreads();

  // Phase A: FFT along dim0 (32 independent columns). DIF, w = e^{+2pi i /len}.
  #pragma unroll
  for (int st = 0; st < 5; ++st) {
    int half = 16 >> st;           // len/2
    int tmul = 1 << st;            // 32/len
    #pragma unroll
    for (int rep = 0; rep < 2; ++rep) {
      int e = tid + rep * 256;
      int col = e & 31;
      int p = e >> 5;                               // 0..15
      int j2 = p & (half - 1);
      int i0 = ((p >> (4 - st)) << (5 - st)) + j2;
      int i1 = i0 + half;
      float2 u = S[i0][col], v = S[i1][col];
      float2 t = tw[(j2 * tmul) & 31];
      float2 d = c_mk(u.x - v.x, u.y - v.y);
      S[i0][col] = c_mk(u.x + v.x, u.y + v.y);
      S[i1][col] = c_mk(d.x * t.x - d.y * t.y, d.x * t.y + d.y * t.x);
    }
    __syncthreads();
  }

  // Phase B: FFT along dim1 (32 independent rows).
  #pragma unroll
  for (int st = 0; st < 5; ++st) {
    int half = 16 >> st;
    int tmul = 1 << st;
    #pragma unroll
    for (int rep = 0; rep < 2; ++rep) {
      int e = tid + rep * 256;
      int row = e & 31;
      int p = e >> 5;
      int j2 = p & (half - 1);
      int i0 = ((p >> (4 - st)) << (5 - st)) + j2;
      int i1 = i0 + half;
      float2 u = S[row][i0], v = S[row][i1];
      float2 t = tw[(j2 * tmul) & 31];
      float2 d = c_mk(u.x - v.x, u.y - v.y);
      S[row][i0] = c_mk(u.x + v.x, u.y + v.y);
      S[row][i1] = c_mk(d.x * t.x - d.y * t.y, d.x * t.y + d.y * t.x);
    }
    __syncthreads();
  }

  // out[a,g] = Re S[rev(g)][rev(a)] + bias; fused bn stats.
  float bval = bias[o];
  long long obase = (long long)bo * SPAT + (long long)j * 1024;
  float s1 = 0.f, s2 = 0.f;
  for (int e = tid; e < 1024; e += 256) {
    int a = e >> 5, g = e & 31;
    float v = S[bitrev5(g)][bitrev5(a)].x + bval;
    out[obase + e] = v;
    s1 += v;
    s2 += v * v;
  }
  // block reduction of (s1, s2) -> one atomic per block
  red[tid] = s1;
  __syncthreads();
  for (int st = 128; st > 0; st >>= 1) {
    if (tid < st) red[tid] += red[tid + st];
    __syncthreads();
  }
  float bs1 = red[0];
  __syncthreads();
  red[tid] = s2;
  __syncthreads();
  for (int st = 128; st > 0; st >>= 1) {
    if (tid < st) red[tid] += red[tid + st];
    __syncthreads();
  }
  if (tid == 0) {
    atomicAdd(&parts[bo].x, bs1);
    atomicAdd(&parts[bo].y, red[0]);
  }
}

// ---------------- batchnorm ----------------

__global__ void bn_finalize_kernel(const float2* __restrict__ partials,
                                   const float* __restrict__ g, const float* __restrict__ bb,
                                   float2* __restrict__ sc) {
  int o = threadIdx.x;
  if (o >= NCH) return;
  float s = 0.f, ss = 0.f;
  for (int b = 0; b < NBATCH; ++b) { float2 p = partials[b * NCH + o]; s += p.x; ss += p.y; }
  float inv = 1.f / (float)(NBATCH * SPAT);
  float mu = s * inv;
  float var = ss * inv - mu * mu;
  float scale = g[o] * rsqrtf(var + 1e-5f);
  sc[o] = c_mk(scale, bb[o] - mu * scale);
}

// ---------------- SO(3) conv ----------------

// 2D DFT of a real 32x32 tile -> 31x31 signed-order spectrum.
// Fused bn+relu applied on load (sc indexed by channel).
__global__ __launch_bounds__(256) void dft2b_kernel(const float* __restrict__ h,
                                                    const float2* __restrict__ sc,
                                                    float2* __restrict__ Xf) {
  __shared__ float xt[32 * 33];   // padded stride kills bank conflict
  __shared__ float2 P[32 * 16];   // [a][n], n = 0..15
  __shared__ float2 Xs[NQ];
  __shared__ float2 tw[32];
  fill_tw(tw);
  int tid = threadIdx.x;
  long long blk = blockIdx.x;
  int c = (int)((blk >> 5) % NCH);
  float2 s = sc[c];
  const float* src = h + blk * 1024;
  for (int e = tid; e < 1024; e += 256) {
    float v = src[e];
    xt[(e >> 5) * 33 + (e & 31)] = fmaxf(v * s.x + s.y, 0.f);
  }
  __syncthreads();
  // P[a,n] = sum_g x[a,g] e^{-i n g th}
  for (int e = tid; e < 512; e += 256) {
    int a = e >> 4, n = e & 15;
    float re = 0.f, im = 0.f;
    const float* row = xt + a * 33;
    #pragma unroll
    for (int g = 0; g < 32; ++g) {
      float v = row[g];
      float2 t = tw[(n * g) & 31];
      re += v * t.x; im -= v * t.y;
    }
    P[a * 16 + n] = c_mk(re, im);
  }
  __syncthreads();
  // X[m,n] = sum_a P[a,n] e^{-i m a th}; m=+mh and m=-mh together.
  {
    int e = tid;
    if (e < 256) {
      int mh = e >> 4, n = e & 15;
      float sxx = 0.f, sxy = 0.f, syx = 0.f, syy = 0.f;
      #pragma unroll
      for (int a = 0; a < 32; ++a) {
        float2 p = P[a * 16 + n];
        float2 t = tw[(mh * a) & 31];
        sxx += p.x * t.x; sxy += p.x * t.y;
        syx += p.y * t.x; syy += p.y * t.y;
      }
      float2 Xp = c_mk(sxx + syy, syx - sxy);   // X[+mh, n]
      float2 Xm = c_mk(sxx - syy, syx + sxy);   // X[-mh, n]
      Xs[(mh + MOFF) * MM + (n + MOFF)] = Xp;
      Xs[(MOFF - mh) * MM + (n + MOFF)] = Xm;
      Xs[(MOFF - mh) * MM + (MOFF - n)] = c_mk(Xp.x, -Xp.y);
      Xs[(mh + MOFF) * MM + (MOFF - n)] = c_mk(Xm.x, -Xm.y);
    }
  }
  __syncthreads();
  float2* dst = Xf + blk * NQ;
  for (int e = tid; e < NQ; e += 256) dst[e] = Xs[e];
}

// xh[bc,l,q] = sum_j qw[j]*dbeta[j,l,q]*Xf[bc,j,q]   (q = mi*MM+ni)
__global__ void xh_kernel(const float2* __restrict__ Xf, const float* __restrict__ qw,
                          const float* __restrict__ dbeta, float2* __restrict__ xh) {
  int idx = blockIdx.x * blockDim.x + threadIdx.x;
  if (idx >= NBATCH * NCH * NQ) return;
  int q = idx % NQ;
  int bc = idx / NQ;
  float2 acc[LL];
  #pragma unroll
  for (int l = 0; l < LL; ++l) acc[l] = c_mk(0.f, 0.f);
  for (int j = 0; j < NB; ++j) {
    float2 xv = Xf[((long long)bc * NB + j) * NQ + q];
    float qj = qw[j];
    const float* dbase = dbeta + (long long)(j * LL) * NQ + q;
    #pragma unroll
    for (int l = 0; l < LL; ++l) {
      float w = qj * dbase[l * NQ];
      acc[l].x += w * xv.x;
      acc[l].y += w * xv.y;
    }
  }
  #pragma unroll
  for (int l = 0; l < LL; ++l) xh[((long long)bc * LL + l) * NQ + q] = acc[l];
}

// hk2[r][ni][ich] = sum_k xh[(b*NCH+ich),l,mi,k] * deq[l,ni,k], r=(b*LL+l)*MM+mi.
__global__ __launch_bounds__(64) void hk_kernel(const float2* __restrict__ xh,
                                                const float* __restrict__ deq,
                                                float2* __restrict__ hk2) {
  int r = blockIdx.x;                 // 0..3967
  int mi = r % MM;
  int bl = r / MM;                    // b*LL + l
  int l = bl % LL;
  int b = bl / LL;
  int ich = threadIdx.x;
  if (ich >= NCH) return;
  float2 row[MM];
  const float2* src = xh + ((long long)(b * NCH + ich) * LL + l) * NQ + mi * MM;
  #pragma unroll
  for (int k = 0; k < MM; ++k) row[k] = src[k];
  const float* dl = deq + l * NQ;
  long long obase = (long long)r * MM * NCH + ich;
  for (int ni = 0; ni < MM; ++ni) {
    const float* dr = dl + ni * MM;
    float re = 0.f, im = 0.f;
    #pragma unroll
    for (int k = 0; k < MM; ++k) {
      float d = dr[k];
      re += d * row[k].x;
      im += d * row[k].y;
    }
    hk2[obase + (long long)ni * NCH] = c_mk(re, im);
  }
}

// z[b][o][l][ni][mi] = sum_i hk2[(r*31+ni)*50+i] * conj(Wf[ni,i,o]), r=(b,l,mi)
// Wf[ni] slice (50x50 float2 = 20 KB) staged in LDS; inner-loop w reads are
// wave-uniform broadcasts. hk2 float4 loads are the only VMEM in the loop.
__global__ __launch_bounds__(256) void z_kernel(const float2* __restrict__ hk2,
                                                const float2* __restrict__ Wf,
                                                float2* __restrict__ z) {
  __shared__ float2 ws[NCH * NCH];   // 20 KB
  int ni = blockIdx.x / MM;          // 0..30
  int rowtile = blockIdx.x % MM;     // 0..30
  int tid = threadIdx.x;
  {
    const float4* s4 = reinterpret_cast<const float4*>(Wf + ni * (NCH * NCH));
    float4* d4 = reinterpret_cast<float4*>(ws);
    for (int e = tid; e < NCH * NCH / 2; e += 256) d4[e] = s4[e];
  }
  __syncthreads();
  int r = rowtile * 128 + (tid & 127);   // 0..3967 = (b,l,mi)
  int o0 = (tid >> 7) * 25;
  int b = r / (LL * MM);
  int rem = r % (LL * MM);
  int l = rem / MM;
  int mi = rem % MM;

  const float4* h4 = reinterpret_cast<const float4*>(hk2 + ((long long)r * MM + ni) * NCH);

  float2 acc[25];
  #pragma unroll
  for (int u = 0; u < 25; ++u) acc[u] = c_mk(0.f, 0.f);

  for (int ih = 0; ih < 25; ++ih) {     // 2 channels per iteration
    float4 hv = h4[ih];
    const float2* w0 = ws + (2 * ih) * NCH + o0;
    #pragma unroll
    for (int u = 0; u < 25; ++u) {
      float2 w = w0[u];
      acc[u].x += hv.x * w.x + hv.y * w.y;
      acc[u].y += hv.y * w.x - hv.x * w.y;
    }
    const float2* w1 = w0 + NCH;
    #pragma unroll
    for (int u = 0; u < 25; ++u) {
      float2 w = w1[u];
      acc[u].x += hv.z * w.x + hv.w * w.y;
      acc[u].y += hv.w * w.x - hv.z * w.y;
    }
  }

  long long zb = (((long long)(b * NCH + o0) * LL + l) * NQ) + ni * MM + mi;
  #pragma unroll
  for (int u = 0; u < 25; ++u)
    z[zb + (long long)u * LL * NQ] = acc[u];
}

// ---------------- head ----------------

// pool with fused bn+relu (layer-3 scale/shift applied per element)
__global__ void pool_kernel(const float* __restrict__ h, const float2* __restrict__ sc,
                            float* __restrict__ pooled) {
  __shared__ float sm[256];
  int tid = threadIdx.x;
  int o = blockIdx.x % NCH;
  float2 s = sc[o];
  const float* base = h + (long long)blockIdx.x * SPAT;
  float best = -1e30f;
  for (int e = tid; e < 1024; e += 256) {
    float acc = 0.f;
    for (int g = 0; g < NB; ++g) {
      float v = base[e * NB + g];
      acc += fmaxf(v * s.x + s.y, 0.f);
    }
    best = fmaxf(best, acc * (1.f / 32.f));
  }
  sm[tid] = best;
  __syncthreads();
  for (int st = 128; st > 0; st >>= 1) {
    if (tid < st) sm[tid] = fmaxf(sm[tid], sm[tid + st]);
    __syncthreads();
  }
  if (tid == 0) pooled[blockIdx.x] = sm[0];
}

__global__ __launch_bounds__(256) void head_kernel(const float* __restrict__ pooled,
    const float* __restrict__ fc1w, const float* __restrict__ fc1b,
    const float* __restrict__ g1, const float* __restrict__ b1,
    const float* __restrict__ fc2w, const float* __restrict__ fc2b,
    const float* __restrict__ g2, const float* __restrict__ b2,
    const float* __restrict__ fc3w, const float* __restrict__ fc3b,
    float* __restrict__ out) {
  __shared__ float pin[NBATCH * NCH];
  __shared__ float A[NBATCH * 256];
  __shared__ float Bm[NBATCH * 128];
  __shared__ float Cm[NBATCH * 40];
  int tid = threadIdx.x;
  for (int e = tid; e < NBATCH * NCH; e += 256) pin[e] = pooled[e];
  __syncthreads();
  {
    float v[NBATCH];
    #pragma unroll
    for (int b = 0; b < NBATCH; ++b) {
      float acc = fc1b[tid];
      for (int c = 0; c < NCH; ++c) acc += pin[b * NCH + c] * fc1w[tid * NCH + c];
      v[b] = acc;
    }
    float s = 0.f, ss = 0.f;
    #pragma unroll
    for (int b = 0; b < NBATCH; ++b) { s += v[b]; ss += v[b] * v[b]; }
    float mu = s * 0.125f, var = ss * 0.125f - mu * mu;
    float sc = g1[tid] * rsqrtf(var + 1e-5f), sh = b1[tid] - mu * sc;
    #pragma unroll
    for (int b = 0; b < NBATCH; ++b) A[b * 256 + tid] = fmaxf(v[b] * sc + sh, 0.f);
  }
  __syncthreads();
  if (tid < 128) {
    float v[NBATCH];
    #pragma unroll
    for (int b = 0; b < NBATCH; ++b) {
      float acc = fc2b[tid];
      for (int c = 0; c < 256; ++c) acc += A[b * 256 + c] * fc2w[tid * 256 + c];
      v[b] = acc;
    }
    float s = 0.f, ss = 0.f;
    #pragma unroll
    for (int b = 0; b < NBATCH; ++b) { s += v[b]; ss += v[b] * v[b]; }
    float mu = s * 0.125f, var = ss * 0.125f - mu * mu;
    float sc = g2[tid] * rsqrtf(var + 1e-5f), sh = b2[tid] - mu * sc;
    #pragma unroll
    for (int b = 0; b < NBATCH; ++b) Bm[b * 128 + tid] = fmaxf(v[b] * sc + sh, 0.f);
  }
  __syncthreads();
  if (tid < 40) {
    #pragma unroll
    for (int b = 0; b < NBATCH; ++b) {
      float acc = fc3b[tid];
      for (int c = 0; c < 128; ++c) acc += Bm[b * 128 + c] * fc3w[tid * 128 + c];
      Cm[b * 40 + tid] = acc;
    }
  }
  __syncthreads();
  if (tid < NBATCH) {
    int b = tid;
    float mx = -1e30f;
    for (int f = 0; f < 40; ++f) mx = fmaxf(mx, Cm[b * 40 + f]);
    float se = 0.f;
    for (int f = 0; f < 40; ++f) se += expf(Cm[b * 40 + f] - mx);
    float lse = mx + logf(se);
    for (int f = 0; f < 40; ++f) out[b * 40 + f] = Cm[b * 40 + f] - lse;
  }
}

// ---------------- host ----------------

extern "C" void kernel_launch(void* const* d_in, const int* in_sizes, int n_in,
                              void* d_out, int out_size, void* d_ws, size_t ws_size,
                              hipStream_t stream) {
  (void)in_sizes; (void)n_in; (void)out_size;
  const float* x    = (const float*)d_in[0];
  const float* k1   = (const float*)d_in[1];
  const float* c1b  = (const float*)d_in[2];
  const float* bn1g = (const float*)d_in[3];
  const float* bn1b = (const float*)d_in[4];
  const float* k2   = (const float*)d_in[5];
  const float* c2b  = (const float*)d_in[6];
  const float* bn2g = (const float*)d_in[7];
  const float* bn2b = (const float*)d_in[8];
  const float* k3   = (const float*)d_in[9];
  const float* c3b  = (const float*)d_in[10];
  const float* bn3g = (const float*)d_in[11];
  const float* bn3b = (const float*)d_in[12];
  const float* fc1w = (const float*)d_in[13];
  const float* fc1b = (const float*)d_in[14];
  const float* g1   = (const float*)d_in[15];
  const float* bb1  = (const float*)d_in[16];
  const float* fc2w = (const float*)d_in[17];
  const float* fc2b = (const float*)d_in[18];
  const float* g2   = (const float*)d_in[19];
  const float* bb2  = (const float*)d_in[20];
  const float* fc3w = (const float*)d_in[21];
  const float* fc3b = (const float*)d_in[22];
  float* out = (float*)d_out;

  char* ws = (char*)d_ws;
  size_t off = 0;
  auto alloc = [&](size_t n) -> char* {
    char* p = ws + off;
    off += (n + 255) & ~(size_t)255;
    return p;
  };

  float*  dbeta  = (float*)alloc(sizeof(float) * NB * LL * NQ);      // 1.97 MB
  float*  dbT    = (float*)alloc(sizeof(float) * NB * LL * NQ);      // 1.97 MB
  float*  deq    = (float*)alloc(sizeof(float) * LL * NQ);
  float*  qw     = (float*)alloc(sizeof(float) * NB);
  float2* xh1    = (float2*)alloc(sizeof(float2) * NBATCH * LL * MM);
  float2* Wf     = (float2*)alloc(sizeof(float2) * MM * NCH * NCH);  // 620 KB
  float2* parts  = (float2*)alloc(sizeof(float2) * NBATCH * NCH);
  float2* bnsc   = (float2*)alloc(sizeof(float2) * 64);
  float*  pooled = (float*)alloc(sizeof(float) * NBATCH * NCH);
  float*  HA     = (float*)alloc(sizeof(float) * (size_t)HN);        // 52.4 MB
  float*  HB     = (float*)alloc(sizeof(float) * (size_t)HN);        // 52.4 MB
  size_t XFB = (size_t)NBATCH * NCH * NB * NQ * sizeof(float2);      // 98.4 MB
  size_t XHB = (size_t)NBATCH * NCH * LL * NQ * sizeof(float2);      // 49.2 MB
  char* AR = alloc(XFB + XHB);                                       // 147.6 MB arena
  float2* Xf  = (float2*)AR;           // live: dft2 -> xh
  float2* xh  = (float2*)(AR + XFB);   // live: xh -> hk
  float2* hk2 = (float2*)AR;           // live: hk -> z    (reuses dead Xf)
  float2* zb  = (float2*)(AR + XFB);   // live: z -> fjq   (reuses dead xh; also z1)
  float2* Fb  = (float2*)AR;           // live: fjq -> dft (reuses dead hk2/Xf; 98.4 MB exact)

  if (ws_size < off) return;  // insufficient scratch: leave d_out zeroed

  const int T = 256;
  const size_t PARTS_B = sizeof(float2) * NBATCH * NCH;
  // constants
  qw_kernel<<<1, 32, 0, stream>>>(qw);
  wigner_kernel<<<(NB * LL * NQ + T - 1) / T, T, 0, stream>>>(dbeta, NB, 0);
  wigner_kernel<<<(LL * NQ + T - 1) / T, T, 0, stream>>>(deq, 1, 1);
  transpose_d_kernel<<<(NB * LL * NQ + T - 1) / T, T, 0, stream>>>(dbeta, dbT);

  // ---- layer 1: S2 conv -> HA
  s2_xh_kernel<<<NBATCH, T, 0, stream>>>(x, qw, dbeta, xh1);
  wfft_kernel<<<(MM * 1 * NCH + T - 1) / T, T, 0, stream>>>(k1, 1 * NCH, Wf);
  s2_z_kernel<<<(NBATCH * NCH * LL * NQ + T - 1) / T, T, 0, stream>>>(xh1, Wf, deq, zb);
  fjq_kernel<<<121 * 16, T, 0, stream>>>(zb, dbT, Fb);
  hipMemsetAsync(parts, 0, PARTS_B, stream);
  so3_dft_kernel<<<NBATCH * NCH * NB, T, 0, stream>>>(Fb, c1b, HA, parts);
  bn_finalize_kernel<<<1, 64, 0, stream>>>(parts, bn1g, bn1b, bnsc);

  // ---- layer 2: SO(3) conv HA -> HB (bn1+relu fused into dft2b load)
  dft2b_kernel<<<NBATCH * NCH * NB, T, 0, stream>>>(HA, bnsc, Xf);
  xh_kernel<<<(NBATCH * NCH * NQ + T - 1) / T, T, 0, stream>>>(Xf, qw, dbeta, xh);
  wfft_kernel<<<(MM * NCH * NCH + T - 1) / T, T, 0, stream>>>(k2, NCH * NCH, Wf);
  hk_kernel<<<NBATCH * LL * MM, 64, 0, stream>>>(xh, deq, hk2);
  z_kernel<<<MM * MM, T, 0, stream>>>(hk2, Wf, zb);
  fjq_kernel<<<121 * 16, T, 0, stream>>>(zb, dbT, Fb);
  hipMemsetAsync(parts, 0, PARTS_B, stream);
  so3_dft_kernel<<<NBATCH * NCH * NB, T, 0, stream>>>(Fb, c2b, HB, parts);
  bn_finalize_kernel<<<1, 64, 0, stream>>>(parts, bn2g, bn2b, bnsc);

  // ---- layer 3: SO(3) conv HB -> HA (bn2+relu fused into dft2b load)
  dft2b_kernel<<<NBATCH * NCH * NB, T, 0, stream>>>(HB, bnsc, Xf);
  xh_kernel<<<(NBATCH * NCH * NQ + T - 1) / T, T, 0, stream>>>(Xf, qw, dbeta, xh);
  wfft_kernel<<<(MM * NCH * NCH + T - 1) / T, T, 0, stream>>>(k3, NCH * NCH, Wf);
  hk_kernel<<<NBATCH * LL * MM, 64, 0, stream>>>(xh, deq, hk2);
  z_kernel<<<MM * MM, T, 0, stream>>>(hk2, Wf, zb);
  fjq_kernel<<<121 * 16, T, 0, stream>>>(zb, dbT, Fb);
  hipMemsetAsync(parts, 0, PARTS_B, stream);
  so3_dft_kernel<<<NBATCH * NCH * NB, T, 0, stream>>>(Fb, c3b, HA, parts);
  bn_finalize_kernel<<<1, 64, 0, stream>>>(parts, bn3g, bn3b, bnsc);

  // ---- head (bn3+relu fused into pool)
  pool_kernel<<<NBATCH * NCH, T, 0, stream>>>(HA, bnsc, pooled);
  head_kernel<<<1, T, 0, stream>>>(pooled, fc1w, fc1b, g1, bb1,
                                   fc2w, fc2b, g2, bb2, fc3w, fc3b, out);
}

// Round 8
// 902.945 us; speedup vs baseline: 3.5136x; 1.1420x over previous
//
#include <hip/hip_runtime.h>
#include <math.h>

constexpr int NB = 32;       // samples per angle
constexpr int LL = 16;       // bandwidth
constexpr int MM = 31;       // spectral orders (2*BW-1)
constexpr int MOFF = 15;
constexpr int NBATCH = 8;
constexpr int NCH = 50;
constexpr int NQ = MM * MM;          // 961
constexpr int SPAT = NB * NB * NB;   // 32768
constexpr long long HN = (long long)NBATCH * NCH * SPAT;  // 13,107,200

#define PI_D 3.14159265358979323846

__device__ inline float2 c_mk(float x, float y) { float2 r; r.x = x; r.y = y; return r; }

__device__ inline void fill_tw(float2* tw) {
  int t = threadIdx.x;
  if (t < 32) {
    double a = (double)t * (PI_D / 16.0);
    tw[t] = c_mk((float)cos(a), (float)sin(a));
  }
}

__device__ inline int bitrev5(int n) {
  return ((n & 1) << 4) | ((n & 2) << 2) | (n & 4) | ((n & 8) >> 2) | ((n & 16) >> 4);
}

__device__ inline double dpow(double x, int n) {
  double r = 1.0;
  for (int i = 0; i < n; ++i) r *= x;
  return r;
}

// ---------------- constants ----------------

__global__ void qw_kernel(float* __restrict__ qw) {
  int j = threadIdx.x;
  if (j >= NB) return;
  double beta = PI_D * (2 * j + 1) / 64.0;
  double acc = 0.0;
  for (int kk = 0; kk < LL; ++kk)
    acc += sin((double)(2 * j + 1) * (2 * kk + 1) * PI_D / 64.0) / (double)(2 * kk + 1);
  qw[j] = (float)((2.0 / 16.0) * sin(beta) * acc);
}

// out layout [j][l][mp][m]; eqmode: nj==1, beta=pi/2
__global__ void wigner_kernel(float* __restrict__ out, int nj, int eqmode) {
  __shared__ double fact[66];
  int tid = threadIdx.x;
  if (tid < 66) { double f = 1.0; for (int i = 2; i <= tid; ++i) f *= (double)i; fact[tid] = f; }
  __syncthreads();
  int total = nj * LL * NQ;
  int idx = blockIdx.x * blockDim.x + tid;
  if (idx >= total) return;
  int q = idx % NQ;
  int l = (idx / NQ) % LL;
  int j = idx / (NQ * LL);
  int mp = q / MM - MOFF;
  int m  = q % MM - MOFF;
  int amp = mp < 0 ? -mp : mp, am = m < 0 ? -m : m;
  float res = 0.f;
  if (amp <= l && am <= l) {
    double beta = eqmode ? (PI_D * 0.5) : (PI_D * (2 * j + 1) / 64.0);
    double c = cos(beta * 0.5), s = sin(beta * 0.5);
    double pref = sqrt(fact[l + mp] * fact[l - mp] * fact[l + m] * fact[l - m]);
    int k0 = max(0, m - mp), k1 = min(l + m, l - mp);
    double acc = 0.0;
    for (int k = k0; k <= k1; ++k) {
      double denom = fact[l + m - k] * fact[k] * fact[l - k - mp] * fact[k - m + mp];
      double term = dpow(c, 2 * l - 2 * k + m - mp) * dpow(s, 2 * k - m + mp) / denom;
      acc += ((mp - m + k) & 1) ? -term : term;
    }
    res = (float)(pref * acc);
  }
  out[idx] = res;
}

// dbT[j][l][n][m] = dbeta[j][l][m][n]
__global__ void transpose_d_kernel(const float* __restrict__ dbeta, float* __restrict__ dbT) {
  int idx = blockIdx.x * blockDim.x + threadIdx.x;
  if (idx >= NB * LL * NQ) return;
  int m = idx % MM;
  int n = (idx / MM) % MM;
  int jl = idx / NQ;
  dbT[idx] = dbeta[jl * NQ + m * MM + n];
}

// ---------------- layer 1 (S2 conv) ----------------

__global__ __launch_bounds__(256) void s2_xh_kernel(const float* __restrict__ x,
                                                    const float* __restrict__ qw,
                                                    const float* __restrict__ dbeta,
                                                    float2* __restrict__ xh1) {
  __shared__ float xt[NB * NB];
  __shared__ float2 Xf0[NB * MM];
  __shared__ float2 tw[32];
  fill_tw(tw);
  int tid = threadIdx.x, b = blockIdx.x;
  for (int e = tid; e < NB * NB; e += 256) xt[e] = x[b * 1024 + e];
  __syncthreads();
  for (int e = tid; e < NB * MM; e += 256) {
    int j = e / MM, mi = e % MM, m = mi - MOFF;
    float re = 0.f, im = 0.f;
    const float* row = xt + j * NB;
    for (int a = 0; a < NB; ++a) {
      float v = row[a];
      float2 t = tw[(m * a) & 31];
      re += v * t.x; im -= v * t.y;   // e^{-i m a th}
    }
    Xf0[e] = c_mk(re, im);
  }
  __syncthreads();
  for (int e = tid; e < LL * MM; e += 256) {
    int l = e / MM, mi = e % MM;
    float re = 0.f, im = 0.f;
    for (int j = 0; j < NB; ++j) {
      float w = qw[j] * dbeta[(j * LL + l) * NQ + mi * MM + MOFF];
      float2 X = Xf0[j * MM + mi];
      re += w * X.x; im += w * X.y;
    }
    xh1[(b * LL + l) * MM + mi] = c_mk(re, im);
  }
}

// Wf[ni][ic] = sum_t W[ic][t] e^{-2pi i n t/32}, ic = i*Co+o
__global__ __launch_bounds__(256) void wfft_kernel(const float* __restrict__ W, int CiCo,
                                                   float2* __restrict__ Wf) {
  __shared__ float2 tw[32];
  fill_tw(tw);
  __syncthreads();
  int idx = blockIdx.x * blockDim.x + threadIdx.x;
  if (idx >= MM * CiCo) return;
  int ni = idx / CiCo, ic = idx % CiCo;
  int n = ni - MOFF;
  float re = 0.f, im = 0.f;
  for (int t = 0; t < NB; ++t) {
    float v = W[ic * NB + t];
    float2 tt = tw[(n * t) & 31];
    re += v * tt.x; im -= v * tt.y;
  }
  Wf[idx] = c_mk(re, im);
}

// z layout: [b][o][l][ni][mi].  z = deq0[l,ni] * xh1[b,l,mi] * conj(Wf1[ni,o])
__global__ void s2_z_kernel(const float2* __restrict__ xh1, const float2* __restrict__ Wf1,
                            const float* __restrict__ deq, float2* __restrict__ z) {
  int idx = blockIdx.x * blockDim.x + threadIdx.x;
  if (idx >= NBATCH * NCH * LL * NQ) return;
  int mi = idx % MM; int t = idx / MM;
  int ni = t % MM; t /= MM;
  int l = t % LL; t /= LL;
  int o = t % NCH; int b = t / NCH;
  float d0 = deq[(l * MM + ni) * MM + MOFF];
  float2 xv = xh1[(b * LL + l) * MM + mi];
  float2 wv = Wf1[ni * NCH + o];
  float re = d0 * (xv.x * wv.x + xv.y * wv.y);
  float im = d0 * (xv.y * wv.x - xv.x * wv.y);
  z[idx] = c_mk(re, im);
}

// ---------------- SO(3) inverse transform: split into fjq + dft ----------------

// F[bo][j][q] = sum_l (2l+1) * d^l_{m,n}(beta_j) * z[bo][l][q], q = ni*31+mi.
__global__ __launch_bounds__(256) void fjq_kernel(const float2* __restrict__ z,
                                                  const float* __restrict__ dbT,
                                                  float2* __restrict__ F) {
  __shared__ float2 zs[2][LL][8];
  int qg = blockIdx.x % 121;
  int bg = blockIdx.x / 121;
  int tid = threadIdx.x;
  int j = tid >> 3, ql = tid & 7;
  int q = qg * 8 + ql;
  bool qok = q < NQ;
  int qc = qok ? q : NQ - 1;
  float w[LL];
  #pragma unroll
  for (int l = 0; l < LL; ++l)
    w[l] = (2.f * l + 1.f) * dbT[(j * LL + l) * NQ + qc];
  int bo0 = bg * 25;
  if (tid < 128) {
    int l = tid >> 3, qq = qg * 8 + (tid & 7);
    zs[0][l][tid & 7] = (qq < NQ) ? z[((long long)bo0 * LL + l) * NQ + qq] : c_mk(0.f, 0.f);
  }
  __syncthreads();
  for (int i = 0; i < 25; ++i) {
    int bo = bo0 + i;
    if (i < 24 && tid < 128) {
      int l = tid >> 3, qq = qg * 8 + (tid & 7);
      zs[(i + 1) & 1][l][tid & 7] =
          (qq < NQ) ? z[((long long)(bo + 1) * LL + l) * NQ + qq] : c_mk(0.f, 0.f);
    }
    float fr = 0.f, fi = 0.f;
    #pragma unroll
    for (int l = 0; l < LL; ++l) {
      float2 zv = zs[i & 1][l][ql];
      fr += w[l] * zv.x; fi += w[l] * zv.y;
    }
    if (qok) F[((long long)bo * NB + j) * NQ + q] = c_mk(fr, fi);
    __syncthreads();
  }
}

// One wave per block, 2 (bo,j) tiles (lanes 0-31 / 32-63). Each lane owns a
// full 32-point column/row: FFT entirely in registers (radix-2 DIF, +i sign).
// LDS (planar re/im, stride 33 -> conflict-free) only for the transpose.
// Bit-reversal folded into the reg->LDS writeback and the final store.
// bn stats wave-reduced -> one atomic pair per block (both tiles same bo).
__global__ __launch_bounds__(64) void so3_dft_kernel(const float2* __restrict__ F,
                                                     const float* __restrict__ bias,
                                                     float* __restrict__ out,
                                                     float2* __restrict__ parts) {
  __shared__ float Sre[2][32][33];
  __shared__ float Sim[2][32][33];
  __shared__ float2 tw[32];
  fill_tw(tw);
  int tid = threadIdx.x;
  int lane = tid & 31;
  int t = tid >> 5;                 // tile within block
  int idx = blockIdx.x * 2 + t;     // global tile
  int j = idx & 31;
  int bo = idx >> 5;                // same for both tiles (2 | 32)
  int o = bo % NCH;

  // zero bin-16 row and column
  Sre[t][16][lane] = 0.f; Sim[t][16][lane] = 0.f;
  Sre[t][lane][16] = 0.f; Sim[t][lane][16] = 0.f;
  __syncthreads();

  // load F row, bin-mapped: S[(ni+17)&31][(mi+17)&31]
  const float2* src = F + ((long long)bo * NB + j) * NQ;
  for (int e = lane; e < NQ; e += 32) {
    int ni = e / MM, mi = e % MM;
    float2 v = src[e];
    Sre[t][(ni + 17) & 31][(mi + 17) & 31] = v.x;
    Sim[t][(ni + 17) & 31][(mi + 17) & 31] = v.y;
  }
  __syncthreads();

  float vr[32], vi[32];

  // ---- dim0 FFT (column = lane), fully in registers
  #pragma unroll
  for (int r = 0; r < 32; ++r) { vr[r] = Sre[t][r][lane]; vi[r] = Sim[t][r][lane]; }
  #pragma unroll
  for (int st = 0; st < 5; ++st) {
    const int half = 16 >> st, tmul = 1 << st;
    #pragma unroll
    for (int p = 0; p < 16; ++p) {
      const int j2 = p & (half - 1);
      const int i0 = ((p >> (4 - st)) << (5 - st)) + j2;
      const int i1 = i0 + half;
      float2 tt = tw[(j2 * tmul) & 31];
      float ur = vr[i0], ui = vi[i0], wr = vr[i1], wi = vi[i1];
      float dr = ur - wr, di = ui - wi;
      vr[i0] = ur + wr; vi[i0] = ui + wi;
      vr[i1] = dr * tt.x - di * tt.y;
      vi[i1] = dr * tt.y + di * tt.x;
    }
  }
  // write back un-bit-reversed: X[k] lives at v[bitrev5(k)]
  #pragma unroll
  for (int k = 0; k < 32; ++k) {
    Sre[t][k][lane] = vr[bitrev5(k)];
    Sim[t][k][lane] = vi[bitrev5(k)];
  }
  __syncthreads();

  // ---- dim1 FFT (row = lane = g), in registers
  #pragma unroll
  for (int m = 0; m < 32; ++m) { vr[m] = Sre[t][lane][m]; vi[m] = Sim[t][lane][m]; }
  #pragma unroll
  for (int st = 0; st < 5; ++st) {
    const int half = 16 >> st, tmul = 1 << st;
    #pragma unroll
    for (int p = 0; p < 16; ++p) {
      const int j2 = p & (half - 1);
      const int i0 = ((p >> (4 - st)) << (5 - st)) + j2;
      const int i1 = i0 + half;
      float2 tt = tw[(j2 * tmul) & 31];
      float ur = vr[i0], ui = vi[i0], wr = vr[i1], wi = vi[i1];
      float dr = ur - wr, di = ui - wi;
      vr[i0] = ur + wr; vi[i0] = ui + wi;
      vr[i1] = dr * tt.x - di * tt.y;
      vi[i1] = dr * tt.y + di * tt.x;
    }
  }

  // ---- store out[a,g] = Re X[a] + bias (g = lane), fused bn stats
  float bval = bias[o];
  long long obase = (long long)bo * SPAT + (long long)j * 1024 + lane;
  float s1 = 0.f, s2 = 0.f;
  #pragma unroll
  for (int a = 0; a < 32; ++a) {
    float val = vr[bitrev5(a)] + bval;
    out[obase + a * 32] = val;
    s1 += val; s2 += val * val;
  }
  #pragma unroll
  for (int off = 32; off > 0; off >>= 1) {
    s1 += __shfl_down(s1, off);
    s2 += __shfl_down(s2, off);
  }
  if (tid == 0) {
    atomicAdd(&parts[bo].x, s1);
    atomicAdd(&parts[bo].y, s2);
  }
}

// ---------------- batchnorm ----------------

__global__ void bn_finalize_kernel(const float2* __restrict__ partials,
                                   const float* __restrict__ g, const float* __restrict__ bb,
                                   float2* __restrict__ sc) {
  int o = threadIdx.x;
  if (o >= NCH) return;
  float s = 0.f, ss = 0.f;
  for (int b = 0; b < NBATCH; ++b) { float2 p = partials[b * NCH + o]; s += p.x; ss += p.y; }
  float inv = 1.f / (float)(NBATCH * SPAT);
  float mu = s * inv;
  float var = ss * inv - mu * mu;
  float scale = g[o] * rsqrtf(var + 1e-5f);
  sc[o] = c_mk(scale, bb[o] - mu * scale);
}

// ---------------- SO(3) conv ----------------

// 2D DFT of a real 32x32 tile -> 31x31 signed-order spectrum.
// Fused bn+relu applied on load (sc indexed by channel).
__global__ __launch_bounds__(256) void dft2b_kernel(const float* __restrict__ h,
                                                    const float2* __restrict__ sc,
                                                    float2* __restrict__ Xf) {
  __shared__ float xt[32 * 33];   // padded stride kills bank conflict
  __shared__ float2 P[32 * 16];   // [a][n], n = 0..15
  __shared__ float2 Xs[NQ];
  __shared__ float2 tw[32];
  fill_tw(tw);
  int tid = threadIdx.x;
  long long blk = blockIdx.x;
  int c = (int)((blk >> 5) % NCH);
  float2 s = sc[c];
  const float* src = h + blk * 1024;
  for (int e = tid; e < 1024; e += 256) {
    float v = src[e];
    xt[(e >> 5) * 33 + (e & 31)] = fmaxf(v * s.x + s.y, 0.f);
  }
  __syncthreads();
  // P[a,n] = sum_g x[a,g] e^{-i n g th}
  for (int e = tid; e < 512; e += 256) {
    int a = e >> 4, n = e & 15;
    float re = 0.f, im = 0.f;
    const float* row = xt + a * 33;
    #pragma unroll
    for (int g = 0; g < 32; ++g) {
      float v = row[g];
      float2 t = tw[(n * g) & 31];
      re += v * t.x; im -= v * t.y;
    }
    P[a * 16 + n] = c_mk(re, im);
  }
  __syncthreads();
  // X[m,n] = sum_a P[a,n] e^{-i m a th}; m=+mh and m=-mh together.
  {
    int e = tid;
    if (e < 256) {
      int mh = e >> 4, n = e & 15;
      float sxx = 0.f, sxy = 0.f, syx = 0.f, syy = 0.f;
      #pragma unroll
      for (int a = 0; a < 32; ++a) {
        float2 p = P[a * 16 + n];
        float2 t = tw[(mh * a) & 31];
        sxx += p.x * t.x; sxy += p.x * t.y;
        syx += p.y * t.x; syy += p.y * t.y;
      }
      float2 Xp = c_mk(sxx + syy, syx - sxy);   // X[+mh, n]
      float2 Xm = c_mk(sxx - syy, syx + sxy);   // X[-mh, n]
      Xs[(mh + MOFF) * MM + (n + MOFF)] = Xp;
      Xs[(MOFF - mh) * MM + (n + MOFF)] = Xm;
      Xs[(MOFF - mh) * MM + (MOFF - n)] = c_mk(Xp.x, -Xp.y);
      Xs[(mh + MOFF) * MM + (MOFF - n)] = c_mk(Xm.x, -Xm.y);
    }
  }
  __syncthreads();
  float2* dst = Xf + blk * NQ;
  for (int e = tid; e < NQ; e += 256) dst[e] = Xs[e];
}

// xh[bc,l,q] = sum_j qw[j]*dbeta[j,l,q]*Xf[bc,j,q]   (q = mi*MM+ni)
__global__ void xh_kernel(const float2* __restrict__ Xf, const float* __restrict__ qw,
                          const float* __restrict__ dbeta, float2* __restrict__ xh) {
  int idx = blockIdx.x * blockDim.x + threadIdx.x;
  if (idx >= NBATCH * NCH * NQ) return;
  int q = idx % NQ;
  int bc = idx / NQ;
  float2 acc[LL];
  #pragma unroll
  for (int l = 0; l < LL; ++l) acc[l] = c_mk(0.f, 0.f);
  for (int j = 0; j < NB; ++j) {
    float2 xv = Xf[((long long)bc * NB + j) * NQ + q];
    float qj = qw[j];
    const float* dbase = dbeta + (long long)(j * LL) * NQ + q;
    #pragma unroll
    for (int l = 0; l < LL; ++l) {
      float w = qj * dbase[l * NQ];
      acc[l].x += w * xv.x;
      acc[l].y += w * xv.y;
    }
  }
  #pragma unroll
  for (int l = 0; l < LL; ++l) xh[((long long)bc * LL + l) * NQ + q] = acc[l];
}

// hk2[r][ni][ich] = sum_k xh[(b*NCH+ich),l,mi,k] * deq[l,ni,k], r=(b*LL+l)*MM+mi.
__global__ __launch_bounds__(64) void hk_kernel(const float2* __restrict__ xh,
                                                const float* __restrict__ deq,
                                                float2* __restrict__ hk2) {
  int r = blockIdx.x;                 // 0..3967
  int mi = r % MM;
  int bl = r / MM;                    // b*LL + l
  int l = bl % LL;
  int b = bl / LL;
  int ich = threadIdx.x;
  if (ich >= NCH) return;
  float2 row[MM];
  const float2* src = xh + ((long long)(b * NCH + ich) * LL + l) * NQ + mi * MM;
  #pragma unroll
  for (int k = 0; k < MM; ++k) row[k] = src[k];
  const float* dl = deq + l * NQ;
  long long obase = (long long)r * MM * NCH + ich;
  for (int ni = 0; ni < MM; ++ni) {
    const float* dr = dl + ni * MM;
    float re = 0.f, im = 0.f;
    #pragma unroll
    for (int k = 0; k < MM; ++k) {
      float d = dr[k];
      re += d * row[k].x;
      im += d * row[k].y;
    }
    hk2[obase + (long long)ni * NCH] = c_mk(re, im);
  }
}

// z[b][o][l][ni][mi] = sum_i hk2[(r*31+ni)*50+i] * conj(Wf[ni,i,o]), r=(b,l,mi)
// Wf[ni] slice (50x50 float2 = 20 KB) staged in LDS; inner-loop w reads are
// wave-uniform broadcasts. hk2 float4 loads are the only VMEM in the loop.
__global__ __launch_bounds__(256) void z_kernel(const float2* __restrict__ hk2,
                                                const float2* __restrict__ Wf,
                                                float2* __restrict__ z) {
  __shared__ float2 ws[NCH * NCH];   // 20 KB
  int ni = blockIdx.x / MM;          // 0..30
  int rowtile = blockIdx.x % MM;     // 0..30
  int tid = threadIdx.x;
  {
    const float4* s4 = reinterpret_cast<const float4*>(Wf + ni * (NCH * NCH));
    float4* d4 = reinterpret_cast<float4*>(ws);
    for (int e = tid; e < NCH * NCH / 2; e += 256) d4[e] = s4[e];
  }
  __syncthreads();
  int r = rowtile * 128 + (tid & 127);   // 0..3967 = (b,l,mi)
  int o0 = (tid >> 7) * 25;
  int b = r / (LL * MM);
  int rem = r % (LL * MM);
  int l = rem / MM;
  int mi = rem % MM;

  const float4* h4 = reinterpret_cast<const float4*>(hk2 + ((long long)r * MM + ni) * NCH);

  float2 acc[25];
  #pragma unroll
  for (int u = 0; u < 25; ++u) acc[u] = c_mk(0.f, 0.f);

  for (int ih = 0; ih < 25; ++ih) {     // 2 channels per iteration
    float4 hv = h4[ih];
    const float2* w0 = ws + (2 * ih) * NCH + o0;
    #pragma unroll
    for (int u = 0; u < 25; ++u) {
      float2 w = w0[u];
      acc[u].x += hv.x * w.x + hv.y * w.y;
      acc[u].y += hv.y * w.x - hv.x * w.y;
    }
    const float2* w1 = w0 + NCH;
    #pragma unroll
    for (int u = 0; u < 25; ++u) {
      float2 w = w1[u];
      acc[u].x += hv.z * w.x + hv.w * w.y;
      acc[u].y += hv.w * w.x - hv.z * w.y;
    }
  }

  long long zb = (((long long)(b * NCH + o0) * LL + l) * NQ) + ni * MM + mi;
  #pragma unroll
  for (int u = 0; u < 25; ++u)
    z[zb + (long long)u * LL * NQ] = acc[u];
}

// ---------------- head ----------------

// pool with fused bn+relu (layer-3 scale/shift applied per element)
__global__ void pool_kernel(const float* __restrict__ h, const float2* __restrict__ sc,
                            float* __restrict__ pooled) {
  __shared__ float sm[256];
  int tid = threadIdx.x;
  int o = blockIdx.x % NCH;
  float2 s = sc[o];
  const float* base = h + (long long)blockIdx.x * SPAT;
  float best = -1e30f;
  for (int e = tid; e < 1024; e += 256) {
    float acc = 0.f;
    for (int g = 0; g < NB; ++g) {
      float v = base[e * NB + g];
      acc += fmaxf(v * s.x + s.y, 0.f);
    }
    best = fmaxf(best, acc * (1.f / 32.f));
  }
  sm[tid] = best;
  __syncthreads();
  for (int st = 128; st > 0; st >>= 1) {
    if (tid < st) sm[tid] = fmaxf(sm[tid], sm[tid + st]);
    __syncthreads();
  }
  if (tid == 0) pooled[blockIdx.x] = sm[0];
}

__global__ __launch_bounds__(256) void head_kernel(const float* __restrict__ pooled,
    const float* __restrict__ fc1w, const float* __restrict__ fc1b,
    const float* __restrict__ g1, const float* __restrict__ b1,
    const float* __restrict__ fc2w, const float* __restrict__ fc2b,
    const float* __restrict__ g2, const float* __restrict__ b2,
    const float* __restrict__ fc3w, const float* __restrict__ fc3b,
    float* __restrict__ out) {
  __shared__ float pin[NBATCH * NCH];
  __shared__ float A[NBATCH * 256];
  __shared__ float Bm[NBATCH * 128];
  __shared__ float Cm[NBATCH * 40];
  int tid = threadIdx.x;
  for (int e = tid; e < NBATCH * NCH; e += 256) pin[e] = pooled[e];
  __syncthreads();
  {
    float v[NBATCH];
    #pragma unroll
    for (int b = 0; b < NBATCH; ++b) {
      float acc = fc1b[tid];
      for (int c = 0; c < NCH; ++c) acc += pin[b * NCH + c] * fc1w[tid * NCH + c];
      v[b] = acc;
    }
    float s = 0.f, ss = 0.f;
    #pragma unroll
    for (int b = 0; b < NBATCH; ++b) { s += v[b]; ss += v[b] * v[b]; }
    float mu = s * 0.125f, var = ss * 0.125f - mu * mu;
    float sc = g1[tid] * rsqrtf(var + 1e-5f), sh = b1[tid] - mu * sc;
    #pragma unroll
    for (int b = 0; b < NBATCH; ++b) A[b * 256 + tid] = fmaxf(v[b] * sc + sh, 0.f);
  }
  __syncthreads();
  if (tid < 128) {
    float v[NBATCH];
    #pragma unroll
    for (int b = 0; b < NBATCH; ++b) {
      float acc = fc2b[tid];
      for (int c = 0; c < 256; ++c) acc += A[b * 256 + c] * fc2w[tid * 256 + c];
      v[b] = acc;
    }
    float s = 0.f, ss = 0.f;
    #pragma unroll
    for (int b = 0; b < NBATCH; ++b) { s += v[b]; ss += v[b] * v[b]; }
    float mu = s * 0.125f, var = ss * 0.125f - mu * mu;
    float sc = g2[tid] * rsqrtf(var + 1e-5f), sh = b2[tid] - mu * sc;
    #pragma unroll
    for (int b = 0; b < NBATCH; ++b) Bm[b * 128 + tid] = fmaxf(v[b] * sc + sh, 0.f);
  }
  __syncthreads();
  if (tid < 40) {
    #pragma unroll
    for (int b = 0; b < NBATCH; ++b) {
      float acc = fc3b[tid];
      for (int c = 0; c < 128; ++c) acc += Bm[b * 128 + c] * fc3w[tid * 128 + c];
      Cm[b * 40 + tid] = acc;
    }
  }
  __syncthreads();
  if (tid < NBATCH) {
    int b = tid;
    float mx = -1e30f;
    for (int f = 0; f < 40; ++f) mx = fmaxf(mx, Cm[b * 40 + f]);
    float se = 0.f;
    for (int f = 0; f < 40; ++f) se += expf(Cm[b * 40 + f] - mx);
    float lse = mx + logf(se);
    for (int f = 0; f < 40; ++f) out[b * 40 + f] = Cm[b * 40 + f] - lse;
  }
}

// ---------------- host ----------------

extern "C" void kernel_launch(void* const* d_in, const int* in_sizes, int n_in,
                              void* d_out, int out_size, void* d_ws, size_t ws_size,
                              hipStream_t stream) {
  (void)in_sizes; (void)n_in; (void)out_size;
  const float* x    = (const float*)d_in[0];
  const float* k1   = (const float*)d_in[1];
  const float* c1b  = (const float*)d_in[2];
  const float* bn1g = (const float*)d_in[3];
  const float* bn1b = (const float*)d_in[4];
  const float* k2   = (const float*)d_in[5];
  const float* c2b  = (const float*)d_in[6];
  const float* bn2g = (const float*)d_in[7];
  const float* bn2b = (const float*)d_in[8];
  const float* k3   = (const float*)d_in[9];
  const float* c3b  = (const float*)d_in[10];
  const float* bn3g = (const float*)d_in[11];
  const float* bn3b = (const float*)d_in[12];
  const float* fc1w = (const float*)d_in[13];
  const float* fc1b = (const float*)d_in[14];
  const float* g1   = (const float*)d_in[15];
  const float* bb1  = (const float*)d_in[16];
  const float* fc2w = (const float*)d_in[17];
  const float* fc2b = (const float*)d_in[18];
  const float* g2   = (const float*)d_in[19];
  const float* bb2  = (const float*)d_in[20];
  const float* fc3w = (const float*)d_in[21];
  const float* fc3b = (const float*)d_in[22];
  float* out = (float*)d_out;

  char* ws = (char*)d_ws;
  size_t off = 0;
  auto alloc = [&](size_t n) -> char* {
    char* p = ws + off;
    off += (n + 255) & ~(size_t)255;
    return p;
  };

  float*  dbeta  = (float*)alloc(sizeof(float) * NB * LL * NQ);      // 1.97 MB
  float*  dbT    = (float*)alloc(sizeof(float) * NB * LL * NQ);      // 1.97 MB
  float*  deq    = (float*)alloc(sizeof(float) * LL * NQ);
  float*  qw     = (float*)alloc(sizeof(float) * NB);
  float2* xh1    = (float2*)alloc(sizeof(float2) * NBATCH * LL * MM);
  float2* Wf     = (float2*)alloc(sizeof(float2) * MM * NCH * NCH);  // 620 KB
  float2* parts  = (float2*)alloc(sizeof(float2) * NBATCH * NCH);
  float2* bnsc   = (float2*)alloc(sizeof(float2) * 64);
  float*  pooled = (float*)alloc(sizeof(float) * NBATCH * NCH);
  float*  HA     = (float*)alloc(sizeof(float) * (size_t)HN);        // 52.4 MB
  float*  HB     = (float*)alloc(sizeof(float) * (size_t)HN);        // 52.4 MB
  size_t XFB = (size_t)NBATCH * NCH * NB * NQ * sizeof(float2);      // 98.4 MB
  size_t XHB = (size_t)NBATCH * NCH * LL * NQ * sizeof(float2);      // 49.2 MB
  char* AR = alloc(XFB + XHB);                                       // 147.6 MB arena
  float2* Xf  = (float2*)AR;           // live: dft2 -> xh
  float2* xh  = (float2*)(AR + XFB);   // live: xh -> hk
  float2* hk2 = (float2*)AR;           // live: hk -> z    (reuses dead Xf)
  float2* zb  = (float2*)(AR + XFB);   // live: z -> fjq   (reuses dead xh; also z1)
  float2* Fb  = (float2*)AR;           // live: fjq -> dft (reuses dead hk2/Xf; 98.4 MB exact)

  if (ws_size < off) return;  // insufficient scratch: leave d_out zeroed

  const int T = 256;
  const size_t PARTS_B = sizeof(float2) * NBATCH * NCH;
  // constants
  qw_kernel<<<1, 32, 0, stream>>>(qw);
  wigner_kernel<<<(NB * LL * NQ + T - 1) / T, T, 0, stream>>>(dbeta, NB, 0);
  wigner_kernel<<<(LL * NQ + T - 1) / T, T, 0, stream>>>(deq, 1, 1);
  transpose_d_kernel<<<(NB * LL * NQ + T - 1) / T, T, 0, stream>>>(dbeta, dbT);

  // ---- layer 1: S2 conv -> HA
  s2_xh_kernel<<<NBATCH, T, 0, stream>>>(x, qw, dbeta, xh1);
  wfft_kernel<<<(MM * 1 * NCH + T - 1) / T, T, 0, stream>>>(k1, 1 * NCH, Wf);
  s2_z_kernel<<<(NBATCH * NCH * LL * NQ + T - 1) / T, T, 0, stream>>>(xh1, Wf, deq, zb);
  fjq_kernel<<<121 * 16, T, 0, stream>>>(zb, dbT, Fb);
  hipMemsetAsync(parts, 0, PARTS_B, stream);
  so3_dft_kernel<<<NBATCH * NCH * NB / 2, 64, 0, stream>>>(Fb, c1b, HA, parts);
  bn_finalize_kernel<<<1, 64, 0, stream>>>(parts, bn1g, bn1b, bnsc);

  // ---- layer 2: SO(3) conv HA -> HB (bn1+relu fused into dft2b load)
  dft2b_kernel<<<NBATCH * NCH * NB, T, 0, stream>>>(HA, bnsc, Xf);
  xh_kernel<<<(NBATCH * NCH * NQ + T - 1) / T, T, 0, stream>>>(Xf, qw, dbeta, xh);
  wfft_kernel<<<(MM * NCH * NCH + T - 1) / T, T, 0, stream>>>(k2, NCH * NCH, Wf);
  hk_kernel<<<NBATCH * LL * MM, 64, 0, stream>>>(xh, deq, hk2);
  z_kernel<<<MM * MM, T, 0, stream>>>(hk2, Wf, zb);
  fjq_kernel<<<121 * 16, T, 0, stream>>>(zb, dbT, Fb);
  hipMemsetAsync(parts, 0, PARTS_B, stream);
  so3_dft_kernel<<<NBATCH * NCH * NB / 2, 64, 0, stream>>>(Fb, c2b, HB, parts);
  bn_finalize_kernel<<<1, 64, 0, stream>>>(parts, bn2g, bn2b, bnsc);

  // ---- layer 3: SO(3) conv HB -> HA (bn2+relu fused into dft2b load)
  dft2b_kernel<<<NBATCH * NCH * NB, T, 0, stream>>>(HB, bnsc, Xf);
  xh_kernel<<<(NBATCH * NCH * NQ + T - 1) / T, T, 0, stream>>>(Xf, qw, dbeta, xh);
  wfft_kernel<<<(MM * NCH * NCH + T - 1) / T, T, 0, stream>>>(k3, NCH * NCH, Wf);
  hk_kernel<<<NBATCH * LL * MM, 64, 0, stream>>>(xh, deq, hk2);
  z_kernel<<<MM * MM, T, 0, stream>>>(hk2, Wf, zb);
  fjq_kernel<<<121 * 16, T, 0, stream>>>(zb, dbT, Fb);
  hipMemsetAsync(parts, 0, PARTS_B, stream);
  so3_dft_kernel<<<NBATCH * NCH * NB / 2, 64, 0, stream>>>(Fb, c3b, HA, parts);
  bn_finalize_kernel<<<1, 64, 0, stream>>>(parts, bn3g, bn3b, bnsc);

  // ---- head (bn3+relu fused into pool)
  pool_kernel<<<NBATCH * NCH, T, 0, stream>>>(HA, bnsc, pooled);
  head_kernel<<<1, T, 0, stream>>>(pooled, fc1w, fc1b, g1, bb1,
                                   fc2w, fc2b, g2, bb2, fc3w, fc3b, out);
}

// Round 9
// 799.230 us; speedup vs baseline: 3.9695x; 1.1298x over previous
//
#include <hip/hip_runtime.h>
#include <math.h>

constexpr int NB = 32;       // samples per angle
constexpr int LL = 16;       // bandwidth
constexpr int MM = 31;       // spectral orders (2*BW-1)
constexpr int MOFF = 15;
constexpr int NBATCH = 8;
constexpr int NCH = 50;
constexpr int NQ = MM * MM;          // 961
constexpr int SPAT = NB * NB * NB;   // 32768
constexpr long long HN = (long long)NBATCH * NCH * SPAT;  // 13,107,200

#define PI_D 3.14159265358979323846

__device__ inline float2 c_mk(float x, float y) { float2 r; r.x = x; r.y = y; return r; }

__device__ inline void fill_tw(float2* tw) {
  int t = threadIdx.x;
  if (t < 32) {
    double a = (double)t * (PI_D / 16.0);
    tw[t] = c_mk((float)cos(a), (float)sin(a));
  }
}

__device__ inline int bitrev5(int n) {
  return ((n & 1) << 4) | ((n & 2) << 2) | (n & 4) | ((n & 8) >> 2) | ((n & 16) >> 4);
}

__device__ inline double dpow(double x, int n) {
  double r = 1.0;
  for (int i = 0; i < n; ++i) r *= x;
  return r;
}

// ---------------- constants ----------------

__global__ void qw_kernel(float* __restrict__ qw) {
  int j = threadIdx.x;
  if (j >= NB) return;
  double beta = PI_D * (2 * j + 1) / 64.0;
  double acc = 0.0;
  for (int kk = 0; kk < LL; ++kk)
    acc += sin((double)(2 * j + 1) * (2 * kk + 1) * PI_D / 64.0) / (double)(2 * kk + 1);
  qw[j] = (float)((2.0 / 16.0) * sin(beta) * acc);
}

// out layout [j][l][mp][m]; eqmode: nj==1, beta=pi/2
__global__ void wigner_kernel(float* __restrict__ out, int nj, int eqmode) {
  __shared__ double fact[66];
  int tid = threadIdx.x;
  if (tid < 66) { double f = 1.0; for (int i = 2; i <= tid; ++i) f *= (double)i; fact[tid] = f; }
  __syncthreads();
  int total = nj * LL * NQ;
  int idx = blockIdx.x * blockDim.x + tid;
  if (idx >= total) return;
  int q = idx % NQ;
  int l = (idx / NQ) % LL;
  int j = idx / (NQ * LL);
  int mp = q / MM - MOFF;
  int m  = q % MM - MOFF;
  int amp = mp < 0 ? -mp : mp, am = m < 0 ? -m : m;
  float res = 0.f;
  if (amp <= l && am <= l) {
    double beta = eqmode ? (PI_D * 0.5) : (PI_D * (2 * j + 1) / 64.0);
    double c = cos(beta * 0.5), s = sin(beta * 0.5);
    double pref = sqrt(fact[l + mp] * fact[l - mp] * fact[l + m] * fact[l - m]);
    int k0 = max(0, m - mp), k1 = min(l + m, l - mp);
    double acc = 0.0;
    for (int k = k0; k <= k1; ++k) {
      double denom = fact[l + m - k] * fact[k] * fact[l - k - mp] * fact[k - m + mp];
      double term = dpow(c, 2 * l - 2 * k + m - mp) * dpow(s, 2 * k - m + mp) / denom;
      acc += ((mp - m + k) & 1) ? -term : term;
    }
    res = (float)(pref * acc);
  }
  out[idx] = res;
}

// dbT[j][l][n][m] = dbeta[j][l][m][n]
__global__ void transpose_d_kernel(const float* __restrict__ dbeta, float* __restrict__ dbT) {
  int idx = blockIdx.x * blockDim.x + threadIdx.x;
  if (idx >= NB * LL * NQ) return;
  int m = idx % MM;
  int n = (idx / MM) % MM;
  int jl = idx / NQ;
  dbT[idx] = dbeta[jl * NQ + m * MM + n];
}

// ---------------- layer 1 (S2 conv) ----------------

__global__ __launch_bounds__(256) void s2_xh_kernel(const float* __restrict__ x,
                                                    const float* __restrict__ qw,
                                                    const float* __restrict__ dbeta,
                                                    float2* __restrict__ xh1) {
  __shared__ float xt[NB * NB];
  __shared__ float2 Xf0[NB * MM];
  __shared__ float2 tw[32];
  fill_tw(tw);
  int tid = threadIdx.x, b = blockIdx.x;
  for (int e = tid; e < NB * NB; e += 256) xt[e] = x[b * 1024 + e];
  __syncthreads();
  for (int e = tid; e < NB * MM; e += 256) {
    int j = e / MM, mi = e % MM, m = mi - MOFF;
    float re = 0.f, im = 0.f;
    const float* row = xt + j * NB;
    for (int a = 0; a < NB; ++a) {
      float v = row[a];
      float2 t = tw[(m * a) & 31];
      re += v * t.x; im -= v * t.y;   // e^{-i m a th}
    }
    Xf0[e] = c_mk(re, im);
  }
  __syncthreads();
  for (int e = tid; e < LL * MM; e += 256) {
    int l = e / MM, mi = e % MM;
    float re = 0.f, im = 0.f;
    for (int j = 0; j < NB; ++j) {
      float w = qw[j] * dbeta[(j * LL + l) * NQ + mi * MM + MOFF];
      float2 X = Xf0[j * MM + mi];
      re += w * X.x; im += w * X.y;
    }
    xh1[(b * LL + l) * MM + mi] = c_mk(re, im);
  }
}

// Wf[ni][ic] = sum_t W[ic][t] e^{-2pi i n t/32}, ic = i*Co+o
__global__ __launch_bounds__(256) void wfft_kernel(const float* __restrict__ W, int CiCo,
                                                   float2* __restrict__ Wf) {
  __shared__ float2 tw[32];
  fill_tw(tw);
  __syncthreads();
  int idx = blockIdx.x * blockDim.x + threadIdx.x;
  if (idx >= MM * CiCo) return;
  int ni = idx / CiCo, ic = idx % CiCo;
  int n = ni - MOFF;
  float re = 0.f, im = 0.f;
  for (int t = 0; t < NB; ++t) {
    float v = W[ic * NB + t];
    float2 tt = tw[(n * t) & 31];
    re += v * tt.x; im -= v * tt.y;
  }
  Wf[idx] = c_mk(re, im);
}

// z layout: [b][o][l][ni][mi].  z = deq0[l,ni] * xh1[b,l,mi] * conj(Wf1[ni,o])
__global__ void s2_z_kernel(const float2* __restrict__ xh1, const float2* __restrict__ Wf1,
                            const float* __restrict__ deq, float2* __restrict__ z) {
  int idx = blockIdx.x * blockDim.x + threadIdx.x;
  if (idx >= NBATCH * NCH * LL * NQ) return;
  int mi = idx % MM; int t = idx / MM;
  int ni = t % MM; t /= MM;
  int l = t % LL; t /= LL;
  int o = t % NCH; int b = t / NCH;
  float d0 = deq[(l * MM + ni) * MM + MOFF];
  float2 xv = xh1[(b * LL + l) * MM + mi];
  float2 wv = Wf1[ni * NCH + o];
  float re = d0 * (xv.x * wv.x + xv.y * wv.y);
  float im = d0 * (xv.y * wv.x - xv.x * wv.y);
  z[idx] = c_mk(re, im);
}

// ---------------- SO(3) inverse transform: split into fjq + dft ----------------

// F[bo][j][q] = sum_l (2l+1) * d^l_{m,n}(beta_j) * z[bo][l][q], q = ni*31+mi.
// Staging skips z entries with l < |ni-15| (dbT is exactly 0 there).
__global__ __launch_bounds__(256) void fjq_kernel(const float2* __restrict__ z,
                                                  const float* __restrict__ dbT,
                                                  float2* __restrict__ F) {
  __shared__ float2 zs[2][LL][8];
  int qg = blockIdx.x % 121;
  int bg = blockIdx.x / 121;
  int tid = threadIdx.x;
  int j = tid >> 3, ql = tid & 7;
  int q = qg * 8 + ql;
  bool qok = q < NQ;
  int qc = qok ? q : NQ - 1;
  float w[LL];
  #pragma unroll
  for (int l = 0; l < LL; ++l)
    w[l] = (2.f * l + 1.f) * dbT[(j * LL + l) * NQ + qc];
  int bo0 = bg * 25;
  if (tid < 128) {
    int l = tid >> 3, qq = qg * 8 + (tid & 7);
    int dd = (qq < NQ) ? (qq / MM - MOFF) : 99; if (dd < 0) dd = -dd;
    zs[0][l][tid & 7] = (l >= dd) ? z[((long long)bo0 * LL + l) * NQ + qq] : c_mk(0.f, 0.f);
  }
  __syncthreads();
  for (int i = 0; i < 25; ++i) {
    int bo = bo0 + i;
    if (i < 24 && tid < 128) {
      int l = tid >> 3, qq = qg * 8 + (tid & 7);
      int dd = (qq < NQ) ? (qq / MM - MOFF) : 99; if (dd < 0) dd = -dd;
      zs[(i + 1) & 1][l][tid & 7] =
          (l >= dd) ? z[((long long)(bo + 1) * LL + l) * NQ + qq] : c_mk(0.f, 0.f);
    }
    float fr = 0.f, fi = 0.f;
    #pragma unroll
    for (int l = 0; l < LL; ++l) {
      float2 zv = zs[i & 1][l][ql];
      fr += w[l] * zv.x; fi += w[l] * zv.y;
    }
    if (qok) F[((long long)bo * NB + j) * NQ + q] = c_mk(fr, fi);
    __syncthreads();
  }
}

// One wave per block, 2 (bo,j) tiles (lanes 0-31 / 32-63). Register radix-2 FFT.
__global__ __launch_bounds__(64) void so3_dft_kernel(const float2* __restrict__ F,
                                                     const float* __restrict__ bias,
                                                     float* __restrict__ out,
                                                     float2* __restrict__ parts) {
  __shared__ float Sre[2][32][33];
  __shared__ float Sim[2][32][33];
  __shared__ float2 tw[32];
  fill_tw(tw);
  int tid = threadIdx.x;
  int lane = tid & 31;
  int t = tid >> 5;                 // tile within block
  int idx = blockIdx.x * 2 + t;     // global tile
  int j = idx & 31;
  int bo = idx >> 5;                // same for both tiles (2 | 32)
  int o = bo % NCH;

  // zero bin-16 row and column
  Sre[t][16][lane] = 0.f; Sim[t][16][lane] = 0.f;
  Sre[t][lane][16] = 0.f; Sim[t][lane][16] = 0.f;
  __syncthreads();

  // load F row, bin-mapped: S[(ni+17)&31][(mi+17)&31]
  const float2* src = F + ((long long)bo * NB + j) * NQ;
  for (int e = lane; e < NQ; e += 32) {
    int ni = e / MM, mi = e % MM;
    float2 v = src[e];
    Sre[t][(ni + 17) & 31][(mi + 17) & 31] = v.x;
    Sim[t][(ni + 17) & 31][(mi + 17) & 31] = v.y;
  }
  __syncthreads();

  float vr[32], vi[32];

  // ---- dim0 FFT (column = lane), fully in registers
  #pragma unroll
  for (int r = 0; r < 32; ++r) { vr[r] = Sre[t][r][lane]; vi[r] = Sim[t][r][lane]; }
  #pragma unroll
  for (int st = 0; st < 5; ++st) {
    const int half = 16 >> st, tmul = 1 << st;
    #pragma unroll
    for (int p = 0; p < 16; ++p) {
      const int j2 = p & (half - 1);
      const int i0 = ((p >> (4 - st)) << (5 - st)) + j2;
      const int i1 = i0 + half;
      float2 tt = tw[(j2 * tmul) & 31];
      float ur = vr[i0], ui = vi[i0], wr = vr[i1], wi = vi[i1];
      float dr = ur - wr, di = ui - wi;
      vr[i0] = ur + wr; vi[i0] = ui + wi;
      vr[i1] = dr * tt.x - di * tt.y;
      vi[i1] = dr * tt.y + di * tt.x;
    }
  }
  // write back un-bit-reversed: X[k] lives at v[bitrev5(k)]
  #pragma unroll
  for (int k = 0; k < 32; ++k) {
    Sre[t][k][lane] = vr[bitrev5(k)];
    Sim[t][k][lane] = vi[bitrev5(k)];
  }
  __syncthreads();

  // ---- dim1 FFT (row = lane = g), in registers
  #pragma unroll
  for (int m = 0; m < 32; ++m) { vr[m] = Sre[t][lane][m]; vi[m] = Sim[t][lane][m]; }
  #pragma unroll
  for (int st = 0; st < 5; ++st) {
    const int half = 16 >> st, tmul = 1 << st;
    #pragma unroll
    for (int p = 0; p < 16; ++p) {
      const int j2 = p & (half - 1);
      const int i0 = ((p >> (4 - st)) << (5 - st)) + j2;
      const int i1 = i0 + half;
      float2 tt = tw[(j2 * tmul) & 31];
      float ur = vr[i0], ui = vi[i0], wr = vr[i1], wi = vi[i1];
      float dr = ur - wr, di = ui - wi;
      vr[i0] = ur + wr; vi[i0] = ui + wi;
      vr[i1] = dr * tt.x - di * tt.y;
      vi[i1] = dr * tt.y + di * tt.x;
    }
  }

  // ---- store out[a,g] = Re X[a] + bias (g = lane), fused bn stats
  float bval = bias[o];
  long long obase = (long long)bo * SPAT + (long long)j * 1024 + lane;
  float s1 = 0.f, s2 = 0.f;
  #pragma unroll
  for (int a = 0; a < 32; ++a) {
    float val = vr[bitrev5(a)] + bval;
    out[obase + a * 32] = val;
    s1 += val; s2 += val * val;
  }
  #pragma unroll
  for (int off = 32; off > 0; off >>= 1) {
    s1 += __shfl_down(s1, off);
    s2 += __shfl_down(s2, off);
  }
  if (tid == 0) {
    atomicAdd(&parts[bo].x, s1);
    atomicAdd(&parts[bo].y, s2);
  }
}

// ---------------- batchnorm ----------------

__global__ void bn_finalize_kernel(const float2* __restrict__ partials,
                                   const float* __restrict__ g, const float* __restrict__ bb,
                                   float2* __restrict__ sc) {
  int o = threadIdx.x;
  if (o >= NCH) return;
  float s = 0.f, ss = 0.f;
  for (int b = 0; b < NBATCH; ++b) { float2 p = partials[b * NCH + o]; s += p.x; ss += p.y; }
  float inv = 1.f / (float)(NBATCH * SPAT);
  float mu = s * inv;
  float var = ss * inv - mu * mu;
  float scale = g[o] * rsqrtf(var + 1e-5f);
  sc[o] = c_mk(scale, bb[o] - mu * scale);
}

// ---------------- SO(3) conv ----------------

// 2D DFT of a real 32x32 tile -> 31x31 signed-order spectrum.
// Fused bn+relu applied on load (sc indexed by channel).
__global__ __launch_bounds__(256) void dft2b_kernel(const float* __restrict__ h,
                                                    const float2* __restrict__ sc,
                                                    float2* __restrict__ Xf) {
  __shared__ float xt[32 * 33];   // padded stride kills bank conflict
  __shared__ float2 P[32 * 16];   // [a][n], n = 0..15
  __shared__ float2 Xs[NQ];
  __shared__ float2 tw[32];
  fill_tw(tw);
  int tid = threadIdx.x;
  long long blk = blockIdx.x;
  int c = (int)((blk >> 5) % NCH);
  float2 s = sc[c];
  const float* src = h + blk * 1024;
  for (int e = tid; e < 1024; e += 256) {
    float v = src[e];
    xt[(e >> 5) * 33 + (e & 31)] = fmaxf(v * s.x + s.y, 0.f);
  }
  __syncthreads();
  // P[a,n] = sum_g x[a,g] e^{-i n g th}
  for (int e = tid; e < 512; e += 256) {
    int a = e >> 4, n = e & 15;
    float re = 0.f, im = 0.f;
    const float* row = xt + a * 33;
    #pragma unroll
    for (int g = 0; g < 32; ++g) {
      float v = row[g];
      float2 t = tw[(n * g) & 31];
      re += v * t.x; im -= v * t.y;
    }
    P[a * 16 + n] = c_mk(re, im);
  }
  __syncthreads();
  // X[m,n] = sum_a P[a,n] e^{-i m a th}; m=+mh and m=-mh together.
  {
    int e = tid;
    if (e < 256) {
      int mh = e >> 4, n = e & 15;
      float sxx = 0.f, sxy = 0.f, syx = 0.f, syy = 0.f;
      #pragma unroll
      for (int a = 0; a < 32; ++a) {
        float2 p = P[a * 16 + n];
        float2 t = tw[(mh * a) & 31];
        sxx += p.x * t.x; sxy += p.x * t.y;
        syx += p.y * t.x; syy += p.y * t.y;
      }
      float2 Xp = c_mk(sxx + syy, syx - sxy);   // X[+mh, n]
      float2 Xm = c_mk(sxx - syy, syx + sxy);   // X[-mh, n]
      Xs[(mh + MOFF) * MM + (n + MOFF)] = Xp;
      Xs[(MOFF - mh) * MM + (n + MOFF)] = Xm;
      Xs[(MOFF - mh) * MM + (MOFF - n)] = c_mk(Xp.x, -Xp.y);
      Xs[(mh + MOFF) * MM + (MOFF - n)] = c_mk(Xm.x, -Xm.y);
    }
  }
  __syncthreads();
  float2* dst = Xf + blk * NQ;
  for (int e = tid; e < NQ; e += 256) dst[e] = Xs[e];
}

// xh[bc,l,q] = sum_j qw[j]*dbeta[j,l,q]*Xf[bc,j,q]   (q = mi*MM+ni)
__global__ void xh_kernel(const float2* __restrict__ Xf, const float* __restrict__ qw,
                          const float* __restrict__ dbeta, float2* __restrict__ xh) {
  int idx = blockIdx.x * blockDim.x + threadIdx.x;
  if (idx >= NBATCH * NCH * NQ) return;
  int q = idx % NQ;
  int bc = idx / NQ;
  float2 acc[LL];
  #pragma unroll
  for (int l = 0; l < LL; ++l) acc[l] = c_mk(0.f, 0.f);
  for (int j = 0; j < NB; ++j) {
    float2 xv = Xf[((long long)bc * NB + j) * NQ + q];
    float qj = qw[j];
    const float* dbase = dbeta + (long long)(j * LL) * NQ + q;
    #pragma unroll
    for (int l = 0; l < LL; ++l) {
      float w = qj * dbase[l * NQ];
      acc[l].x += w * xv.x;
      acc[l].y += w * xv.y;
    }
  }
  #pragma unroll
  for (int l = 0; l < LL; ++l) xh[((long long)bc * LL + l) * NQ + q] = acc[l];
}

// hk2[r][ni][ich], r = (l*8+b)*31+mi (l-major). Support sparsity:
// entire block zero (skipped) when |mi-15|>l; ni loop restricted to
// [15-l, 15+l]. k-loop stays full (xh entries outside are exact zeros).
// Unwritten hk2 rows hold garbage -> masked by dbT zeros in fjq.
__global__ __launch_bounds__(64) void hk_kernel(const float2* __restrict__ xh,
                                                const float* __restrict__ deq,
                                                float2* __restrict__ hk2) {
  int r = blockIdx.x;                 // (l*8+b)*31 + mi
  int mi = r % MM;
  int lb = r / MM;                    // l*8 + b
  int b = lb & 7;
  int l = lb >> 3;
  int adm = mi - MOFF; adm = adm < 0 ? -adm : adm;
  if (adm > l) return;
  int ich = threadIdx.x;
  if (ich >= NCH) return;
  float2 row[MM];
  const float2* src = xh + ((long long)(b * NCH + ich) * LL + l) * NQ + mi * MM;
  #pragma unroll
  for (int k = 0; k < MM; ++k) row[k] = src[k];
  const float* dl = deq + l * NQ;
  long long obase = (long long)r * MM * NCH + ich;
  for (int ni = MOFF - l; ni <= MOFF + l; ++ni) {
    const float* dr = dl + ni * MM;
    float re = 0.f, im = 0.f;
    #pragma unroll
    for (int k = 0; k < MM; ++k) {
      float d = dr[k];
      re += d * row[k].x;
      im += d * row[k].y;
    }
    hk2[obase + (long long)ni * NCH] = c_mk(re, im);
  }
}

// z[b][o][l][ni][mi] = sum_i hk2[(r*31+ni)*50+i] * conj(Wf[ni,i,o]).
// Rows l-major; per ni only tiles with l >= |ni-15| are launched (512 blocks).
// 124 rows x 2 o-halves = 248 active threads. Wf[ni] slice staged in LDS.
__global__ __launch_bounds__(256) void z_kernel(const float2* __restrict__ hk2,
                                                const float2* __restrict__ Wf,
                                                float2* __restrict__ z) {
  __shared__ float2 ws[NCH * NCH];   // 20 KB
  int blk = blockIdx.x;
  int ni = 0;
  for (;;) {
    int d = ni - MOFF; if (d < 0) d = -d;
    int nt = 32 - 2 * d;
    if (blk < nt) break;
    blk -= nt; ++ni;
  }
  int dmin = ni - MOFF; if (dmin < 0) dmin = -dmin;
  int tid = threadIdx.x;
  {
    const float4* s4 = reinterpret_cast<const float4*>(Wf + ni * (NCH * NCH));
    float4* d4 = reinterpret_cast<float4*>(ws);
    for (int e = tid; e < NCH * NCH / 2; e += 256) d4[e] = s4[e];
  }
  __syncthreads();
  if (tid >= 248) return;
  int r = dmin * 248 + blk * 124 + (tid % 124);
  int o0 = (tid / 124) * 25;
  int mi = r % MM;
  int rem = r / MM;                  // l*8 + b
  int b = rem & 7;
  int l = rem >> 3;

  const float4* h4 = reinterpret_cast<const float4*>(hk2 + ((long long)r * MM + ni) * NCH);

  float2 acc[25];
  #pragma unroll
  for (int u = 0; u < 25; ++u) acc[u] = c_mk(0.f, 0.f);

  for (int ih = 0; ih < 25; ++ih) {     // 2 channels per iteration
    float4 hv = h4[ih];
    const float2* w0 = ws + (2 * ih) * NCH + o0;
    #pragma unroll
    for (int u = 0; u < 25; ++u) {
      float2 w = w0[u];
      acc[u].x += hv.x * w.x + hv.y * w.y;
      acc[u].y += hv.y * w.x - hv.x * w.y;
    }
    const float2* w1 = w0 + NCH;
    #pragma unroll
    for (int u = 0; u < 25; ++u) {
      float2 w = w1[u];
      acc[u].x += hv.z * w.x + hv.w * w.y;
      acc[u].y += hv.w * w.x - hv.z * w.y;
    }
  }

  long long zbase = (((long long)(b * NCH + o0) * LL + l) * NQ) + ni * MM + mi;
  #pragma unroll
  for (int u = 0; u < 25; ++u)
    z[zbase + (long long)u * LL * NQ] = acc[u];
}

// ---------------- head ----------------

// pool with fused bn+relu (layer-3 scale/shift applied per element)
__global__ void pool_kernel(const float* __restrict__ h, const float2* __restrict__ sc,
                            float* __restrict__ pooled) {
  __shared__ float sm[256];
  int tid = threadIdx.x;
  int o = blockIdx.x % NCH;
  float2 s = sc[o];
  const float* base = h + (long long)blockIdx.x * SPAT;
  float best = -1e30f;
  for (int e = tid; e < 1024; e += 256) {
    float acc = 0.f;
    for (int g = 0; g < NB; ++g) {
      float v = base[e * NB + g];
      acc += fmaxf(v * s.x + s.y, 0.f);
    }
    best = fmaxf(best, acc * (1.f / 32.f));
  }
  sm[tid] = best;
  __syncthreads();
  for (int st = 128; st > 0; st >>= 1) {
    if (tid < st) sm[tid] = fmaxf(sm[tid], sm[tid + st]);
    __syncthreads();
  }
  if (tid == 0) pooled[blockIdx.x] = sm[0];
}

__global__ __launch_bounds__(256) void head_kernel(const float* __restrict__ pooled,
    const float* __restrict__ fc1w, const float* __restrict__ fc1b,
    const float* __restrict__ g1, const float* __restrict__ b1,
    const float* __restrict__ fc2w, const float* __restrict__ fc2b,
    const float* __restrict__ g2, const float* __restrict__ b2,
    const float* __restrict__ fc3w, const float* __restrict__ fc3b,
    float* __restrict__ out) {
  __shared__ float pin[NBATCH * NCH];
  __shared__ float A[NBATCH * 256];
  __shared__ float Bm[NBATCH * 128];
  __shared__ float Cm[NBATCH * 40];
  int tid = threadIdx.x;
  for (int e = tid; e < NBATCH * NCH; e += 256) pin[e] = pooled[e];
  __syncthreads();
  {
    float v[NBATCH];
    #pragma unroll
    for (int b = 0; b < NBATCH; ++b) {
      float acc = fc1b[tid];
      for (int c = 0; c < NCH; ++c) acc += pin[b * NCH + c] * fc1w[tid * NCH + c];
      v[b] = acc;
    }
    float s = 0.f, ss = 0.f;
    #pragma unroll
    for (int b = 0; b < NBATCH; ++b) { s += v[b]; ss += v[b] * v[b]; }
    float mu = s * 0.125f, var = ss * 0.125f - mu * mu;
    float sc = g1[tid] * rsqrtf(var + 1e-5f), sh = b1[tid] - mu * sc;
    #pragma unroll
    for (int b = 0; b < NBATCH; ++b) A[b * 256 + tid] = fmaxf(v[b] * sc + sh, 0.f);
  }
  __syncthreads();
  if (tid < 128) {
    float v[NBATCH];
    #pragma unroll
    for (int b = 0; b < NBATCH; ++b) {
      float acc = fc2b[tid];
      for (int c = 0; c < 256; ++c) acc += A[b * 256 + c] * fc2w[tid * 256 + c];
      v[b] = acc;
    }
    float s = 0.f, ss = 0.f;
    #pragma unroll
    for (int b = 0; b < NBATCH; ++b) { s += v[b]; ss += v[b] * v[b]; }
    float mu = s * 0.125f, var = ss * 0.125f - mu * mu;
    float sc = g2[tid] * rsqrtf(var + 1e-5f), sh = b2[tid] - mu * sc;
    #pragma unroll
    for (int b = 0; b < NBATCH; ++b) Bm[b * 128 + tid] = fmaxf(v[b] * sc + sh, 0.f);
  }
  __syncthreads();
  if (tid < 40) {
    #pragma unroll
    for (int b = 0; b < NBATCH; ++b) {
      float acc = fc3b[tid];
      for (int c = 0; c < 128; ++c) acc += Bm[b * 128 + c] * fc3w[tid * 128 + c];
      Cm[b * 40 + tid] = acc;
    }
  }
  __syncthreads();
  if (tid < NBATCH) {
    int b = tid;
    float mx = -1e30f;
    for (int f = 0; f < 40; ++f) mx = fmaxf(mx, Cm[b * 40 + f]);
    float se = 0.f;
    for (int f = 0; f < 40; ++f) se += expf(Cm[b * 40 + f] - mx);
    float lse = mx + logf(se);
    for (int f = 0; f < 40; ++f) out[b * 40 + f] = Cm[b * 40 + f] - lse;
  }
}

// ---------------- host ----------------

extern "C" void kernel_launch(void* const* d_in, const int* in_sizes, int n_in,
                              void* d_out, int out_size, void* d_ws, size_t ws_size,
                              hipStream_t stream) {
  (void)in_sizes; (void)n_in; (void)out_size;
  const float* x    = (const float*)d_in[0];
  const float* k1   = (const float*)d_in[1];
  const float* c1b  = (const float*)d_in[2];
  const float* bn1g = (const float*)d_in[3];
  const float* bn1b = (const float*)d_in[4];
  const float* k2   = (const float*)d_in[5];
  const float* c2b  = (const float*)d_in[6];
  const float* bn2g = (const float*)d_in[7];
  const float* bn2b = (const float*)d_in[8];
  const float* k3   = (const float*)d_in[9];
  const float* c3b  = (const float*)d_in[10];
  const float* bn3g = (const float*)d_in[11];
  const float* bn3b = (const float*)d_in[12];
  const float* fc1w = (const float*)d_in[13];
  const float* fc1b = (const float*)d_in[14];
  const float* g1   = (const float*)d_in[15];
  const float* bb1  = (const float*)d_in[16];
  const float* fc2w = (const float*)d_in[17];
  const float* fc2b = (const float*)d_in[18];
  const float* g2   = (const float*)d_in[19];
  const float* bb2  = (const float*)d_in[20];
  const float* fc3w = (const float*)d_in[21];
  const float* fc3b = (const float*)d_in[22];
  float* out = (float*)d_out;

  char* ws = (char*)d_ws;
  size_t off = 0;
  auto alloc = [&](size_t n) -> char* {
    char* p = ws + off;
    off += (n + 255) & ~(size_t)255;
    return p;
  };

  float*  dbeta  = (float*)alloc(sizeof(float) * NB * LL * NQ);      // 1.97 MB
  float*  dbT    = (float*)alloc(sizeof(float) * NB * LL * NQ);      // 1.97 MB
  float*  deq    = (float*)alloc(sizeof(float) * LL * NQ);
  float*  qw     = (float*)alloc(sizeof(float) * NB);
  float2* xh1    = (float2*)alloc(sizeof(float2) * NBATCH * LL * MM);
  float2* Wf     = (float2*)alloc(sizeof(float2) * MM * NCH * NCH);  // 620 KB
  float2* parts  = (float2*)alloc(sizeof(float2) * NBATCH * NCH);
  float2* bnsc   = (float2*)alloc(sizeof(float2) * 64);
  float*  pooled = (float*)alloc(sizeof(float) * NBATCH * NCH);
  float*  HA     = (float*)alloc(sizeof(float) * (size_t)HN);        // 52.4 MB
  float*  HB     = (float*)alloc(sizeof(float) * (size_t)HN);        // 52.4 MB
  size_t XFB = (size_t)NBATCH * NCH * NB * NQ * sizeof(float2);      // 98.4 MB
  size_t XHB = (size_t)NBATCH * NCH * LL * NQ * sizeof(float2);      // 49.2 MB
  char* AR = alloc(XFB + XHB);                                       // 147.6 MB arena
  float2* Xf  = (float2*)AR;           // live: dft2 -> xh
  float2* xh  = (float2*)(AR + XFB);   // live: xh -> hk
  float2* hk2 = (float2*)AR;           // live: hk -> z    (reuses dead Xf)
  float2* zb  = (float2*)(AR + XFB);   // live: z -> fjq   (reuses dead xh; also z1)
  float2* Fb  = (float2*)AR;           // live: fjq -> dft (reuses dead hk2/Xf; 98.4 MB exact)

  if (ws_size < off) return;  // insufficient scratch: leave d_out zeroed

  const int T = 256;
  const size_t PARTS_B = sizeof(float2) * NBATCH * NCH;
  // constants
  qw_kernel<<<1, 32, 0, stream>>>(qw);
  wigner_kernel<<<(NB * LL * NQ + T - 1) / T, T, 0, stream>>>(dbeta, NB, 0);
  wigner_kernel<<<(LL * NQ + T - 1) / T, T, 0, stream>>>(deq, 1, 1);
  transpose_d_kernel<<<(NB * LL * NQ + T - 1) / T, T, 0, stream>>>(dbeta, dbT);

  // ---- layer 1: S2 conv -> HA
  s2_xh_kernel<<<NBATCH, T, 0, stream>>>(x, qw, dbeta, xh1);
  wfft_kernel<<<(MM * 1 * NCH + T - 1) / T, T, 0, stream>>>(k1, 1 * NCH, Wf);
  s2_z_kernel<<<(NBATCH * NCH * LL * NQ + T - 1) / T, T, 0, stream>>>(xh1, Wf, deq, zb);
  fjq_kernel<<<121 * 16, T, 0, stream>>>(zb, dbT, Fb);
  hipMemsetAsync(parts, 0, PARTS_B, stream);
  so3_dft_kernel<<<NBATCH * NCH * NB / 2, 64, 0, stream>>>(Fb, c1b, HA, parts);
  bn_finalize_kernel<<<1, 64, 0, stream>>>(parts, bn1g, bn1b, bnsc);

  // ---- layer 2: SO(3) conv HA -> HB (bn1+relu fused into dft2b load)
  dft2b_kernel<<<NBATCH * NCH * NB, T, 0, stream>>>(HA, bnsc, Xf);
  xh_kernel<<<(NBATCH * NCH * NQ + T - 1) / T, T, 0, stream>>>(Xf, qw, dbeta, xh);
  wfft_kernel<<<(MM * NCH * NCH + T - 1) / T, T, 0, stream>>>(k2, NCH * NCH, Wf);
  hk_kernel<<<NBATCH * LL * MM, 64, 0, stream>>>(xh, deq, hk2);
  z_kernel<<<512, T, 0, stream>>>(hk2, Wf, zb);
  fjq_kernel<<<121 * 16, T, 0, stream>>>(zb, dbT, Fb);
  hipMemsetAsync(parts, 0, PARTS_B, stream);
  so3_dft_kernel<<<NBATCH * NCH * NB / 2, 64, 0, stream>>>(Fb, c2b, HB, parts);
  bn_finalize_kernel<<<1, 64, 0, stream>>>(parts, bn2g, bn2b, bnsc);

  // ---- layer 3: SO(3) conv HB -> HA (bn2+relu fused into dft2b load)
  dft2b_kernel<<<NBATCH * NCH * NB, T, 0, stream>>>(HB, bnsc, Xf);
  xh_kernel<<<(NBATCH * NCH * NQ + T - 1) / T, T, 0, stream>>>(Xf, qw, dbeta, xh);
  wfft_kernel<<<(MM * NCH * NCH + T - 1) / T, T, 0, stream>>>(k3, NCH * NCH, Wf);
  hk_kernel<<<NBATCH * LL * MM, 64, 0, stream>>>(xh, deq, hk2);
  z_kernel<<<512, T, 0, stream>>>(hk2, Wf, zb);
  fjq_kernel<<<121 * 16, T, 0, stream>>>(zb, dbT, Fb);
  hipMemsetAsync(parts, 0, PARTS_B, stream);
  so3_dft_kernel<<<NBATCH * NCH * NB / 2, 64, 0, stream>>>(Fb, c3b, HA, parts);
  bn_finalize_kernel<<<1, 64, 0, stream>>>(parts, bn3g, bn3b, bnsc);

  // ---- head (bn3+relu fused into pool)
  pool_kernel<<<NBATCH * NCH, T, 0, stream>>>(HA, bnsc, pooled);
  head_kernel<<<1, T, 0, stream>>>(pooled, fc1w, fc1b, g1, bb1,
                                   fc2w, fc2b, g2, bb2, fc3w, fc3b, out);
}

// Round 10
// 782.152 us; speedup vs baseline: 4.0562x; 1.0218x over previous
//
#include <hip/hip_runtime.h>
#include <math.h>

constexpr int NB = 32;       // samples per angle
constexpr int LL = 16;       // bandwidth
constexpr int MM = 31;       // spectral orders (2*BW-1)
constexpr int MOFF = 15;
constexpr int NBATCH = 8;
constexpr int NCH = 50;
constexpr int NQ = MM * MM;          // 961
constexpr int SPAT = NB * NB * NB;   // 32768
constexpr long long HN = (long long)NBATCH * NCH * SPAT;  // 13,107,200

#define PI_D 3.14159265358979323846

__device__ inline float2 c_mk(float x, float y) { float2 r; r.x = x; r.y = y; return r; }

__device__ inline void fill_tw(float2* tw) {
  int t = threadIdx.x;
  if (t < 32) {
    double a = (double)t * (PI_D / 16.0);
    tw[t] = c_mk((float)cos(a), (float)sin(a));
  }
}

__device__ inline int bitrev5(int n) {
  return ((n & 1) << 4) | ((n & 2) << 2) | (n & 4) | ((n & 8) >> 2) | ((n & 16) >> 4);
}

__device__ inline double dpow(double x, int n) {
  double r = 1.0;
  for (int i = 0; i < n; ++i) r *= x;
  return r;
}

// ---------------- constants ----------------

__global__ void qw_kernel(float* __restrict__ qw) {
  int j = threadIdx.x;
  if (j >= NB) return;
  double beta = PI_D * (2 * j + 1) / 64.0;
  double acc = 0.0;
  for (int kk = 0; kk < LL; ++kk)
    acc += sin((double)(2 * j + 1) * (2 * kk + 1) * PI_D / 64.0) / (double)(2 * kk + 1);
  qw[j] = (float)((2.0 / 16.0) * sin(beta) * acc);
}

// out layout [j][l][mp][m]; eqmode: nj==1, beta=pi/2
__global__ void wigner_kernel(float* __restrict__ out, int nj, int eqmode) {
  __shared__ double fact[66];
  int tid = threadIdx.x;
  if (tid < 66) { double f = 1.0; for (int i = 2; i <= tid; ++i) f *= (double)i; fact[tid] = f; }
  __syncthreads();
  int total = nj * LL * NQ;
  int idx = blockIdx.x * blockDim.x + tid;
  if (idx >= total) return;
  int q = idx % NQ;
  int l = (idx / NQ) % LL;
  int j = idx / (NQ * LL);
  int mp = q / MM - MOFF;
  int m  = q % MM - MOFF;
  int amp = mp < 0 ? -mp : mp, am = m < 0 ? -m : m;
  float res = 0.f;
  if (amp <= l && am <= l) {
    double beta = eqmode ? (PI_D * 0.5) : (PI_D * (2 * j + 1) / 64.0);
    double c = cos(beta * 0.5), s = sin(beta * 0.5);
    double pref = sqrt(fact[l + mp] * fact[l - mp] * fact[l + m] * fact[l - m]);
    int k0 = max(0, m - mp), k1 = min(l + m, l - mp);
    double acc = 0.0;
    for (int k = k0; k <= k1; ++k) {
      double denom = fact[l + m - k] * fact[k] * fact[l - k - mp] * fact[k - m + mp];
      double term = dpow(c, 2 * l - 2 * k + m - mp) * dpow(s, 2 * k - m + mp) / denom;
      acc += ((mp - m + k) & 1) ? -term : term;
    }
    res = (float)(pref * acc);
  }
  out[idx] = res;
}

// dbT[j][l][n][m] = dbeta[j][l][m][n]
__global__ void transpose_d_kernel(const float* __restrict__ dbeta, float* __restrict__ dbT) {
  int idx = blockIdx.x * blockDim.x + threadIdx.x;
  if (idx >= NB * LL * NQ) return;
  int m = idx % MM;
  int n = (idx / MM) % MM;
  int jl = idx / NQ;
  dbT[idx] = dbeta[jl * NQ + m * MM + n];
}

// ---------------- layer 1 (S2 conv) ----------------

__global__ __launch_bounds__(256) void s2_xh_kernel(const float* __restrict__ x,
                                                    const float* __restrict__ qw,
                                                    const float* __restrict__ dbeta,
                                                    float2* __restrict__ xh1) {
  __shared__ float xt[NB * NB];
  __shared__ float2 Xf0[NB * MM];
  __shared__ float2 tw[32];
  fill_tw(tw);
  int tid = threadIdx.x, b = blockIdx.x;
  for (int e = tid; e < NB * NB; e += 256) xt[e] = x[b * 1024 + e];
  __syncthreads();
  for (int e = tid; e < NB * MM; e += 256) {
    int j = e / MM, mi = e % MM, m = mi - MOFF;
    float re = 0.f, im = 0.f;
    const float* row = xt + j * NB;
    for (int a = 0; a < NB; ++a) {
      float v = row[a];
      float2 t = tw[(m * a) & 31];
      re += v * t.x; im -= v * t.y;   // e^{-i m a th}
    }
    Xf0[e] = c_mk(re, im);
  }
  __syncthreads();
  for (int e = tid; e < LL * MM; e += 256) {
    int l = e / MM, mi = e % MM;
    float re = 0.f, im = 0.f;
    for (int j = 0; j < NB; ++j) {
      float w = qw[j] * dbeta[(j * LL + l) * NQ + mi * MM + MOFF];
      float2 X = Xf0[j * MM + mi];
      re += w * X.x; im += w * X.y;
    }
    xh1[(b * LL + l) * MM + mi] = c_mk(re, im);
  }
}

// Wf[ni][ic] = sum_t W[ic][t] e^{-2pi i n t/32}, ic = i*Co+o
__global__ __launch_bounds__(256) void wfft_kernel(const float* __restrict__ W, int CiCo,
                                                   float2* __restrict__ Wf) {
  __shared__ float2 tw[32];
  fill_tw(tw);
  __syncthreads();
  int idx = blockIdx.x * blockDim.x + threadIdx.x;
  if (idx >= MM * CiCo) return;
  int ni = idx / CiCo, ic = idx % CiCo;
  int n = ni - MOFF;
  float re = 0.f, im = 0.f;
  for (int t = 0; t < NB; ++t) {
    float v = W[ic * NB + t];
    float2 tt = tw[(n * t) & 31];
    re += v * tt.x; im -= v * tt.y;
  }
  Wf[idx] = c_mk(re, im);
}

// z layout: [b][o][l][ni][mi].  z = deq0[l,ni] * xh1[b,l,mi] * conj(Wf1[ni,o])
__global__ void s2_z_kernel(const float2* __restrict__ xh1, const float2* __restrict__ Wf1,
                            const float* __restrict__ deq, float2* __restrict__ z) {
  int idx = blockIdx.x * blockDim.x + threadIdx.x;
  if (idx >= NBATCH * NCH * LL * NQ) return;
  int mi = idx % MM; int t = idx / MM;
  int ni = t % MM; t /= MM;
  int l = t % LL; t /= LL;
  int o = t % NCH; int b = t / NCH;
  float d0 = deq[(l * MM + ni) * MM + MOFF];
  float2 xv = xh1[(b * LL + l) * MM + mi];
  float2 wv = Wf1[ni * NCH + o];
  float re = d0 * (xv.x * wv.x + xv.y * wv.y);
  float im = d0 * (xv.y * wv.x - xv.x * wv.y);
  z[idx] = c_mk(re, im);
}

// ---------------- SO(3) inverse transform: split into fjq + dft ----------------

// F[bo][j][q] = sum_l (2l+1) * d^l_{m,n}(beta_j) * z[bo][l][q], q = ni*31+mi.
// Staging skips z entries with l < |ni-15| (dbT is exactly 0 there).
__global__ __launch_bounds__(256) void fjq_kernel(const float2* __restrict__ z,
                                                  const float* __restrict__ dbT,
                                                  float2* __restrict__ F) {
  __shared__ float2 zs[2][LL][8];
  int qg = blockIdx.x % 121;
  int bg = blockIdx.x / 121;
  int tid = threadIdx.x;
  int j = tid >> 3, ql = tid & 7;
  int q = qg * 8 + ql;
  bool qok = q < NQ;
  int qc = qok ? q : NQ - 1;
  float w[LL];
  #pragma unroll
  for (int l = 0; l < LL; ++l)
    w[l] = (2.f * l + 1.f) * dbT[(j * LL + l) * NQ + qc];
  int bo0 = bg * 25;
  if (tid < 128) {
    int l = tid >> 3, qq = qg * 8 + (tid & 7);
    int dd = (qq < NQ) ? (qq / MM - MOFF) : 99; if (dd < 0) dd = -dd;
    zs[0][l][tid & 7] = (l >= dd) ? z[((long long)bo0 * LL + l) * NQ + qq] : c_mk(0.f, 0.f);
  }
  __syncthreads();
  for (int i = 0; i < 25; ++i) {
    int bo = bo0 + i;
    if (i < 24 && tid < 128) {
      int l = tid >> 3, qq = qg * 8 + (tid & 7);
      int dd = (qq < NQ) ? (qq / MM - MOFF) : 99; if (dd < 0) dd = -dd;
      zs[(i + 1) & 1][l][tid & 7] =
          (l >= dd) ? z[((long long)(bo + 1) * LL + l) * NQ + qq] : c_mk(0.f, 0.f);
    }
    float fr = 0.f, fi = 0.f;
    #pragma unroll
    for (int l = 0; l < LL; ++l) {
      float2 zv = zs[i & 1][l][ql];
      fr += w[l] * zv.x; fi += w[l] * zv.y;
    }
    if (qok) F[((long long)bo * NB + j) * NQ + q] = c_mk(fr, fi);
    __syncthreads();
  }
}

// One wave per block, 2 (bo,j) tiles (lanes 0-31 / 32-63). Register radix-2 FFT.
__global__ __launch_bounds__(64) void so3_dft_kernel(const float2* __restrict__ F,
                                                     const float* __restrict__ bias,
                                                     float* __restrict__ out,
                                                     float2* __restrict__ parts) {
  __shared__ float Sre[2][32][33];
  __shared__ float Sim[2][32][33];
  __shared__ float2 tw[32];
  fill_tw(tw);
  int tid = threadIdx.x;
  int lane = tid & 31;
  int t = tid >> 5;                 // tile within block
  int idx = blockIdx.x * 2 + t;     // global tile
  int j = idx & 31;
  int bo = idx >> 5;                // same for both tiles (2 | 32)
  int o = bo % NCH;

  // zero bin-16 row and column
  Sre[t][16][lane] = 0.f; Sim[t][16][lane] = 0.f;
  Sre[t][lane][16] = 0.f; Sim[t][lane][16] = 0.f;
  __syncthreads();

  // load F row, bin-mapped: S[(ni+17)&31][(mi+17)&31]
  const float2* src = F + ((long long)bo * NB + j) * NQ;
  for (int e = lane; e < NQ; e += 32) {
    int ni = e / MM, mi = e % MM;
    float2 v = src[e];
    Sre[t][(ni + 17) & 31][(mi + 17) & 31] = v.x;
    Sim[t][(ni + 17) & 31][(mi + 17) & 31] = v.y;
  }
  __syncthreads();

  float vr[32], vi[32];

  // ---- dim0 FFT (column = lane), fully in registers
  #pragma unroll
  for (int r = 0; r < 32; ++r) { vr[r] = Sre[t][r][lane]; vi[r] = Sim[t][r][lane]; }
  #pragma unroll
  for (int st = 0; st < 5; ++st) {
    const int half = 16 >> st, tmul = 1 << st;
    #pragma unroll
    for (int p = 0; p < 16; ++p) {
      const int j2 = p & (half - 1);
      const int i0 = ((p >> (4 - st)) << (5 - st)) + j2;
      const int i1 = i0 + half;
      float2 tt = tw[(j2 * tmul) & 31];
      float ur = vr[i0], ui = vi[i0], wr = vr[i1], wi = vi[i1];
      float dr = ur - wr, di = ui - wi;
      vr[i0] = ur + wr; vi[i0] = ui + wi;
      vr[i1] = dr * tt.x - di * tt.y;
      vi[i1] = dr * tt.y + di * tt.x;
    }
  }
  // write back un-bit-reversed: X[k] lives at v[bitrev5(k)]
  #pragma unroll
  for (int k = 0; k < 32; ++k) {
    Sre[t][k][lane] = vr[bitrev5(k)];
    Sim[t][k][lane] = vi[bitrev5(k)];
  }
  __syncthreads();

  // ---- dim1 FFT (row = lane = g), in registers
  #pragma unroll
  for (int m = 0; m < 32; ++m) { vr[m] = Sre[t][lane][m]; vi[m] = Sim[t][lane][m]; }
  #pragma unroll
  for (int st = 0; st < 5; ++st) {
    const int half = 16 >> st, tmul = 1 << st;
    #pragma unroll
    for (int p = 0; p < 16; ++p) {
      const int j2 = p & (half - 1);
      const int i0 = ((p >> (4 - st)) << (5 - st)) + j2;
      const int i1 = i0 + half;
      float2 tt = tw[(j2 * tmul) & 31];
      float ur = vr[i0], ui = vi[i0], wr = vr[i1], wi = vi[i1];
      float dr = ur - wr, di = ui - wi;
      vr[i0] = ur + wr; vi[i0] = ui + wi;
      vr[i1] = dr * tt.x - di * tt.y;
      vi[i1] = dr * tt.y + di * tt.x;
    }
  }

  // ---- store out[a,g] = Re X[a] + bias (g = lane), fused bn stats
  float bval = bias[o];
  long long obase = (long long)bo * SPAT + (long long)j * 1024 + lane;
  float s1 = 0.f, s2 = 0.f;
  #pragma unroll
  for (int a = 0; a < 32; ++a) {
    float val = vr[bitrev5(a)] + bval;
    out[obase + a * 32] = val;
    s1 += val; s2 += val * val;
  }
  #pragma unroll
  for (int off = 32; off > 0; off >>= 1) {
    s1 += __shfl_down(s1, off);
    s2 += __shfl_down(s2, off);
  }
  if (tid == 0) {
    atomicAdd(&parts[bo].x, s1);
    atomicAdd(&parts[bo].y, s2);
  }
}

// ---------------- batchnorm ----------------

__global__ void bn_finalize_kernel(const float2* __restrict__ partials,
                                   const float* __restrict__ g, const float* __restrict__ bb,
                                   float2* __restrict__ sc) {
  int o = threadIdx.x;
  if (o >= NCH) return;
  float s = 0.f, ss = 0.f;
  for (int b = 0; b < NBATCH; ++b) { float2 p = partials[b * NCH + o]; s += p.x; ss += p.y; }
  float inv = 1.f / (float)(NBATCH * SPAT);
  float mu = s * inv;
  float var = ss * inv - mu * mu;
  float scale = g[o] * rsqrtf(var + 1e-5f);
  sc[o] = c_mk(scale, bb[o] - mu * scale);
}

// ---------------- SO(3) conv ----------------

// 2D DFT of a real 32x32 tile -> 31x31 signed-order spectrum.
// Fused bn+relu applied on load (sc indexed by channel).
__global__ __launch_bounds__(256) void dft2b_kernel(const float* __restrict__ h,
                                                    const float2* __restrict__ sc,
                                                    float2* __restrict__ Xf) {
  __shared__ float xt[32 * 33];   // padded stride kills bank conflict
  __shared__ float2 P[32 * 16];   // [a][n], n = 0..15
  __shared__ float2 Xs[NQ];
  __shared__ float2 tw[32];
  fill_tw(tw);
  int tid = threadIdx.x;
  long long blk = blockIdx.x;
  int c = (int)((blk >> 5) % NCH);
  float2 s = sc[c];
  const float* src = h + blk * 1024;
  for (int e = tid; e < 1024; e += 256) {
    float v = src[e];
    xt[(e >> 5) * 33 + (e & 31)] = fmaxf(v * s.x + s.y, 0.f);
  }
  __syncthreads();
  // P[a,n] = sum_g x[a,g] e^{-i n g th}
  for (int e = tid; e < 512; e += 256) {
    int a = e >> 4, n = e & 15;
    float re = 0.f, im = 0.f;
    const float* row = xt + a * 33;
    #pragma unroll
    for (int g = 0; g < 32; ++g) {
      float v = row[g];
      float2 t = tw[(n * g) & 31];
      re += v * t.x; im -= v * t.y;
    }
    P[a * 16 + n] = c_mk(re, im);
  }
  __syncthreads();
  // X[m,n] = sum_a P[a,n] e^{-i m a th}; m=+mh and m=-mh together.
  {
    int e = tid;
    if (e < 256) {
      int mh = e >> 4, n = e & 15;
      float sxx = 0.f, sxy = 0.f, syx = 0.f, syy = 0.f;
      #pragma unroll
      for (int a = 0; a < 32; ++a) {
        float2 p = P[a * 16 + n];
        float2 t = tw[(mh * a) & 31];
        sxx += p.x * t.x; sxy += p.x * t.y;
        syx += p.y * t.x; syy += p.y * t.y;
      }
      float2 Xp = c_mk(sxx + syy, syx - sxy);   // X[+mh, n]
      float2 Xm = c_mk(sxx - syy, syx + sxy);   // X[-mh, n]
      Xs[(mh + MOFF) * MM + (n + MOFF)] = Xp;
      Xs[(MOFF - mh) * MM + (n + MOFF)] = Xm;
      Xs[(MOFF - mh) * MM + (MOFF - n)] = c_mk(Xp.x, -Xp.y);
      Xs[(mh + MOFF) * MM + (MOFF - n)] = c_mk(Xm.x, -Xm.y);
    }
  }
  __syncthreads();
  float2* dst = Xf + blk * NQ;
  for (int e = tid; e < NQ; e += 256) dst[e] = Xs[e];
}

// xh[bc,l,q] = sum_j qw[j]*dbeta[j,l,q]*Xf[bc,j,q]   (q = mi*MM+ni)
// Stores only supported l (l >= max(|mi-15|,|ni-15|)); unsupported entries
// are consumed only multiplied by exact-zero deq in hk.
__global__ void xh_kernel(const float2* __restrict__ Xf, const float* __restrict__ qw,
                          const float* __restrict__ dbeta, float2* __restrict__ xh) {
  int idx = blockIdx.x * blockDim.x + threadIdx.x;
  if (idx >= NBATCH * NCH * NQ) return;
  int q = idx % NQ;
  int bc = idx / NQ;
  int dm = q / MM - MOFF; if (dm < 0) dm = -dm;
  int dn = q % MM - MOFF; if (dn < 0) dn = -dn;
  int lmin = dm > dn ? dm : dn;
  float2 acc[LL];
  #pragma unroll
  for (int l = 0; l < LL; ++l) acc[l] = c_mk(0.f, 0.f);
  for (int j = 0; j < NB; ++j) {
    float2 xv = Xf[((long long)bc * NB + j) * NQ + q];
    float qj = qw[j];
    const float* dbase = dbeta + (long long)(j * LL) * NQ + q;
    #pragma unroll
    for (int l = 0; l < LL; ++l) {
      float w = qj * dbase[l * NQ];
      acc[l].x += w * xv.x;
      acc[l].y += w * xv.y;
    }
  }
  #pragma unroll
  for (int l = 0; l < LL; ++l)
    if (l >= lmin) xh[((long long)bc * LL + l) * NQ + q] = acc[l];
}

// hk2[r][ni][ich], r = (l*8+b)*31+mi (l-major). Support sparsity:
// entire block zero (skipped) when |mi-15|>l; ni loop restricted to
// [15-l, 15+l]. k-loop stays full (xh entries outside are exact zeros
// or masked-by-zero-deq garbage).
__global__ __launch_bounds__(64) void hk_kernel(const float2* __restrict__ xh,
                                                const float* __restrict__ deq,
                                                float2* __restrict__ hk2) {
  int r = blockIdx.x;                 // (l*8+b)*31 + mi
  int mi = r % MM;
  int lb = r / MM;                    // l*8 + b
  int b = lb & 7;
  int l = lb >> 3;
  int adm = mi - MOFF; adm = adm < 0 ? -adm : adm;
  if (adm > l) return;
  int ich = threadIdx.x;
  if (ich >= NCH) return;
  float2 row[MM];
  const float2* src = xh + ((long long)(b * NCH + ich) * LL + l) * NQ + mi * MM;
  #pragma unroll
  for (int k = 0; k < MM; ++k) row[k] = src[k];
  const float* dl = deq + l * NQ;
  long long obase = (long long)r * MM * NCH + ich;
  for (int ni = MOFF - l; ni <= MOFF + l; ++ni) {
    const float* dr = dl + ni * MM;
    float re = 0.f, im = 0.f;
    #pragma unroll
    for (int k = 0; k < MM; ++k) {
      float d = dr[k];
      re += d * row[k].x;
      im += d * row[k].y;
    }
    hk2[obase + (long long)ni * NCH] = c_mk(re, im);
  }
}

// z[b][o][l][ni][mi] = sum_i hk2[(r*31+ni)*50+i] * conj(Wf[ni,i,o]).
// Rows l-major; per ni only tiles with l >= |ni-15| are launched (512 blocks).
__global__ __launch_bounds__(256) void z_kernel(const float2* __restrict__ hk2,
                                                const float2* __restrict__ Wf,
                                                float2* __restrict__ z) {
  __shared__ float2 ws[NCH * NCH];   // 20 KB
  int blk = blockIdx.x;
  int ni = 0;
  for (;;) {
    int d = ni - MOFF; if (d < 0) d = -d;
    int nt = 32 - 2 * d;
    if (blk < nt) break;
    blk -= nt; ++ni;
  }
  int dmin = ni - MOFF; if (dmin < 0) dmin = -dmin;
  int tid = threadIdx.x;
  {
    const float4* s4 = reinterpret_cast<const float4*>(Wf + ni * (NCH * NCH));
    float4* d4 = reinterpret_cast<float4*>(ws);
    for (int e = tid; e < NCH * NCH / 2; e += 256) d4[e] = s4[e];
  }
  __syncthreads();
  if (tid >= 248) return;
  int r = dmin * 248 + blk * 124 + (tid % 124);
  int o0 = (tid / 124) * 25;
  int mi = r % MM;
  int rem = r / MM;                  // l*8 + b
  int b = rem & 7;
  int l = rem >> 3;

  const float4* h4 = reinterpret_cast<const float4*>(hk2 + ((long long)r * MM + ni) * NCH);

  float2 acc[25];
  #pragma unroll
  for (int u = 0; u < 25; ++u) acc[u] = c_mk(0.f, 0.f);

  for (int ih = 0; ih < 25; ++ih) {     // 2 channels per iteration
    float4 hv = h4[ih];
    const float2* w0 = ws + (2 * ih) * NCH + o0;
    #pragma unroll
    for (int u = 0; u < 25; ++u) {
      float2 w = w0[u];
      acc[u].x += hv.x * w.x + hv.y * w.y;
      acc[u].y += hv.y * w.x - hv.x * w.y;
    }
    const float2* w1 = w0 + NCH;
    #pragma unroll
    for (int u = 0; u < 25; ++u) {
      float2 w = w1[u];
      acc[u].x += hv.z * w.x + hv.w * w.y;
      acc[u].y += hv.w * w.x - hv.z * w.y;
    }
  }

  long long zbase = (((long long)(b * NCH + o0) * LL + l) * NQ) + ni * MM + mi;
  #pragma unroll
  for (int u = 0; u < 25; ++u)
    z[zbase + (long long)u * LL * NQ] = acc[u];
}

// ---------------- head ----------------

// pool with fused bn+relu (layer-3 scale/shift applied per element)
__global__ void pool_kernel(const float* __restrict__ h, const float2* __restrict__ sc,
                            float* __restrict__ pooled) {
  __shared__ float sm[256];
  int tid = threadIdx.x;
  int o = blockIdx.x % NCH;
  float2 s = sc[o];
  const float* base = h + (long long)blockIdx.x * SPAT;
  float best = -1e30f;
  for (int e = tid; e < 1024; e += 256) {
    float acc = 0.f;
    for (int g = 0; g < NB; ++g) {
      float v = base[e * NB + g];
      acc += fmaxf(v * s.x + s.y, 0.f);
    }
    best = fmaxf(best, acc * (1.f / 32.f));
  }
  sm[tid] = best;
  __syncthreads();
  for (int st = 128; st > 0; st >>= 1) {
    if (tid < st) sm[tid] = fmaxf(sm[tid], sm[tid + st]);
    __syncthreads();
  }
  if (tid == 0) pooled[blockIdx.x] = sm[0];
}

// All FC weights staged into LDS with coalesced reads; parallel (o,b)
// mappings; strides padded for low bank conflict. Fixes the latency-bound
// uncoalesced per-thread weight walks (was ~80 us for ~1.3 MFLOP).
__global__ __launch_bounds__(256) void head_kernel(const float* __restrict__ pooled,
    const float* __restrict__ fc1w, const float* __restrict__ fc1b,
    const float* __restrict__ g1, const float* __restrict__ b1,
    const float* __restrict__ fc2w, const float* __restrict__ fc2b,
    const float* __restrict__ g2, const float* __restrict__ b2,
    const float* __restrict__ fc3w, const float* __restrict__ fc3b,
    float* __restrict__ out) {
  __shared__ __align__(16) float WB[64 * 260];   // 66.6 KB staging
  __shared__ float pin[NBATCH * NCH];
  __shared__ float A[NBATCH * 256];
  __shared__ float R[NBATCH * 128];
  __shared__ float Bm[NBATCH * 128];
  __shared__ float Cm[NBATCH * 40];
  int tid = threadIdx.x;

  for (int e = tid; e < NBATCH * NCH; e += 256) pin[e] = pooled[e];
  // stage fc1w: row stride 51 (19 mod 32 -> conflict-free reads)
  for (int e = tid; e < 256 * 50; e += 256) {
    int row = e / 50, c = e % 50;
    WB[row * 51 + c] = fc1w[e];
  }
  __syncthreads();

  // ---- fc1: thread = output o (256), 8 batches each
  {
    int o = tid;
    const float* wr = WB + o * 51;
    float v[NBATCH];
    float bias = fc1b[o];
    #pragma unroll
    for (int b = 0; b < NBATCH; ++b) {
      float acc = bias;
      #pragma unroll
      for (int c = 0; c < NCH; ++c) acc += pin[b * NCH + c] * wr[c];
      v[b] = acc;
    }
    float s = 0.f, ss = 0.f;
    #pragma unroll
    for (int b = 0; b < NBATCH; ++b) { s += v[b]; ss += v[b] * v[b]; }
    float mu = s * 0.125f, var = ss * 0.125f - mu * mu;
    float sc = g1[o] * rsqrtf(var + 1e-5f), sh = b1[o] - mu * sc;
    #pragma unroll
    for (int b = 0; b < NBATCH; ++b) A[b * 256 + o] = fmaxf(v[b] * sc + sh, 0.f);
  }
  __syncthreads();

  // ---- fc2 in two row-chunks of 64 outputs; thread = (b, oo):
  // b = tid>>5, oo = tid&31 handles outputs oo and oo+32 of the chunk.
  for (int ch = 0; ch < 2; ++ch) {
    {
      const float4* s4 = reinterpret_cast<const float4*>(fc2w + ch * 64 * 256);
      float4* d4 = reinterpret_cast<float4*>(WB);
      for (int e = tid; e < 64 * 64; e += 256) {
        int row = e >> 6, k = e & 63;
        d4[row * 65 + k] = s4[e];
      }
    }
    __syncthreads();
    {
      int b = tid >> 5, oo = tid & 31;
      int o_a = ch * 64 + oo, o_b = o_a + 32;
      float acc0 = fc2b[o_a], acc1 = fc2b[o_b];
      const float4* av4 = reinterpret_cast<const float4*>(A + b * 256);
      const float4* w04 = reinterpret_cast<const float4*>(WB + oo * 260);
      const float4* w14 = reinterpret_cast<const float4*>(WB + (oo + 32) * 260);
      #pragma unroll
      for (int c4 = 0; c4 < 64; ++c4) {
        float4 av = av4[c4];
        float4 w0 = w04[c4];
        float4 w1 = w14[c4];
        acc0 += av.x * w0.x + av.y * w0.y + av.z * w0.z + av.w * w0.w;
        acc1 += av.x * w1.x + av.y * w1.y + av.z * w1.z + av.w * w1.w;
      }
      R[b * 128 + o_a] = acc0;
      R[b * 128 + o_b] = acc1;
    }
    __syncthreads();
  }
  // BN for fc2 + stage fc3w (independent; same phase)
  if (tid < 128) {
    int o = tid;
    float s = 0.f, ss = 0.f;
    #pragma unroll
    for (int b = 0; b < NBATCH; ++b) { float v = R[b * 128 + o]; s += v; ss += v * v; }
    float mu = s * 0.125f, var = ss * 0.125f - mu * mu;
    float sc = g2[o] * rsqrtf(var + 1e-5f), sh = b2[o] - mu * sc;
    #pragma unroll
    for (int b = 0; b < NBATCH; ++b) Bm[b * 128 + o] = fmaxf(R[b * 128 + o] * sc + sh, 0.f);
  }
  for (int e = tid; e < 40 * 128; e += 256) {
    int row = e >> 7, c = e & 127;
    WB[row * 129 + c] = fc3w[e];
  }
  __syncthreads();

  // ---- fc3: t<160: o = t>>2 (40), q = t&3 handles b=q and b=q+4
  if (tid < 160) {
    int o = tid >> 2, q = tid & 3;
    const float* wr = WB + o * 129;
    float a0 = fc3b[o], a1 = a0;
    #pragma unroll
    for (int c = 0; c < 128; ++c) {
      float w = wr[c];
      a0 += Bm[q * 128 + c] * w;
      a1 += Bm[(q + 4) * 128 + c] * w;
    }
    Cm[q * 40 + o] = a0;
    Cm[(q + 4) * 40 + o] = a1;
  }
  __syncthreads();
  if (tid < NBATCH) {
    int b = tid;
    float mx = -1e30f;
    for (int f = 0; f < 40; ++f) mx = fmaxf(mx, Cm[b * 40 + f]);
    float se = 0.f;
    for (int f = 0; f < 40; ++f) se += expf(Cm[b * 40 + f] - mx);
    float lse = mx + logf(se);
    for (int f = 0; f < 40; ++f) out[b * 40 + f] = Cm[b * 40 + f] - lse;
  }
}

// ---------------- host ----------------

extern "C" void kernel_launch(void* const* d_in, const int* in_sizes, int n_in,
                              void* d_out, int out_size, void* d_ws, size_t ws_size,
                              hipStream_t stream) {
  (void)in_sizes; (void)n_in; (void)out_size;
  const float* x    = (const float*)d_in[0];
  const float* k1   = (const float*)d_in[1];
  const float* c1b  = (const float*)d_in[2];
  const float* bn1g = (const float*)d_in[3];
  const float* bn1b = (const float*)d_in[4];
  const float* k2   = (const float*)d_in[5];
  const float* c2b  = (const float*)d_in[6];
  const float* bn2g = (const float*)d_in[7];
  const float* bn2b = (const float*)d_in[8];
  const float* k3   = (const float*)d_in[9];
  const float* c3b  = (const float*)d_in[10];
  const float* bn3g = (const float*)d_in[11];
  const float* bn3b = (const float*)d_in[12];
  const float* fc1w = (const float*)d_in[13];
  const float* fc1b = (const float*)d_in[14];
  const float* g1   = (const float*)d_in[15];
  const float* bb1  = (const float*)d_in[16];
  const float* fc2w = (const float*)d_in[17];
  const float* fc2b = (const float*)d_in[18];
  const float* g2   = (const float*)d_in[19];
  const float* bb2  = (const float*)d_in[20];
  const float* fc3w = (const float*)d_in[21];
  const float* fc3b = (const float*)d_in[22];
  float* out = (float*)d_out;

  char* ws = (char*)d_ws;
  size_t off = 0;
  auto alloc = [&](size_t n) -> char* {
    char* p = ws + off;
    off += (n + 255) & ~(size_t)255;
    return p;
  };

  float*  dbeta  = (float*)alloc(sizeof(float) * NB * LL * NQ);      // 1.97 MB
  float*  dbT    = (float*)alloc(sizeof(float) * NB * LL * NQ);      // 1.97 MB
  float*  deq    = (float*)alloc(sizeof(float) * LL * NQ);
  float*  qw     = (float*)alloc(sizeof(float) * NB);
  float2* xh1    = (float2*)alloc(sizeof(float2) * NBATCH * LL * MM);
  float2* Wf     = (float2*)alloc(sizeof(float2) * MM * NCH * NCH);  // 620 KB
  float2* parts  = (float2*)alloc(sizeof(float2) * NBATCH * NCH);
  float2* bnsc   = (float2*)alloc(sizeof(float2) * 64);
  float*  pooled = (float*)alloc(sizeof(float) * NBATCH * NCH);
  float*  HA     = (float*)alloc(sizeof(float) * (size_t)HN);        // 52.4 MB
  float*  HB     = (float*)alloc(sizeof(float) * (size_t)HN);        // 52.4 MB
  size_t XFB = (size_t)NBATCH * NCH * NB * NQ * sizeof(float2);      // 98.4 MB
  size_t XHB = (size_t)NBATCH * NCH * LL * NQ * sizeof(float2);      // 49.2 MB
  char* AR = alloc(XFB + XHB);                                       // 147.6 MB arena
  float2* Xf  = (float2*)AR;           // live: dft2 -> xh
  float2* xh  = (float2*)(AR + XFB);   // live: xh -> hk
  float2* hk2 = (float2*)AR;           // live: hk -> z    (reuses dead Xf)
  float2* zb  = (float2*)(AR + XFB);   // live: z -> fjq   (reuses dead xh; also z1)
  float2* Fb  = (float2*)AR;           // live: fjq -> dft (reuses dead hk2/Xf; 98.4 MB exact)

  if (ws_size < off) return;  // insufficient scratch: leave d_out zeroed

  const int T = 256;
  const size_t PARTS_B = sizeof(float2) * NBATCH * NCH;
  // constants
  qw_kernel<<<1, 32, 0, stream>>>(qw);
  wigner_kernel<<<(NB * LL * NQ + T - 1) / T, T, 0, stream>>>(dbeta, NB, 0);
  wigner_kernel<<<(LL * NQ + T - 1) / T, T, 0, stream>>>(deq, 1, 1);
  transpose_d_kernel<<<(NB * LL * NQ + T - 1) / T, T, 0, stream>>>(dbeta, dbT);

  // ---- layer 1: S2 conv -> HA
  s2_xh_kernel<<<NBATCH, T, 0, stream>>>(x, qw, dbeta, xh1);
  wfft_kernel<<<(MM * 1 * NCH + T - 1) / T, T, 0, stream>>>(k1, 1 * NCH, Wf);
  s2_z_kernel<<<(NBATCH * NCH * LL * NQ + T - 1) / T, T, 0, stream>>>(xh1, Wf, deq, zb);
  fjq_kernel<<<121 * 16, T, 0, stream>>>(zb, dbT, Fb);
  hipMemsetAsync(parts, 0, PARTS_B, stream);
  so3_dft_kernel<<<NBATCH * NCH * NB / 2, 64, 0, stream>>>(Fb, c1b, HA, parts);
  bn_finalize_kernel<<<1, 64, 0, stream>>>(parts, bn1g, bn1b, bnsc);

  // ---- layer 2: SO(3) conv HA -> HB (bn1+relu fused into dft2b load)
  dft2b_kernel<<<NBATCH * NCH * NB, T, 0, stream>>>(HA, bnsc, Xf);
  xh_kernel<<<(NBATCH * NCH * NQ + T - 1) / T, T, 0, stream>>>(Xf, qw, dbeta, xh);
  wfft_kernel<<<(MM * NCH * NCH + T - 1) / T, T, 0, stream>>>(k2, NCH * NCH, Wf);
  hk_kernel<<<NBATCH * LL * MM, 64, 0, stream>>>(xh, deq, hk2);
  z_kernel<<<512, T, 0, stream>>>(hk2, Wf, zb);
  fjq_kernel<<<121 * 16, T, 0, stream>>>(zb, dbT, Fb);
  hipMemsetAsync(parts, 0, PARTS_B, stream);
  so3_dft_kernel<<<NBATCH * NCH * NB / 2, 64, 0, stream>>>(Fb, c2b, HB, parts);
  bn_finalize_kernel<<<1, 64, 0, stream>>>(parts, bn2g, bn2b, bnsc);

  // ---- layer 3: SO(3) conv HB -> HA (bn2+relu fused into dft2b load)
  dft2b_kernel<<<NBATCH * NCH * NB, T, 0, stream>>>(HB, bnsc, Xf);
  xh_kernel<<<(NBATCH * NCH * NQ + T - 1) / T, T, 0, stream>>>(Xf, qw, dbeta, xh);
  wfft_kernel<<<(MM * NCH * NCH + T - 1) / T, T, 0, stream>>>(k3, NCH * NCH, Wf);
  hk_kernel<<<NBATCH * LL * MM, 64, 0, stream>>>(xh, deq, hk2);
  z_kernel<<<512, T, 0, stream>>>(hk2, Wf, zb);
  fjq_kernel<<<121 * 16, T, 0, stream>>>(zb, dbT, Fb);
  hipMemsetAsync(parts, 0, PARTS_B, stream);
  so3_dft_kernel<<<NBATCH * NCH * NB / 2, 64, 0, stream>>>(Fb, c3b, HA, parts);
  bn_finalize_kernel<<<1, 64, 0, stream>>>(parts, bn3g, bn3b, bnsc);

  // ---- head (bn3+relu fused into pool)
  pool_kernel<<<NBATCH * NCH, T, 0, stream>>>(HA, bnsc, pooled);
  head_kernel<<<1, T, 0, stream>>>(pooled, fc1w, fc1b, g1, bb1,
                                   fc2w, fc2b, g2, bb2, fc3w, fc3b, out);
}